// Round 2
// baseline (6163.259 us; speedup 1.0000x reference)
//
#include <hip/hip_runtime.h>
#include <hip/hip_bf16.h>

// Model dims (compile-time constants from the reference)
#define BATCH  16
#define SEQ    512
#define IND    32
#define OUTD   32
#define EMBD   512
#define NBLK   2
#define NHEAD  4
#define INNERD 1024   // 2*EMB
#define DHEAD  256    // INNER/NH
#define GATES  3072   // 3*INNER
#define LNEPS  1e-5f

#define CB     4                  // batches per chunk (workspace = ~71 MB total)
#define RCH    (CB * SEQ)         // rows per chunk = 2048

// ---------------------------------------------------------------------------
// block-wide (256 threads, 4 waves of 64) reduction of two floats
__device__ __forceinline__ void block_sum2(float& a, float& b, float* red, int tid) {
#pragma unroll
  for (int o = 1; o < 64; o <<= 1) { a += __shfl_xor(a, o); b += __shfl_xor(b, o); }
  int wid = tid >> 6;
  if ((tid & 63) == 0) { red[wid] = a; red[4 + wid] = b; }
  __syncthreads();
  a = red[0] + red[1] + red[2] + red[3];
  b = red[4] + red[5] + red[6] + red[7];
  __syncthreads();
}

// ---------------------------------------------------------------------------
// h[row, e] = sum_i inputs[row, i] * W_in[i, e]   (full batch, 8192 rows)
__global__ __launch_bounds__(256) void inproj_kernel(
    const float* __restrict__ in, const float* __restrict__ Win,
    float* __restrict__ h) {
  long idx = (long)blockIdx.x * 256 + threadIdx.x;   // B*S*EMB
  int  e   = (int)(idx & (EMBD - 1));
  long row = idx >> 9;                                // EMB=512
  const float* ir = in + row * IND;
  float acc = 0.f;
#pragma unroll
  for (int i = 0; i < IND; ++i) acc += ir[i] * Win[i * EMBD + e];
  h[idx] = acc;
}

// ---------------------------------------------------------------------------
// xn[row,:] = LN(x[row,:]) * w   (row length 512, no bias)
__global__ __launch_bounds__(256) void ln_mul_kernel(
    const float* __restrict__ x, const float* __restrict__ w,
    float* __restrict__ y) {
  __shared__ float red[8];
  long row = blockIdx.x;
  int tid = threadIdx.x;
  const float* xr = x + row * EMBD;
  float v0 = xr[tid], v1 = xr[tid + 256];
  float s = v0 + v1, ss = v0 * v0 + v1 * v1;
  block_sum2(s, ss, red, tid);
  float mu = s * (1.f / EMBD);
  float var = ss * (1.f / EMBD) - mu * mu;
  float rs = rsqrtf(var + LNEPS);
  y[row * EMBD + tid]       = (v0 - mu) * rs * w[tid];
  y[row * EMBD + tid + 256] = (v1 - mu) * rs * w[tid + 256];
}

// ---------------------------------------------------------------------------
// Generic fp32 tiled GEMM: C[m,n] (+)= sum_k A[m,k] * B[k,n]  (or B[n,k] if TRANSB)
// z-batched: per blockIdx.z, A/B/C advance by given element offsets.
#define BM 64
#define BN 64
#define BKG 16
template <bool TRANSB, bool ACCUM>
__global__ __launch_bounds__(256) void gemm_f32(
    const float* __restrict__ A, int lda, long aOffZ,
    const float* __restrict__ B, int ldb, long bOffZ,
    float* __restrict__ C, int ldc, long cOffZ,
    int M, int N, int K) {
  A += (long)blockIdx.z * aOffZ;
  B += (long)blockIdx.z * bOffZ;
  C += (long)blockIdx.z * cOffZ;
  __shared__ float As[BKG][BM + 1];
  __shared__ float Bs[BKG][BN + 1];
  int tid = threadIdx.x;
  int tx = tid & 15, ty = tid >> 4;
  int m0 = blockIdx.y * BM, n0 = blockIdx.x * BN;
  float acc[4][4] = {};
  for (int k0 = 0; k0 < K; k0 += BKG) {
#pragma unroll
    for (int i = 0; i < 4; ++i) {   // A tile 64x16
      int idx = tid + i * 256;
      int m = idx >> 4, kk = idx & 15;
      As[kk][m] = A[(long)(m0 + m) * lda + k0 + kk];
    }
#pragma unroll
    for (int i = 0; i < 4; ++i) {   // B tile 16x64
      int idx = tid + i * 256;
      if (!TRANSB) {
        int kk = idx >> 6, n = idx & 63;
        Bs[kk][n] = B[(long)(k0 + kk) * ldb + n0 + n];
      } else {
        int n = idx >> 4, kk = idx & 15;
        Bs[kk][n] = B[(long)(n0 + n) * ldb + k0 + kk];
      }
    }
    __syncthreads();
#pragma unroll
    for (int kk = 0; kk < BKG; ++kk) {
      float a[4], b[4];
#pragma unroll
      for (int i = 0; i < 4; ++i) a[i] = As[kk][ty * 4 + i];
#pragma unroll
      for (int j = 0; j < 4; ++j) b[j] = Bs[kk][tx * 4 + j];
#pragma unroll
      for (int i = 0; i < 4; ++i)
#pragma unroll
        for (int j = 0; j < 4; ++j) acc[i][j] += a[i] * b[j];
    }
    __syncthreads();
  }
#pragma unroll
  for (int i = 0; i < 4; ++i) {
    int m = m0 + ty * 4 + i;
#pragma unroll
    for (int j = 0; j < 4; ++j) {
      int n = n0 + tx * 4 + j;
      if (ACCUM) C[(long)m * ldc + n] += acc[i][j];
      else       C[(long)m * ldc + n]  = acc[i][j];
    }
  }
}

// ---------------------------------------------------------------------------
// causal depthwise conv (K=4) over xm (= up[:, :1024]) + bias, then silu
// operates on one chunk: rows = RCH, b is chunk-local
__global__ __launch_bounds__(256) void conv_silu_kernel(
    const float* __restrict__ up, const float* __restrict__ w,
    const float* __restrict__ bias, float* __restrict__ xc) {
  long idx = (long)blockIdx.x * 256 + threadIdx.x;  // RCH*INNER
  int c = (int)(idx & (INNERD - 1));
  long bs = idx >> 10;
  int s = (int)(bs & (SEQ - 1));
  long b = bs >> 9;
  float acc = bias[c];
#pragma unroll
  for (int kk = 0; kk < 4; ++kk) {
    int t = s + kk - 3;
    if (t >= 0) acc += w[kk * INNERD + c] * up[((b << 9) + t) * (2 * INNERD) + c];
  }
  float sig = 1.f / (1.f + expf(-acc));
  xc[bs * INNERD + c] = acc * sig;
}

// ---------------------------------------------------------------------------
// gate projections: i_pre/f_pre[b, n, s] = concat(qh,kh,vh)[b,s,:] @ W + b
__global__ __launch_bounds__(256) void gates_kernel(
    const float* __restrict__ qh, const float* __restrict__ kh,
    const float* __restrict__ vh,
    const float* __restrict__ Wi, const float* __restrict__ bi,
    const float* __restrict__ Wf, const float* __restrict__ bf,
    float* __restrict__ ip, float* __restrict__ fp) {
  __shared__ float red[4][8];
  long bs = blockIdx.x;           // chunk-local b*S + s
  int tid = threadIdx.x;
  int lane = tid & 63, wid = tid >> 6;
  float pi[4] = {}, pf[4] = {};
  const float* qr = qh + bs * INNERD;
  const float* kr = kh + bs * INNERD;
  const float* vr = vh + bs * INNERD;
  for (int j = tid; j < INNERD; j += 256) {
    float xq = qr[j], xk = kr[j], xv = vr[j];
    const float* wiq = Wi + (long)j * NHEAD;
    const float* wik = Wi + (long)(j + INNERD) * NHEAD;
    const float* wiv = Wi + (long)(j + 2 * INNERD) * NHEAD;
    const float* wfq = Wf + (long)j * NHEAD;
    const float* wfk = Wf + (long)(j + INNERD) * NHEAD;
    const float* wfv = Wf + (long)(j + 2 * INNERD) * NHEAD;
#pragma unroll
    for (int n = 0; n < NHEAD; ++n) {
      pi[n] += xq * wiq[n] + xk * wik[n] + xv * wiv[n];
      pf[n] += xq * wfq[n] + xk * wfk[n] + xv * wfv[n];
    }
  }
#pragma unroll
  for (int n = 0; n < NHEAD; ++n) {
#pragma unroll
    for (int o = 1; o < 64; o <<= 1) {
      pi[n] += __shfl_xor(pi[n], o);
      pf[n] += __shfl_xor(pf[n], o);
    }
  }
  if (lane == 0) {
#pragma unroll
    for (int n = 0; n < NHEAD; ++n) { red[wid][n] = pi[n]; red[wid][4 + n] = pf[n]; }
  }
  __syncthreads();
  if (tid == 0) {
    long b = bs >> 9;
    int s = (int)(bs & (SEQ - 1));
#pragma unroll
    for (int n = 0; n < NHEAD; ++n) {
      float a = red[0][n] + red[1][n] + red[2][n] + red[3][n] + bi[n];
      float c = red[0][4 + n] + red[1][4 + n] + red[2][4 + n] + red[3][4 + n] + bf[n];
      ip[(b * NHEAD + n) * SEQ + s] = a;
      fp[(b * NHEAD + n) * SEQ + s] = c;
    }
  }
}

// ---------------------------------------------------------------------------
// F[bh,:] = cumsum_t log_sigmoid(f_pre[bh,t])   (bh over CB*NH)
__global__ void fcum_kernel(const float* __restrict__ fp, float* __restrict__ F) {
  int bh = blockIdx.x;
  if (threadIdx.x == 0) {
    const float* f = fp + (long)bh * SEQ;
    float* Fr = F + (long)bh * SEQ;
    float acc = 0.f;
    for (int t = 0; t < SEQ; ++t) {
      float x = f[t];
      float ls = fminf(x, 0.f) - log1pf(expf(-fabsf(x)));  // stable log-sigmoid
      acc += ls;
      Fr[t] = acc;
    }
  }
}

// ---------------------------------------------------------------------------
// mLSTM cell + fused head-norm/skip/silu(z), one workgroup per (b, h, s) row.
// cell: hv[d] = sum_{t<=s} C[t]*v[t,d] / (norm + 1e-6)
// then: xc[bs, h*DH+d] = (LN_d(hv)*onw + skip*xc) * silu(z)
__global__ __launch_bounds__(256) void cell_hnorm_kernel(
    const float* __restrict__ qh, const float* __restrict__ kh,
    const float* __restrict__ vh, const float* __restrict__ ip,
    const float* __restrict__ F,
    const float* __restrict__ onw, const float* __restrict__ skipw,
    const float* __restrict__ up, float* __restrict__ xc) {
  int s = blockIdx.x, h = blockIdx.y, b = blockIdx.z;   // b chunk-local
  int tid = threadIdx.x;
  int lane = tid & 63, wid = tid >> 6;
  __shared__ float sh_q[DHEAD];
  __shared__ float sh_qk[SEQ];
  __shared__ float sh_ld[SEQ];
  __shared__ float sh_red[8];
  long bh = (long)b * NHEAD + h;
  const float* Fr = F + bh * SEQ;
  const float* ipr = ip + bh * SEQ;
  sh_q[tid] = qh[((long)b * SEQ + s) * INNERD + h * DHEAD + tid];
  __syncthreads();
  float Fs = Fr[s];
  float wmax = -INFINITY;
  float4 qv = *(const float4*)(sh_q + lane * 4);
  for (int t = wid; t <= s; t += 4) {
    const float* kr = kh + ((long)b * SEQ + t) * INNERD + h * DHEAD;
    float4 kv = *(const float4*)(kr + lane * 4);
    float p = qv.x * kv.x + qv.y * kv.y + qv.z * kv.z + qv.w * kv.w;
#pragma unroll
    for (int o = 1; o < 64; o <<= 1) p += __shfl_xor(p, o);
    float ld = Fs - Fr[t] + ipr[t];
    if (lane == 0) { sh_qk[t] = p * 0.0625f; sh_ld[t] = ld; }
    wmax = fmaxf(wmax, ld);
  }
  if (lane == 0) sh_red[wid] = wmax;
  __syncthreads();
  float m = fmaxf(fmaxf(sh_red[0], sh_red[1]), fmaxf(sh_red[2], sh_red[3]));
  // C[t] = qk[t]*exp(log_D[t]-m);  also row-sum of C
  float psum = 0.f;
  for (int t = tid; t <= s; t += 256) {
    float c = sh_qk[t] * expf(sh_ld[t] - m);
    sh_qk[t] = c;
    psum += c;
  }
#pragma unroll
  for (int o = 1; o < 64; o <<= 1) psum += __shfl_xor(psum, o);
  if (lane == 0) sh_red[4 + wid] = psum;
  __syncthreads();
  float tot = sh_red[4] + sh_red[5] + sh_red[6] + sh_red[7];
  float denom = fmaxf(fabsf(tot), expf(-m)) + 1e-6f;
  float inv = 1.f / denom;
  // PV: thread d accumulates over t (coalesced v reads)
  float acc = 0.f;
  for (int t = 0; t <= s; ++t) {
    acc += sh_qk[t] * vh[((long)b * SEQ + t) * INNERD + h * DHEAD + tid];
  }
  float hv = acc * inv;
  // ---- fused head-norm + skip + silu(z) gate, write into xc in place ----
  __syncthreads();   // protect sh_red reuse inside block_sum2
  float sum = hv, ss = hv * hv;
  block_sum2(sum, ss, sh_red, tid);
  float mu = sum * (1.f / DHEAD);
  float var = ss * (1.f / DHEAD) - mu * mu;
  float y = (hv - mu) * rsqrtf(var + LNEPS);
  int c = h * DHEAD + tid;
  long bs = (long)b * SEQ + s;
  float z = up[bs * (2 * INNERD) + INNERD + c];
  float sig = 1.f / (1.f + expf(-z));
  float xcv = xc[bs * INNERD + c];
  xc[bs * INNERD + c] = (y * onw[c] + skipw[c] * xcv) * (z * sig);
}

// ---------------------------------------------------------------------------
// final: post-LN (last token only), out-LN (w,b), head GEMM
__global__ __launch_bounds__(256) void final_kernel(
    const float* __restrict__ h, const float* __restrict__ pw,
    const float* __restrict__ ow, const float* __restrict__ ob,
    const float* __restrict__ Wh, const float* __restrict__ bh,
    float* __restrict__ out) {
  __shared__ float red[8];
  __shared__ float sh[EMBD];
  int b = blockIdx.x, tid = threadIdx.x;
  const float* xr = h + ((long)b * SEQ + (SEQ - 1)) * EMBD;
  float v0 = xr[tid], v1 = xr[tid + 256];
  float s = v0 + v1, ss = v0 * v0 + v1 * v1;
  block_sum2(s, ss, red, tid);
  float mu = s * (1.f / EMBD), var = ss * (1.f / EMBD) - mu * mu;
  float rs = rsqrtf(var + LNEPS);
  float y0 = (v0 - mu) * rs * pw[tid];
  float y1 = (v1 - mu) * rs * pw[tid + 256];
  float s2 = y0 + y1, ss2 = y0 * y0 + y1 * y1;
  block_sum2(s2, ss2, red, tid);
  float mu2 = s2 * (1.f / EMBD), var2 = ss2 * (1.f / EMBD) - mu2 * mu2;
  float rs2 = rsqrtf(var2 + LNEPS);
  sh[tid]       = (y0 - mu2) * rs2 * ow[tid] + ob[tid];
  sh[tid + 256] = (y1 - mu2) * rs2 * ow[tid + 256] + ob[tid + 256];
  __syncthreads();
  if (tid < OUTD) {
    float acc = bh[tid];
    for (int e = 0; e < EMBD; ++e) acc += sh[e] * Wh[e * OUTD + tid];
    out[b * OUTD + tid] = acc;
  }
}

// ---------------------------------------------------------------------------
extern "C" void kernel_launch(void* const* d_in, const int* in_sizes, int n_in,
                              void* d_out, int out_size, void* d_ws, size_t ws_size,
                              hipStream_t stream) {
  const float* inputs    = (const float*)d_in[0];
  const float* W_in      = (const float*)d_in[1];
  const float* ln_w      = (const float*)d_in[2];
  const float* W_up      = (const float*)d_in[3];
  const float* conv_w    = (const float*)d_in[4];
  const float* conv_b    = (const float*)d_in[5];
  const float* Wq        = (const float*)d_in[6];
  const float* Wk        = (const float*)d_in[7];
  const float* Wv        = (const float*)d_in[8];
  const float* W_i       = (const float*)d_in[9];
  const float* b_i       = (const float*)d_in[10];
  const float* W_f       = (const float*)d_in[11];
  const float* b_f       = (const float*)d_in[12];
  const float* skipw     = (const float*)d_in[13];
  const float* onorm_w   = (const float*)d_in[14];
  const float* W_down    = (const float*)d_in[15];
  const float* post_ln_w = (const float*)d_in[16];
  const float* out_ln_w  = (const float*)d_in[17];
  const float* out_ln_b  = (const float*)d_in[18];
  const float* W_head    = (const float*)d_in[19];
  const float* b_head    = (const float*)d_in[20];
  float* out = (float*)d_out;

  const long ROWS = (long)BATCH * SEQ;  // 8192
  // workspace layout (~71.4 MB total in fp32)
  float* p = (float*)d_ws;
  float* h    = p; p += ROWS * EMBD;          // 16.8 MB (persistent residual)
  float* xn   = p; p += (long)RCH * EMBD;     //  4.2 MB (per-chunk)
  float* up   = p; p += (long)RCH * 2 * INNERD; // 16.8 MB
  float* xc   = p; p += (long)RCH * INNERD;   //  8.4 MB
  float* qh   = p; p += (long)RCH * INNERD;
  float* khb  = p; p += (long)RCH * INNERD;
  float* vhb  = p; p += (long)RCH * INNERD;
  float* ipb  = p; p += (long)CB * NHEAD * SEQ;
  float* fpb  = p; p += (long)CB * NHEAD * SEQ;
  float* Fc   = p; p += (long)CB * NHEAD * SEQ;

  inproj_kernel<<<(ROWS * EMBD) / 256, 256, 0, stream>>>(inputs, W_in, h);

  for (int bl = 0; bl < NBLK; ++bl) {
    const float* lnw  = ln_w    + (long)bl * EMBD;
    const float* Wupb = W_up    + (long)bl * EMBD * 2 * INNERD;
    const float* cwb  = conv_w  + (long)bl * 4 * INNERD;
    const float* cbb  = conv_b  + (long)bl * INNERD;
    const float* Wqb  = Wq      + (long)bl * NHEAD * DHEAD * DHEAD;
    const float* Wkb  = Wk      + (long)bl * NHEAD * DHEAD * DHEAD;
    const float* Wvb  = Wv      + (long)bl * NHEAD * DHEAD * DHEAD;
    const float* Wib  = W_i     + (long)bl * GATES * NHEAD;
    const float* bib  = b_i     + (long)bl * NHEAD;
    const float* Wfb  = W_f     + (long)bl * GATES * NHEAD;
    const float* bfb  = b_f     + (long)bl * NHEAD;
    const float* skb  = skipw   + (long)bl * INNERD;
    const float* onw  = onorm_w + (long)bl * INNERD;
    const float* Wdb  = W_down  + (long)bl * INNERD * EMBD;

    for (int b0 = 0; b0 < BATCH; b0 += CB) {
      float* hch = h + (long)b0 * SEQ * EMBD;

      ln_mul_kernel<<<RCH, 256, 0, stream>>>(hch, lnw, xn);

      // up-projection: xn (2048x512) @ W_up (512x2048)
      gemm_f32<false, false><<<dim3(2 * INNERD / BN, RCH / BM, 1), 256, 0, stream>>>(
          xn, EMBD, 0, Wupb, 2 * INNERD, 0, up, 2 * INNERD, 0,
          RCH, 2 * INNERD, EMBD);

      conv_silu_kernel<<<((long)RCH * INNERD) / 256, 256, 0, stream>>>(up, cwb, cbb, xc);

      // per-head projections (B^T): qh = xc @ Wq[h]^T, kh = xc @ Wk[h]^T, vh = xm @ Wv[h]^T
      gemm_f32<true, false><<<dim3(DHEAD / BN, RCH / BM, NHEAD), 256, 0, stream>>>(
          xc, INNERD, DHEAD, Wqb, DHEAD, (long)DHEAD * DHEAD, qh, INNERD, DHEAD,
          RCH, DHEAD, DHEAD);
      gemm_f32<true, false><<<dim3(DHEAD / BN, RCH / BM, NHEAD), 256, 0, stream>>>(
          xc, INNERD, DHEAD, Wkb, DHEAD, (long)DHEAD * DHEAD, khb, INNERD, DHEAD,
          RCH, DHEAD, DHEAD);
      gemm_f32<true, false><<<dim3(DHEAD / BN, RCH / BM, NHEAD), 256, 0, stream>>>(
          up, 2 * INNERD, DHEAD, Wvb, DHEAD, (long)DHEAD * DHEAD, vhb, INNERD, DHEAD,
          RCH, DHEAD, DHEAD);

      gates_kernel<<<RCH, 256, 0, stream>>>(qh, khb, vhb, Wib, bib, Wfb, bfb, ipb, fpb);
      fcum_kernel<<<CB * NHEAD, 64, 0, stream>>>(fpb, Fc);

      cell_hnorm_kernel<<<dim3(SEQ, NHEAD, CB), 256, 0, stream>>>(
          qh, khb, vhb, ipb, Fc, onw, skb, up, xc);

      // down-projection with residual: hch += xc (2048x1024) @ W_down (1024x512)
      gemm_f32<false, true><<<dim3(EMBD / BN, RCH / BM, 1), 256, 0, stream>>>(
          xc, INNERD, 0, Wdb, EMBD, 0, hch, EMBD, 0,
          RCH, EMBD, INNERD);
    }
  }

  final_kernel<<<BATCH, 256, 0, stream>>>(h, post_ln_w, out_ln_w, out_ln_b,
                                          W_head, b_head, out);
}

// Round 4
// 1971.138 us; speedup vs baseline: 3.1268x; 3.1268x over previous
//
#include <hip/hip_runtime.h>
#include <hip/hip_bf16.h>

#define BATCH  16
#define SEQ    512
#define IND    32
#define OUTD   32
#define EMBD   512
#define NBLK   2
#define NHEAD  4
#define INNERD 1024   // 2*EMB
#define DHEAD  256    // INNER/NH
#define GATES  3072   // 3*INNER
#define LNEPS  1e-5f

#define CB     4                  // batches per chunk
#define RCH    (CB * SEQ)         // rows per chunk = 2048

typedef __attribute__((ext_vector_type(8))) short bf16x8;   // 8 bf16 in 4 VGPRs
typedef __attribute__((ext_vector_type(4))) float f32x4;

__device__ __forceinline__ float b2f(unsigned short u) {
  union { unsigned int i; float f; } v; v.i = ((unsigned int)u) << 16; return v.f;
}
__device__ __forceinline__ unsigned short f2b(float f) {
  __hip_bfloat16 h = __float2bfloat16(f);           // round-to-nearest
  unsigned short u; __builtin_memcpy(&u, &h, 2); return u;
}

// ---------------------------------------------------------------------------
__device__ __forceinline__ void block_sum2(float& a, float& b, float* red, int tid) {
#pragma unroll
  for (int o = 1; o < 64; o <<= 1) { a += __shfl_xor(a, o); b += __shfl_xor(b, o); }
  int wid = tid >> 6;
  if ((tid & 63) == 0) { red[wid] = a; red[4 + wid] = b; }
  __syncthreads();
  a = red[0] + red[1] + red[2] + red[3];
  b = red[4] + red[5] + red[6] + red[7];
  __syncthreads();
}

// ---------------------------------------------------------------------------
__global__ __launch_bounds__(256) void inproj_kernel(
    const float* __restrict__ in, const float* __restrict__ Win,
    float* __restrict__ h) {
  long idx = (long)blockIdx.x * 256 + threadIdx.x;
  int  e   = (int)(idx & (EMBD - 1));
  long row = idx >> 9;
  const float* ir = in + row * IND;
  float acc = 0.f;
#pragma unroll
  for (int i = 0; i < IND; ++i) acc += ir[i] * Win[i * EMBD + e];
  h[idx] = acc;
}

// ---------------------------------------------------------------------------
// xn[row,:] = bf16( LN(x[row,:]) * w )
__global__ __launch_bounds__(256) void ln_mul_kernel(
    const float* __restrict__ x, const float* __restrict__ w,
    unsigned short* __restrict__ y) {
  __shared__ float red[8];
  long row = blockIdx.x;
  int tid = threadIdx.x;
  const float* xr = x + row * EMBD;
  float v0 = xr[tid], v1 = xr[tid + 256];
  float s = v0 + v1, ss = v0 * v0 + v1 * v1;
  block_sum2(s, ss, red, tid);
  float mu = s * (1.f / EMBD);
  float var = ss * (1.f / EMBD) - mu * mu;
  float rs = rsqrtf(var + LNEPS);
  y[row * EMBD + tid]       = f2b((v0 - mu) * rs * w[tid]);
  y[row * EMBD + tid + 256] = f2b((v1 - mu) * rs * w[tid + 256]);
}

// ---------------------------------------------------------------------------
// weight transpose-cast: out[n][k] = bf16(in[k][n]); z batches
__global__ __launch_bounds__(256) void castT_kernel(
    const float* __restrict__ in, unsigned short* __restrict__ out, int K, int N) {
  __shared__ float t[32][33];
  long zoff = (long)blockIdx.z * K * N;
  in += zoff; out += zoff;
  int n0 = blockIdx.x * 32, k0 = blockIdx.y * 32;
  int tx = threadIdx.x & 31, ty = threadIdx.x >> 5;   // ty 0..7
#pragma unroll
  for (int i = 0; i < 32; i += 8)
    t[ty + i][tx] = in[(long)(k0 + ty + i) * N + n0 + tx];
  __syncthreads();
#pragma unroll
  for (int i = 0; i < 32; i += 8)
    out[(long)(n0 + ty + i) * K + k0 + tx] = f2b(t[tx][ty + i]);
}

__global__ __launch_bounds__(256) void castflat_kernel(
    const float* __restrict__ in, unsigned short* __restrict__ out) {
  long i = (long)blockIdx.x * 256 + threadIdx.x;
  out[i] = f2b(in[i]);
}

// ---------------------------------------------------------------------------
// bf16 MFMA GEMM: C[m,n] = sum_k A[m,k] * Bt[n,k]; 128x128 tile, 4 waves.
// MODE: 1 = f32 accumulate, 2 = bf16 store, 3 = bf16 store + transposed copy CT
//       (CT layout [b][z][col][row&511] for the v-projection, b = row>>9)
template <int MODE>
__global__ __launch_bounds__(256) void gemm_mfma(
    const unsigned short* __restrict__ A, int lda, long aOffZ,
    const unsigned short* __restrict__ B, int ldb, long bOffZ,
    void* __restrict__ Cv, int ldc, long cOffZ,
    unsigned short* __restrict__ CT, int K) {
  int z = blockIdx.z;
  A += (long)z * aOffZ;
  B += (long)z * bOffZ;
  __shared__ unsigned short As[128][72];   // 144B row stride: 16B-aligned, ~2-way reads
  __shared__ unsigned short Bs[128][72];
  int tid = threadIdx.x;
  int lane = tid & 63, w = tid >> 6;
  int l15 = lane & 15, l4 = lane >> 4;
  int wr = w >> 1, wc = w & 1;
  int m0 = blockIdx.y * 128, n0 = blockIdx.x * 128;
  f32x4 acc[4][4];
#pragma unroll
  for (int i = 0; i < 4; ++i)
#pragma unroll
    for (int j = 0; j < 4; ++j) acc[i][j] = (f32x4){0.f, 0.f, 0.f, 0.f};

  for (int k0 = 0; k0 < K; k0 += 32) {
    __syncthreads();
#pragma unroll
    for (int L = 0; L < 2; ++L) {
      int lidx = L * 256 + tid;
      int r = lidx >> 2, kq = (lidx & 3) * 8;
      *(bf16x8*)(&As[r][kq]) = *(const bf16x8*)(A + (long)(m0 + r) * lda + k0 + kq);
      *(bf16x8*)(&Bs[r][kq]) = *(const bf16x8*)(B + (long)(n0 + r) * ldb + k0 + kq);
    }
    __syncthreads();
    bf16x8 af[4], bfr[4];
#pragma unroll
    for (int i = 0; i < 4; ++i)
      af[i] = *(const bf16x8*)(&As[wr * 64 + i * 16 + l15][l4 * 8]);
#pragma unroll
    for (int j = 0; j < 4; ++j)
      bfr[j] = *(const bf16x8*)(&Bs[wc * 64 + j * 16 + l15][l4 * 8]);
#pragma unroll
    for (int i = 0; i < 4; ++i)
#pragma unroll
      for (int j = 0; j < 4; ++j)
        acc[i][j] = __builtin_amdgcn_mfma_f32_16x16x32_bf16(af[i], bfr[j], acc[i][j], 0, 0, 0);
  }

#pragma unroll
  for (int i = 0; i < 4; ++i) {
#pragma unroll
    for (int j = 0; j < 4; ++j) {
      int col = n0 + wc * 64 + j * 16 + l15;
#pragma unroll
      for (int r = 0; r < 4; ++r) {
        int m = m0 + wr * 64 + i * 16 + l4 * 4 + r;
        float val = acc[i][j][r];
        if (MODE == 1) {
          float* C = (float*)Cv + (long)z * cOffZ;
          C[(long)m * ldc + col] += val;
        } else {
          unsigned short* C = (unsigned short*)Cv + (long)z * cOffZ;
          unsigned short bv = f2b(val);
          C[(long)m * ldc + col] = bv;
          if (MODE == 3) {
            long ct = (((long)(m >> 9) * NHEAD + z) * DHEAD + col) * SEQ + (m & (SEQ - 1));
            CT[ct] = bv;
          }
        }
      }
    }
  }
}

// ---------------------------------------------------------------------------
// causal depthwise conv (K=4) over xm = up_b[:, :1024] (bf16) + bias, silu
__global__ __launch_bounds__(256) void conv_silu_kernel(
    const unsigned short* __restrict__ upb, const float* __restrict__ w,
    const float* __restrict__ bias, float* __restrict__ xc,
    unsigned short* __restrict__ xcb) {
  long idx = (long)blockIdx.x * 256 + threadIdx.x;  // RCH*INNER
  int c = (int)(idx & (INNERD - 1));
  long bs = idx >> 10;
  int s = (int)(bs & (SEQ - 1));
  long b = bs >> 9;
  float acc = bias[c];
#pragma unroll
  for (int kk = 0; kk < 4; ++kk) {
    int t = s + kk - 3;
    if (t >= 0) acc += w[kk * INNERD + c] * b2f(upb[((b << 9) + t) * (2 * INNERD) + c]);
  }
  float sig = 1.f / (1.f + __expf(-acc));
  float v = acc * sig;
  xc[bs * INNERD + c] = v;
  xcb[bs * INNERD + c] = f2b(v);
}

// ---------------------------------------------------------------------------
// gate projections from bf16 q/k/v rows
__global__ __launch_bounds__(256) void gates_kernel(
    const unsigned short* __restrict__ qh, const unsigned short* __restrict__ kh,
    const unsigned short* __restrict__ vh,
    const float* __restrict__ Wi, const float* __restrict__ bi,
    const float* __restrict__ Wf, const float* __restrict__ bf,
    float* __restrict__ ip, float* __restrict__ fp) {
  __shared__ float red[4][8];
  long bs = blockIdx.x;
  int tid = threadIdx.x;
  int lane = tid & 63, wid = tid >> 6;
  float pi[4] = {}, pf[4] = {};
  const unsigned short* qr = qh + bs * INNERD;
  const unsigned short* kr = kh + bs * INNERD;
  const unsigned short* vr = vh + bs * INNERD;
  for (int j = tid; j < INNERD; j += 256) {
    float xq = b2f(qr[j]), xk = b2f(kr[j]), xv = b2f(vr[j]);
    const float* wiq = Wi + (long)j * NHEAD;
    const float* wik = Wi + (long)(j + INNERD) * NHEAD;
    const float* wiv = Wi + (long)(j + 2 * INNERD) * NHEAD;
    const float* wfq = Wf + (long)j * NHEAD;
    const float* wfk = Wf + (long)(j + INNERD) * NHEAD;
    const float* wfv = Wf + (long)(j + 2 * INNERD) * NHEAD;
#pragma unroll
    for (int n = 0; n < NHEAD; ++n) {
      pi[n] += xq * wiq[n] + xk * wik[n] + xv * wiv[n];
      pf[n] += xq * wfq[n] + xk * wfk[n] + xv * wfv[n];
    }
  }
#pragma unroll
  for (int n = 0; n < NHEAD; ++n) {
#pragma unroll
    for (int o = 1; o < 64; o <<= 1) {
      pi[n] += __shfl_xor(pi[n], o);
      pf[n] += __shfl_xor(pf[n], o);
    }
  }
  if (lane == 0) {
#pragma unroll
    for (int n = 0; n < NHEAD; ++n) { red[wid][n] = pi[n]; red[wid][4 + n] = pf[n]; }
  }
  __syncthreads();
  if (tid == 0) {
    long b = bs >> 9;
    int s = (int)(bs & (SEQ - 1));
#pragma unroll
    for (int n = 0; n < NHEAD; ++n) {
      float a = red[0][n] + red[1][n] + red[2][n] + red[3][n] + bi[n];
      float c = red[0][4 + n] + red[1][4 + n] + red[2][4 + n] + red[3][4 + n] + bf[n];
      ip[(b * NHEAD + n) * SEQ + s] = a;
      fp[(b * NHEAD + n) * SEQ + s] = c;
    }
  }
}

// ---------------------------------------------------------------------------
// parallel gate scan: F = cumsum(logsig(f)); Bc = F - i; mrow = F + runmax(i - F)
__global__ __launch_bounds__(64) void fgate_kernel(
    const float* __restrict__ fp, const float* __restrict__ ip,
    float* __restrict__ F, float* __restrict__ Bc, float* __restrict__ mrow) {
  int bh = blockIdx.x;
  int lane = threadIdx.x;
  const float* fr = fp + (long)bh * SEQ;
  const float* ir = ip + (long)bh * SEQ;
  float v[8]; float run = 0.f;
#pragma unroll
  for (int i = 0; i < 8; ++i) {
    float x = fr[lane * 8 + i];
    float ls = fminf(x, 0.f) - log1pf(__expf(-fabsf(x)));
    run += ls; v[i] = run;
  }
  float tot = run, scan = run;
#pragma unroll
  for (int off = 1; off < 64; off <<= 1) {
    float n = __shfl_up(scan, off);
    if (lane >= off) scan += n;
  }
  float excl = scan - tot;
  float Fv[8];
#pragma unroll
  for (int i = 0; i < 8; ++i) {
    Fv[i] = excl + v[i];
    F[(long)bh * SEQ + lane * 8 + i] = Fv[i];
  }
  float g[8], pmv[8]; float pm = -INFINITY;
#pragma unroll
  for (int i = 0; i < 8; ++i) {
    g[i] = ir[lane * 8 + i] - Fv[i];
    Bc[(long)bh * SEQ + lane * 8 + i] = -g[i];
    pm = fmaxf(pm, g[i]); pmv[i] = pm;
  }
  float mx = pm;
#pragma unroll
  for (int off = 1; off < 64; off <<= 1) {
    float n = __shfl_up(mx, off);
    if (lane >= off) mx = fmaxf(mx, n);
  }
  float ex = __shfl_up(mx, 1);
  if (lane == 0) ex = -INFINITY;
#pragma unroll
  for (int i = 0; i < 8; ++i) {
    float inc = fmaxf(ex, pmv[i]);
    mrow[(long)bh * SEQ + lane * 8 + i] = Fv[i] + inc;
  }
}

// ---------------------------------------------------------------------------
// flash mLSTM cell + fused head-norm/skip/silu(z). Block = (qtile, h, b); 4 waves,
// wave w owns rows qt*64+w*16 .. +16, full d=256.
__global__ __launch_bounds__(256) void cell_kernel(
    const unsigned short* __restrict__ qb, const unsigned short* __restrict__ kb,
    const unsigned short* __restrict__ vbT,
    const float* __restrict__ F, const float* __restrict__ Bc,
    const float* __restrict__ mrow,
    const float* __restrict__ xc, const unsigned short* __restrict__ upb,
    const float* __restrict__ onw, const float* __restrict__ skw,
    unsigned short* __restrict__ xcb) {
  int qt = blockIdx.x, h = blockIdx.y, b = blockIdx.z;
  int tid = threadIdx.x, lane = tid & 63, w = tid >> 6;
  int l15 = lane & 15, l4 = lane >> 4;
  __shared__ unsigned short P[64][72];
  int bh = b * NHEAD + h;
  const float* Fr = F + (long)bh * SEQ;
  const float* Br = Bc + (long)bh * SEQ;
  const float* Mr = mrow + (long)bh * SEQ;
  int s0 = qt * 64 + w * 16;
  long bs0 = (long)b * SEQ;
  int sr[4]; float Ar[4], Mv[4];
#pragma unroll
  for (int r = 0; r < 4; ++r) {
    sr[r] = s0 + l4 * 4 + r;
    float fs = Fr[sr[r]];
    Mv[r] = Mr[sr[r]];
    Ar[r] = fs - Mv[r];
  }
  bf16x8 qf[8];
  const unsigned short* qp = qb + (bs0 + s0 + l15) * INNERD + h * DHEAD + l4 * 8;
#pragma unroll
  for (int kk = 0; kk < 8; ++kk) qf[kk] = *(const bf16x8*)(qp + kk * 32);
  f32x4 o[16];
#pragma unroll
  for (int i = 0; i < 16; ++i) o[i] = (f32x4){0.f, 0.f, 0.f, 0.f};
  float rs[4] = {0.f, 0.f, 0.f, 0.f};

  for (int tt = 0; tt <= qt; ++tt) {
    int t0 = tt * 64;
    bool diag = (tt == qt);
#pragma unroll
    for (int tf = 0; tf < 4; ++tf) {
      const unsigned short* kp = kb + (bs0 + t0 + tf * 16 + l15) * INNERD + h * DHEAD + l4 * 8;
      f32x4 s = (f32x4){0.f, 0.f, 0.f, 0.f};
#pragma unroll
      for (int kk = 0; kk < 8; ++kk) {
        bf16x8 kf = *(const bf16x8*)(kp + kk * 32);
        s = __builtin_amdgcn_mfma_f32_16x16x32_bf16(qf[kk], kf, s, 0, 0, 0);
      }
      int tcol = t0 + tf * 16 + l15;
      float bc = Br[tcol];
#pragma unroll
      for (int r = 0; r < 4; ++r) {
        float p = s[r] * 0.0625f * __expf(Ar[r] - bc);
        if (diag && tcol > sr[r]) p = 0.f;
        rs[r] += p;
        P[w * 16 + l4 * 4 + r][tf * 16 + l15] = f2b(p);
      }
    }
#pragma unroll
    for (int ks = 0; ks < 2; ++ks) {
      bf16x8 pa = *(const bf16x8*)(&P[w * 16 + l15][ks * 32 + l4 * 8]);
      const unsigned short* vp = vbT + ((long)bh * DHEAD + l15) * SEQ + t0 + ks * 32 + l4 * 8;
#pragma unroll
      for (int df = 0; df < 16; ++df) {
        bf16x8 vf = *(const bf16x8*)(vp + (long)df * 16 * SEQ);
        o[df] = __builtin_amdgcn_mfma_f32_16x16x32_bf16(pa, vf, o[df], 0, 0, 0);
      }
    }
  }
  // rowsum across the 16-lane group
#pragma unroll
  for (int r = 0; r < 4; ++r)
#pragma unroll
    for (int off = 1; off < 16; off <<= 1) rs[r] += __shfl_xor(rs[r], off);
  float inv[4];
#pragma unroll
  for (int r = 0; r < 4; ++r) {
    float denom = fmaxf(fabsf(rs[r]), __expf(-Mv[r])) + 1e-6f;
    inv[r] = 1.f / denom;
  }
#pragma unroll
  for (int df = 0; df < 16; ++df)
#pragma unroll
    for (int r = 0; r < 4; ++r) o[df][r] *= inv[r];
  // fused head-LN over d=256
  float sm[4] = {}, sq[4] = {};
#pragma unroll
  for (int df = 0; df < 16; ++df)
#pragma unroll
    for (int r = 0; r < 4; ++r) { float x = o[df][r]; sm[r] += x; sq[r] += x * x; }
#pragma unroll
  for (int r = 0; r < 4; ++r)
#pragma unroll
    for (int off = 1; off < 16; off <<= 1) {
      sm[r] += __shfl_xor(sm[r], off);
      sq[r] += __shfl_xor(sq[r], off);
    }
  float mu[4], rstd[4];
#pragma unroll
  for (int r = 0; r < 4; ++r) {
    mu[r] = sm[r] * (1.f / DHEAD);
    float var = sq[r] * (1.f / DHEAD) - mu[r] * mu[r];
    rstd[r] = rsqrtf(var + LNEPS);
  }
#pragma unroll
  for (int df = 0; df < 16; ++df) {
    int c = h * DHEAD + df * 16 + l15;
    float ow = onw[c], sw = skw[c];
#pragma unroll
    for (int r = 0; r < 4; ++r) {
      long grow = bs0 + sr[r];
      float z = b2f(upb[grow * (2 * INNERD) + INNERD + c]);
      float sig = 1.f / (1.f + __expf(-z));
      float xcv = xc[grow * INNERD + c];
      float y = (o[df][r] - mu[r]) * rstd[r];
      float g = (y * ow + sw * xcv) * (z * sig);
      xcb[grow * INNERD + c] = f2b(g);
    }
  }
}

// ---------------------------------------------------------------------------
__global__ __launch_bounds__(256) void final_kernel(
    const float* __restrict__ h, const float* __restrict__ pw,
    const float* __restrict__ ow, const float* __restrict__ ob,
    const float* __restrict__ Wh, const float* __restrict__ bh,
    float* __restrict__ out) {
  __shared__ float red[8];
  __shared__ float sh[EMBD];
  int b = blockIdx.x, tid = threadIdx.x;
  const float* xr = h + ((long)b * SEQ + (SEQ - 1)) * EMBD;
  float v0 = xr[tid], v1 = xr[tid + 256];
  float s = v0 + v1, ss = v0 * v0 + v1 * v1;
  block_sum2(s, ss, red, tid);
  float mu = s * (1.f / EMBD), var = ss * (1.f / EMBD) - mu * mu;
  float rs = rsqrtf(var + LNEPS);
  float y0 = (v0 - mu) * rs * pw[tid];
  float y1 = (v1 - mu) * rs * pw[tid + 256];
  float s2 = y0 + y1, ss2 = y0 * y0 + y1 * y1;
  block_sum2(s2, ss2, red, tid);
  float mu2 = s2 * (1.f / EMBD), var2 = ss2 * (1.f / EMBD) - mu2 * mu2;
  float rs2 = rsqrtf(var2 + LNEPS);
  sh[tid]       = (y0 - mu2) * rs2 * ow[tid] + ob[tid];
  sh[tid + 256] = (y1 - mu2) * rs2 * ow[tid + 256] + ob[tid + 256];
  __syncthreads();
  if (tid < OUTD) {
    float acc = bh[tid];
    for (int e = 0; e < EMBD; ++e) acc += sh[e] * Wh[e * OUTD + tid];
    out[b * OUTD + tid] = acc;
  }
}

// ---------------------------------------------------------------------------
extern "C" void kernel_launch(void* const* d_in, const int* in_sizes, int n_in,
                              void* d_out, int out_size, void* d_ws, size_t ws_size,
                              hipStream_t stream) {
  const float* inputs    = (const float*)d_in[0];
  const float* W_in      = (const float*)d_in[1];
  const float* ln_w      = (const float*)d_in[2];
  const float* W_up      = (const float*)d_in[3];
  const float* conv_w    = (const float*)d_in[4];
  const float* conv_b    = (const float*)d_in[5];
  const float* Wq        = (const float*)d_in[6];
  const float* Wk        = (const float*)d_in[7];
  const float* Wv        = (const float*)d_in[8];
  const float* W_i       = (const float*)d_in[9];
  const float* b_i       = (const float*)d_in[10];
  const float* W_f       = (const float*)d_in[11];
  const float* b_f       = (const float*)d_in[12];
  const float* skipw     = (const float*)d_in[13];
  const float* onorm_w   = (const float*)d_in[14];
  const float* W_down    = (const float*)d_in[15];
  const float* post_ln_w = (const float*)d_in[16];
  const float* out_ln_w  = (const float*)d_in[17];
  const float* out_ln_b  = (const float*)d_in[18];
  const float* W_head    = (const float*)d_in[19];
  const float* b_head    = (const float*)d_in[20];
  float* out = (float*)d_out;

  const long ROWS = (long)BATCH * SEQ;
  // ---- workspace layout (~66 MB) ----
  float* fpool = (float*)d_ws;
  float* h    = fpool; fpool += ROWS * EMBD;            // 16.8 MB
  float* xc   = fpool; fpool += (long)RCH * INNERD;     //  8.4 MB
  float* ipb  = fpool; fpool += (long)CB * NHEAD * SEQ;
  float* fpb  = fpool; fpool += (long)CB * NHEAD * SEQ;
  float* Fc   = fpool; fpool += (long)CB * NHEAD * SEQ;
  float* Bcc  = fpool; fpool += (long)CB * NHEAD * SEQ;
  float* mrw  = fpool; fpool += (long)CB * NHEAD * SEQ;
  unsigned short* upool = (unsigned short*)fpool;
  unsigned short* xn    = upool; upool += (long)RCH * EMBD;
  unsigned short* upb   = upool; upool += (long)RCH * 2 * INNERD;
  unsigned short* xcb   = upool; upool += (long)RCH * INNERD;
  unsigned short* qbuf  = upool; upool += (long)RCH * INNERD;
  unsigned short* kbuf  = upool; upool += (long)RCH * INNERD;
  unsigned short* vbuf  = upool; upool += (long)RCH * INNERD;
  unsigned short* vbT   = upool; upool += (long)CB * NHEAD * DHEAD * SEQ;
  unsigned short* WupT  = upool; upool += (long)NBLK * 2 * INNERD * EMBD;
  unsigned short* WdnT  = upool; upool += (long)NBLK * EMBD * INNERD;
  unsigned short* Wqb   = upool; upool += (long)NBLK * NHEAD * DHEAD * DHEAD;
  unsigned short* Wkb   = upool; upool += (long)NBLK * NHEAD * DHEAD * DHEAD;
  unsigned short* Wvb   = upool; upool += (long)NBLK * NHEAD * DHEAD * DHEAD;

  // ---- weight prep (same work every call) ----
  castT_kernel<<<dim3(2 * INNERD / 32, EMBD / 32, NBLK), 256, 0, stream>>>(
      W_up, WupT, EMBD, 2 * INNERD);                       // [512][2048] -> [2048][512]
  castT_kernel<<<dim3(EMBD / 32, INNERD / 32, NBLK), 256, 0, stream>>>(
      W_down, WdnT, INNERD, EMBD);                         // [1024][512] -> [512][1024]
  const int WQN = NBLK * NHEAD * DHEAD * DHEAD;
  castflat_kernel<<<WQN / 256, 256, 0, stream>>>(Wq, Wqb);
  castflat_kernel<<<WQN / 256, 256, 0, stream>>>(Wk, Wkb);
  castflat_kernel<<<WQN / 256, 256, 0, stream>>>(Wv, Wvb);

  inproj_kernel<<<(ROWS * EMBD) / 256, 256, 0, stream>>>(inputs, W_in, h);

  for (int bl = 0; bl < NBLK; ++bl) {
    const float* lnw  = ln_w    + (long)bl * EMBD;
    const float* cwb  = conv_w  + (long)bl * 4 * INNERD;
    const float* cbb  = conv_b  + (long)bl * INNERD;
    const float* Wib  = W_i     + (long)bl * GATES * NHEAD;
    const float* bib  = b_i     + (long)bl * NHEAD;
    const float* Wfb  = W_f     + (long)bl * GATES * NHEAD;
    const float* bfb  = b_f     + (long)bl * NHEAD;
    const float* skb  = skipw   + (long)bl * INNERD;
    const float* onw  = onorm_w + (long)bl * INNERD;
    const unsigned short* WupTb = WupT + (long)bl * 2 * INNERD * EMBD;
    const unsigned short* WdnTb = WdnT + (long)bl * EMBD * INNERD;
    const unsigned short* Wqbb  = Wqb + (long)bl * NHEAD * DHEAD * DHEAD;
    const unsigned short* Wkbb  = Wkb + (long)bl * NHEAD * DHEAD * DHEAD;
    const unsigned short* Wvbb  = Wvb + (long)bl * NHEAD * DHEAD * DHEAD;

    for (int b0 = 0; b0 < BATCH; b0 += CB) {
      float* hch = h + (long)b0 * SEQ * EMBD;

      ln_mul_kernel<<<RCH, 256, 0, stream>>>(hch, lnw, xn);

      // up: [2048x512] @ [512x2048] -> bf16 up_b
      gemm_mfma<2><<<dim3(2 * INNERD / 128, RCH / 128, 1), 256, 0, stream>>>(
          xn, EMBD, 0, WupTb, EMBD, 0, upb, 2 * INNERD, 0, nullptr, EMBD);

      conv_silu_kernel<<<((long)RCH * INNERD) / 256, 256, 0, stream>>>(
          upb, cwb, cbb, xc, xcb);

      // q,k from xcb; v from xm (= up_b cols 0..1023), + transposed copy vbT
      gemm_mfma<2><<<dim3(2, RCH / 128, NHEAD), 256, 0, stream>>>(
          xcb, INNERD, DHEAD, Wqbb, DHEAD, (long)DHEAD * DHEAD,
          qbuf, INNERD, DHEAD, nullptr, DHEAD);
      gemm_mfma<2><<<dim3(2, RCH / 128, NHEAD), 256, 0, stream>>>(
          xcb, INNERD, DHEAD, Wkbb, DHEAD, (long)DHEAD * DHEAD,
          kbuf, INNERD, DHEAD, nullptr, DHEAD);
      gemm_mfma<3><<<dim3(2, RCH / 128, NHEAD), 256, 0, stream>>>(
          upb, 2 * INNERD, DHEAD, Wvbb, DHEAD, (long)DHEAD * DHEAD,
          vbuf, INNERD, DHEAD, vbT, DHEAD);

      gates_kernel<<<RCH, 256, 0, stream>>>(qbuf, kbuf, vbuf, Wib, bib, Wfb, bfb, ipb, fpb);
      fgate_kernel<<<CB * NHEAD, 64, 0, stream>>>(fpb, ipb, Fc, Bcc, mrw);

      cell_kernel<<<dim3(SEQ / 64, NHEAD, CB), 256, 0, stream>>>(
          qbuf, kbuf, vbT, Fc, Bcc, mrw, xc, upb, onw, skb, xcb);

      // down: h += [2048x1024] @ [1024x512]
      gemm_mfma<1><<<dim3(EMBD / 128, RCH / 128, 1), 256, 0, stream>>>(
          xcb, INNERD, 0, WdnTb, INNERD, 0, hch, EMBD, 0, nullptr, INNERD);
    }
  }

  final_kernel<<<BATCH, 256, 0, stream>>>(h, post_ln_w, out_ln_w, out_ln_b,
                                          W_head, b_head, out);
}

// Round 8
// 962.248 us; speedup vs baseline: 6.4051x; 2.0485x over previous
//
#include <hip/hip_runtime.h>
#include <hip/hip_bf16.h>

#define BATCH  16
#define SEQ    512
#define IND    32
#define OUTD   32
#define EMBD   512
#define NBLK   2
#define NHEAD  4
#define INNERD 1024   // 2*EMB
#define DHEAD  256    // INNER/NH
#define GATES  3072   // 3*INNER
#define LNEPS  1e-5f

#define CB     8                  // batches per chunk (workspace ~96 MB total)
#define RCH    (CB * SEQ)         // rows per chunk = 4096

typedef __attribute__((ext_vector_type(8))) short bf16x8;   // 8 bf16 in 4 VGPRs
typedef __attribute__((ext_vector_type(4))) float f32x4;

__device__ __forceinline__ float b2f(unsigned short u) {
  union { unsigned int i; float f; } v; v.i = ((unsigned int)u) << 16; return v.f;
}
__device__ __forceinline__ unsigned short f2b(float f) {
  __hip_bfloat16 h = __float2bfloat16(f);           // round-to-nearest
  unsigned short u; __builtin_memcpy(&u, &h, 2); return u;
}

// ---------------------------------------------------------------------------
__device__ __forceinline__ void block_sum2(float& a, float& b, float* red, int tid) {
#pragma unroll
  for (int o = 1; o < 64; o <<= 1) { a += __shfl_xor(a, o); b += __shfl_xor(b, o); }
  int wid = tid >> 6;
  if ((tid & 63) == 0) { red[wid] = a; red[4 + wid] = b; }
  __syncthreads();
  a = red[0] + red[1] + red[2] + red[3];
  b = red[4] + red[5] + red[6] + red[7];
  __syncthreads();
}

// ---------------------------------------------------------------------------
__global__ __launch_bounds__(256) void inproj_kernel(
    const float* __restrict__ in, const float* __restrict__ Win,
    float* __restrict__ h) {
  long idx = (long)blockIdx.x * 256 + threadIdx.x;
  int  e   = (int)(idx & (EMBD - 1));
  long row = idx >> 9;
  const float* ir = in + row * IND;
  float acc = 0.f;
#pragma unroll
  for (int i = 0; i < IND; ++i) acc += ir[i] * Win[i * EMBD + e];
  h[idx] = acc;
}

// ---------------------------------------------------------------------------
// xn[row,:] = bf16( LN(x[row,:]) * w )
__global__ __launch_bounds__(256) void ln_mul_kernel(
    const float* __restrict__ x, const float* __restrict__ w,
    unsigned short* __restrict__ y) {
  __shared__ float red[8];
  long row = blockIdx.x;
  int tid = threadIdx.x;
  const float* xr = x + row * EMBD;
  float v0 = xr[tid], v1 = xr[tid + 256];
  float s = v0 + v1, ss = v0 * v0 + v1 * v1;
  block_sum2(s, ss, red, tid);
  float mu = s * (1.f / EMBD);
  float var = ss * (1.f / EMBD) - mu * mu;
  float rs = rsqrtf(var + LNEPS);
  y[row * EMBD + tid]       = f2b((v0 - mu) * rs * w[tid]);
  y[row * EMBD + tid + 256] = f2b((v1 - mu) * rs * w[tid + 256]);
}

// ---------------------------------------------------------------------------
// weight transpose-cast: out[n][k] = bf16(in[k][n]); z batches
__global__ __launch_bounds__(256) void castT_kernel(
    const float* __restrict__ in, unsigned short* __restrict__ out, int K, int N) {
  __shared__ float t[32][33];
  long zoff = (long)blockIdx.z * K * N;
  in += zoff; out += zoff;
  int n0 = blockIdx.x * 32, k0 = blockIdx.y * 32;
  int tx = threadIdx.x & 31, ty = threadIdx.x >> 5;   // ty 0..7
#pragma unroll
  for (int i = 0; i < 32; i += 8)
    t[ty + i][tx] = in[(long)(k0 + ty + i) * N + n0 + tx];
  __syncthreads();
#pragma unroll
  for (int i = 0; i < 32; i += 8)
    out[(long)(n0 + ty + i) * K + k0 + tx] = f2b(t[tx][ty + i]);
}

__global__ __launch_bounds__(256) void castflat_kernel(
    const float* __restrict__ in, unsigned short* __restrict__ out) {
  long i = (long)blockIdx.x * 256 + threadIdx.x;
  out[i] = f2b(in[i]);
}

// ---------------------------------------------------------------------------
// bf16 MFMA GEMM: C[m,n] = sum_k A[m,k] * Bt[n,k]; 128x128 tile, 4 waves.
// MODE: 1 = f32 accumulate, 2 = bf16 store, 3 = bf16 store + transposed copy CT
//       (CT layout [b][z][col][row&511] for the v-projection, b = row>>9)
template <int MODE>
__global__ __launch_bounds__(256) void gemm_mfma(
    const unsigned short* __restrict__ A, int lda, long aOffZ,
    const unsigned short* __restrict__ B, int ldb, long bOffZ,
    void* __restrict__ Cv, int ldc, long cOffZ,
    unsigned short* __restrict__ CT, int K) {
  int z = blockIdx.z;
  A += (long)z * aOffZ;
  B += (long)z * bOffZ;
  __shared__ unsigned short As[128][72];   // 144B row stride: 16B-aligned, ~2-way reads
  __shared__ unsigned short Bs[128][72];
  int tid = threadIdx.x;
  int lane = tid & 63, w = tid >> 6;
  int l15 = lane & 15, l4 = lane >> 4;
  int wr = w >> 1, wc = w & 1;
  int m0 = blockIdx.y * 128, n0 = blockIdx.x * 128;
  f32x4 acc[4][4];
#pragma unroll
  for (int i = 0; i < 4; ++i)
#pragma unroll
    for (int j = 0; j < 4; ++j) acc[i][j] = (f32x4){0.f, 0.f, 0.f, 0.f};

  for (int k0 = 0; k0 < K; k0 += 32) {
    __syncthreads();
#pragma unroll
    for (int L = 0; L < 2; ++L) {
      int lidx = L * 256 + tid;
      int r = lidx >> 2, kq = (lidx & 3) * 8;
      *(bf16x8*)(&As[r][kq]) = *(const bf16x8*)(A + (long)(m0 + r) * lda + k0 + kq);
      *(bf16x8*)(&Bs[r][kq]) = *(const bf16x8*)(B + (long)(n0 + r) * ldb + k0 + kq);
    }
    __syncthreads();
    bf16x8 af[4], bfr[4];
#pragma unroll
    for (int i = 0; i < 4; ++i)
      af[i] = *(const bf16x8*)(&As[wr * 64 + i * 16 + l15][l4 * 8]);
#pragma unroll
    for (int j = 0; j < 4; ++j)
      bfr[j] = *(const bf16x8*)(&Bs[wc * 64 + j * 16 + l15][l4 * 8]);
#pragma unroll
    for (int i = 0; i < 4; ++i)
#pragma unroll
      for (int j = 0; j < 4; ++j)
        acc[i][j] = __builtin_amdgcn_mfma_f32_16x16x32_bf16(af[i], bfr[j], acc[i][j], 0, 0, 0);
  }

#pragma unroll
  for (int i = 0; i < 4; ++i) {
#pragma unroll
    for (int j = 0; j < 4; ++j) {
      int col = n0 + wc * 64 + j * 16 + l15;
#pragma unroll
      for (int r = 0; r < 4; ++r) {
        int m = m0 + wr * 64 + i * 16 + l4 * 4 + r;
        float val = acc[i][j][r];
        if (MODE == 1) {
          float* C = (float*)Cv + (long)z * cOffZ;
          C[(long)m * ldc + col] += val;
        } else {
          unsigned short* C = (unsigned short*)Cv + (long)z * cOffZ;
          unsigned short bv = f2b(val);
          C[(long)m * ldc + col] = bv;
          if (MODE == 3) {
            long ct = (((long)(m >> 9) * NHEAD + z) * DHEAD + col) * SEQ + (m & (SEQ - 1));
            CT[ct] = bv;
          }
        }
      }
    }
  }
}

// ---------------------------------------------------------------------------
// causal depthwise conv (K=4) over xm = up_b[:, :1024] (bf16) + bias, silu -> bf16
__global__ __launch_bounds__(256) void conv_silu_kernel(
    const unsigned short* __restrict__ upb, const float* __restrict__ w,
    const float* __restrict__ bias, unsigned short* __restrict__ xcb) {
  long idx = (long)blockIdx.x * 256 + threadIdx.x;  // RCH*INNER
  int c = (int)(idx & (INNERD - 1));
  long bs = idx >> 10;
  int s = (int)(bs & (SEQ - 1));
  long b = bs >> 9;
  float acc = bias[c];
#pragma unroll
  for (int kk = 0; kk < 4; ++kk) {
    int t = s + kk - 3;
    if (t >= 0) acc += w[kk * INNERD + c] * b2f(upb[((b << 9) + t) * (2 * INNERD) + c]);
  }
  float sig = 1.f / (1.f + __expf(-acc));
  xcb[bs * INNERD + c] = f2b(acc * sig);
}

// ---------------------------------------------------------------------------
// gate projections from bf16 q/k/v rows
__global__ __launch_bounds__(256) void gates_kernel(
    const unsigned short* __restrict__ qh, const unsigned short* __restrict__ kh,
    const unsigned short* __restrict__ vh,
    const float* __restrict__ Wi, const float* __restrict__ bi,
    const float* __restrict__ Wf, const float* __restrict__ bf,
    float* __restrict__ ip, float* __restrict__ fp) {
  __shared__ float red[4][8];
  long bs = blockIdx.x;
  int tid = threadIdx.x;
  int lane = tid & 63, wid = tid >> 6;
  float pi[4] = {}, pf[4] = {};
  const unsigned short* qr = qh + bs * INNERD;
  const unsigned short* kr = kh + bs * INNERD;
  const unsigned short* vr = vh + bs * INNERD;
  for (int j = tid; j < INNERD; j += 256) {
    float xq = b2f(qr[j]), xk = b2f(kr[j]), xv = b2f(vr[j]);
    const float* wiq = Wi + (long)j * NHEAD;
    const float* wik = Wi + (long)(j + INNERD) * NHEAD;
    const float* wiv = Wi + (long)(j + 2 * INNERD) * NHEAD;
    const float* wfq = Wf + (long)j * NHEAD;
    const float* wfk = Wf + (long)(j + INNERD) * NHEAD;
    const float* wfv = Wf + (long)(j + 2 * INNERD) * NHEAD;
#pragma unroll
    for (int n = 0; n < NHEAD; ++n) {
      pi[n] += xq * wiq[n] + xk * wik[n] + xv * wiv[n];
      pf[n] += xq * wfq[n] + xk * wfk[n] + xv * wfv[n];
    }
  }
#pragma unroll
  for (int n = 0; n < NHEAD; ++n) {
#pragma unroll
    for (int o = 1; o < 64; o <<= 1) {
      pi[n] += __shfl_xor(pi[n], o);
      pf[n] += __shfl_xor(pf[n], o);
    }
  }
  if (lane == 0) {
#pragma unroll
    for (int n = 0; n < NHEAD; ++n) { red[wid][n] = pi[n]; red[wid][4 + n] = pf[n]; }
  }
  __syncthreads();
  if (tid == 0) {
    long b = bs >> 9;
    int s = (int)(bs & (SEQ - 1));
#pragma unroll
    for (int n = 0; n < NHEAD; ++n) {
      float a = red[0][n] + red[1][n] + red[2][n] + red[3][n] + bi[n];
      float c = red[0][4 + n] + red[1][4 + n] + red[2][4 + n] + red[3][4 + n] + bf[n];
      ip[(b * NHEAD + n) * SEQ + s] = a;
      fp[(b * NHEAD + n) * SEQ + s] = c;
    }
  }
}

// ---------------------------------------------------------------------------
// parallel gate scan: F = cumsum(logsig(f)); Bc = F - i; mrow = F + runmax(i - F)
__global__ __launch_bounds__(64) void fgate_kernel(
    const float* __restrict__ fp, const float* __restrict__ ip,
    float* __restrict__ F, float* __restrict__ Bc, float* __restrict__ mrow) {
  int bh = blockIdx.x;
  int lane = threadIdx.x;
  const float* fr = fp + (long)bh * SEQ;
  const float* ir = ip + (long)bh * SEQ;
  float v[8]; float run = 0.f;
#pragma unroll
  for (int i = 0; i < 8; ++i) {
    float x = fr[lane * 8 + i];
    float ls = fminf(x, 0.f) - log1pf(__expf(-fabsf(x)));
    run += ls; v[i] = run;
  }
  float tot = run, scan = run;
#pragma unroll
  for (int off = 1; off < 64; off <<= 1) {
    float n = __shfl_up(scan, off);
    if (lane >= off) scan += n;
  }
  float excl = scan - tot;
  float Fv[8];
#pragma unroll
  for (int i = 0; i < 8; ++i) {
    Fv[i] = excl + v[i];
    F[(long)bh * SEQ + lane * 8 + i] = Fv[i];
  }
  float g[8], pmv[8]; float pm = -INFINITY;
#pragma unroll
  for (int i = 0; i < 8; ++i) {
    g[i] = ir[lane * 8 + i] - Fv[i];
    Bc[(long)bh * SEQ + lane * 8 + i] = -g[i];
    pm = fmaxf(pm, g[i]); pmv[i] = pm;
  }
  float mx = pm;
#pragma unroll
  for (int off = 1; off < 64; off <<= 1) {
    float n = __shfl_up(mx, off);
    if (lane >= off) mx = fmaxf(mx, n);
  }
  float ex = __shfl_up(mx, 1);
  if (lane == 0) ex = -INFINITY;
#pragma unroll
  for (int i = 0; i < 8; ++i) {
    float inc = fmaxf(ex, pmv[i]);
    mrow[(long)bh * SEQ + lane * 8 + i] = Fv[i] + inc;
  }
}

// ---------------------------------------------------------------------------
// flash mLSTM cell + fused head-norm/skip/silu(z). Block=(qt,h,b) b chunk-local;
// 4 waves; K/V tiles LDS-staged cooperatively (shared by all 4 waves).
// LDS: Ks 33.8KB + Vs 36.9KB + P 9.2KB = 79.9KB -> 2 blocks/CU.
__global__ __launch_bounds__(256) void cell_kernel(
    const unsigned short* __restrict__ qb, const unsigned short* __restrict__ kb,
    const unsigned short* __restrict__ vbT,
    const float* __restrict__ F, const float* __restrict__ Bc,
    const float* __restrict__ mrow,
    const unsigned short* __restrict__ upb,
    const float* __restrict__ onw, const float* __restrict__ skw,
    unsigned short* __restrict__ xcb) {
  int qt = blockIdx.x, h = blockIdx.y, b = blockIdx.z;
  int tid = threadIdx.x, lane = tid & 63, w = tid >> 6;
  int l15 = lane & 15, l4 = lane >> 4;
  __shared__ unsigned short Ks[64][264];   // row stride 528B = 132 dw == 4 mod 32 -> 2-way
  __shared__ unsigned short Vs[256][72];   // row stride 144B = 36 dw == 4 mod 32 -> 2-way
  __shared__ unsigned short P[64][72];
  int bh = b * NHEAD + h;
  const float* Fr = F + (long)bh * SEQ;
  const float* Br = Bc + (long)bh * SEQ;
  const float* Mr = mrow + (long)bh * SEQ;
  int s0 = qt * 64 + w * 16;
  long bs0 = (long)b * SEQ;
  int sr[4]; float Ar[4], Mv[4];
#pragma unroll
  for (int r = 0; r < 4; ++r) {
    sr[r] = s0 + l4 * 4 + r;
    float fs = Fr[sr[r]];
    Mv[r] = Mr[sr[r]];
    Ar[r] = fs - Mv[r];
  }
  bf16x8 qf[8];
  const unsigned short* qp = qb + (bs0 + s0 + l15) * INNERD + h * DHEAD + l4 * 8;
#pragma unroll
  for (int kk = 0; kk < 8; ++kk) qf[kk] = *(const bf16x8*)(qp + kk * 32);
  f32x4 o[16];
#pragma unroll
  for (int i = 0; i < 16; ++i) o[i] = (f32x4){0.f, 0.f, 0.f, 0.f};
  float rs[4] = {0.f, 0.f, 0.f, 0.f};

  for (int tt = 0; tt <= qt; ++tt) {
    int t0 = tt * 64;
    __syncthreads();                        // protect previous iter's LDS reads
    // stage K tile: 64 rows x 256 cols, coalesced (512B runs)
    const unsigned short* ksrc = kb + (bs0 + t0) * INNERD + h * DHEAD;
#pragma unroll
    for (int i = 0; i < 8; ++i) {
      int idx = tid + i * 256;              // 0..2047
      int r = idx >> 5, ch = idx & 31;
      *(bf16x8*)(&Ks[r][ch * 8]) = *(const bf16x8*)(ksrc + (long)r * INNERD + ch * 8);
    }
    // stage V tile (transposed layout [d][t]): 256 rows x 64 cols (128B runs)
    const unsigned short* vsrc = vbT + ((long)bh * DHEAD) * SEQ + t0;
#pragma unroll
    for (int i = 0; i < 8; ++i) {
      int idx = tid + i * 256;
      int d = idx >> 3, ch = idx & 7;
      *(bf16x8*)(&Vs[d][ch * 8]) = *(const bf16x8*)(vsrc + (long)d * SEQ + ch * 8);
    }
    __syncthreads();
    bool diag = (tt == qt);
#pragma unroll
    for (int tf = 0; tf < 4; ++tf) {
      f32x4 s = (f32x4){0.f, 0.f, 0.f, 0.f};
#pragma unroll
      for (int kk = 0; kk < 8; ++kk) {
        bf16x8 kf = *(const bf16x8*)(&Ks[tf * 16 + l15][kk * 32 + l4 * 8]);
        s = __builtin_amdgcn_mfma_f32_16x16x32_bf16(qf[kk], kf, s, 0, 0, 0);
      }
      int tcol = t0 + tf * 16 + l15;
      float bc = Br[tcol];
#pragma unroll
      for (int r = 0; r < 4; ++r) {
        float p = s[r] * 0.0625f * __expf(Ar[r] - bc);
        if (diag && tcol > sr[r]) p = 0.f;
        rs[r] += p;
        P[w * 16 + l4 * 4 + r][tf * 16 + l15] = f2b(p);
      }
    }
#pragma unroll
    for (int ks = 0; ks < 2; ++ks) {
      bf16x8 pa = *(const bf16x8*)(&P[w * 16 + l15][ks * 32 + l4 * 8]);
#pragma unroll
      for (int df = 0; df < 16; ++df) {
        bf16x8 vf = *(const bf16x8*)(&Vs[df * 16 + l15][ks * 32 + l4 * 8]);
        o[df] = __builtin_amdgcn_mfma_f32_16x16x32_bf16(pa, vf, o[df], 0, 0, 0);
      }
    }
  }
  // rowsum across the 16-lane group
#pragma unroll
  for (int r = 0; r < 4; ++r)
#pragma unroll
    for (int off = 1; off < 16; off <<= 1) rs[r] += __shfl_xor(rs[r], off);
  float inv[4];
#pragma unroll
  for (int r = 0; r < 4; ++r) {
    float denom = fmaxf(fabsf(rs[r]), __expf(-Mv[r])) + 1e-6f;
    inv[r] = 1.f / denom;
  }
#pragma unroll
  for (int df = 0; df < 16; ++df)
#pragma unroll
    for (int r = 0; r < 4; ++r) o[df][r] *= inv[r];
  // fused head-LN over d=256
  float sm[4] = {}, sq[4] = {};
#pragma unroll
  for (int df = 0; df < 16; ++df)
#pragma unroll
    for (int r = 0; r < 4; ++r) { float x = o[df][r]; sm[r] += x; sq[r] += x * x; }
#pragma unroll
  for (int r = 0; r < 4; ++r)
#pragma unroll
    for (int off = 1; off < 16; off <<= 1) {
      sm[r] += __shfl_xor(sm[r], off);
      sq[r] += __shfl_xor(sq[r], off);
    }
  float mu[4], rstd[4];
#pragma unroll
  for (int r = 0; r < 4; ++r) {
    mu[r] = sm[r] * (1.f / DHEAD);
    float var = sq[r] * (1.f / DHEAD) - mu[r] * mu[r];
    rstd[r] = rsqrtf(var + LNEPS);
  }
#pragma unroll
  for (int df = 0; df < 16; ++df) {
    int c = h * DHEAD + df * 16 + l15;
    float ow = onw[c], sw = skw[c];
#pragma unroll
    for (int r = 0; r < 4; ++r) {
      long grow = bs0 + sr[r];
      float z = b2f(upb[grow * (2 * INNERD) + INNERD + c]);
      float sig = 1.f / (1.f + __expf(-z));
      float xcv = b2f(xcb[grow * INNERD + c]);   // in-place: read pre-value
      float y = (o[df][r] - mu[r]) * rstd[r];
      float g = (y * ow + sw * xcv) * (z * sig);
      xcb[grow * INNERD + c] = f2b(g);
    }
  }
}

// ---------------------------------------------------------------------------
__global__ __launch_bounds__(256) void final_kernel(
    const float* __restrict__ h, const float* __restrict__ pw,
    const float* __restrict__ ow, const float* __restrict__ ob,
    const float* __restrict__ Wh, const float* __restrict__ bh,
    float* __restrict__ out) {
  __shared__ float red[8];
  __shared__ float sh[EMBD];
  int b = blockIdx.x, tid = threadIdx.x;
  const float* xr = h + ((long)b * SEQ + (SEQ - 1)) * EMBD;
  float v0 = xr[tid], v1 = xr[tid + 256];
  float s = v0 + v1, ss = v0 * v0 + v1 * v1;
  block_sum2(s, ss, red, tid);
  float mu = s * (1.f / EMBD), var = ss * (1.f / EMBD) - mu * mu;
  float rs = rsqrtf(var + LNEPS);
  float y0 = (v0 - mu) * rs * pw[tid];
  float y1 = (v1 - mu) * rs * pw[tid + 256];
  float s2 = y0 + y1, ss2 = y0 * y0 + y1 * y1;
  block_sum2(s2, ss2, red, tid);
  float mu2 = s2 * (1.f / EMBD), var2 = ss2 * (1.f / EMBD) - mu2 * mu2;
  float rs2 = rsqrtf(var2 + LNEPS);
  sh[tid]       = (y0 - mu2) * rs2 * ow[tid] + ob[tid];
  sh[tid + 256] = (y1 - mu2) * rs2 * ow[tid + 256] + ob[tid + 256];
  __syncthreads();
  if (tid < OUTD) {
    float acc = bh[tid];
    for (int e = 0; e < EMBD; ++e) acc += sh[e] * Wh[e * OUTD + tid];
    out[b * OUTD + tid] = acc;
  }
}

// ---------------------------------------------------------------------------
extern "C" void kernel_launch(void* const* d_in, const int* in_sizes, int n_in,
                              void* d_out, int out_size, void* d_ws, size_t ws_size,
                              hipStream_t stream) {
  const float* inputs    = (const float*)d_in[0];
  const float* W_in      = (const float*)d_in[1];
  const float* ln_w      = (const float*)d_in[2];
  const float* W_up      = (const float*)d_in[3];
  const float* conv_w    = (const float*)d_in[4];
  const float* conv_b    = (const float*)d_in[5];
  const float* Wq        = (const float*)d_in[6];
  const float* Wk        = (const float*)d_in[7];
  const float* Wv        = (const float*)d_in[8];
  const float* W_i       = (const float*)d_in[9];
  const float* b_i       = (const float*)d_in[10];
  const float* W_f       = (const float*)d_in[11];
  const float* b_f       = (const float*)d_in[12];
  const float* skipw     = (const float*)d_in[13];
  const float* onorm_w   = (const float*)d_in[14];
  const float* W_down    = (const float*)d_in[15];
  const float* post_ln_w = (const float*)d_in[16];
  const float* out_ln_w  = (const float*)d_in[17];
  const float* out_ln_b  = (const float*)d_in[18];
  const float* W_head    = (const float*)d_in[19];
  const float* b_head    = (const float*)d_in[20];
  float* out = (float*)d_out;

  const long ROWS = (long)BATCH * SEQ;   // 8192
  // ---- workspace layout (~96 MB; chunked activations, CB=8) ----
  float* fpool = (float*)d_ws;
  float* h    = fpool; fpool += ROWS * EMBD;            // 16.8 MB (persistent)
  float* ipb  = fpool; fpool += (long)CB * NHEAD * SEQ;
  float* fpb  = fpool; fpool += (long)CB * NHEAD * SEQ;
  float* Fc   = fpool; fpool += (long)CB * NHEAD * SEQ;
  float* Bcc  = fpool; fpool += (long)CB * NHEAD * SEQ;
  float* mrw  = fpool; fpool += (long)CB * NHEAD * SEQ;
  unsigned short* upool = (unsigned short*)fpool;
  unsigned short* xn    = upool; upool += (long)RCH * EMBD;        //  4.2 MB
  unsigned short* upb   = upool; upool += (long)RCH * 2 * INNERD;  // 16.8 MB
  unsigned short* xcb   = upool; upool += (long)RCH * INNERD;      //  8.4 MB
  unsigned short* qbuf  = upool; upool += (long)RCH * INNERD;
  unsigned short* kbuf  = upool; upool += (long)RCH * INNERD;
  unsigned short* vbuf  = upool; upool += (long)RCH * INNERD;
  unsigned short* vbT   = upool; upool += (long)CB * NHEAD * DHEAD * SEQ;
  unsigned short* WupT  = upool; upool += (long)NBLK * 2 * INNERD * EMBD;
  unsigned short* WdnT  = upool; upool += (long)NBLK * EMBD * INNERD;
  unsigned short* Wqb   = upool; upool += (long)NBLK * NHEAD * DHEAD * DHEAD;
  unsigned short* Wkb   = upool; upool += (long)NBLK * NHEAD * DHEAD * DHEAD;
  unsigned short* Wvb   = upool; upool += (long)NBLK * NHEAD * DHEAD * DHEAD;

  // ---- weight prep (same work every call) ----
  castT_kernel<<<dim3(2 * INNERD / 32, EMBD / 32, NBLK), 256, 0, stream>>>(
      W_up, WupT, EMBD, 2 * INNERD);
  castT_kernel<<<dim3(EMBD / 32, INNERD / 32, NBLK), 256, 0, stream>>>(
      W_down, WdnT, INNERD, EMBD);
  const int WQN = NBLK * NHEAD * DHEAD * DHEAD;
  castflat_kernel<<<WQN / 256, 256, 0, stream>>>(Wq, Wqb);
  castflat_kernel<<<WQN / 256, 256, 0, stream>>>(Wk, Wkb);
  castflat_kernel<<<WQN / 256, 256, 0, stream>>>(Wv, Wvb);

  inproj_kernel<<<(ROWS * EMBD) / 256, 256, 0, stream>>>(inputs, W_in, h);

  for (int bl = 0; bl < NBLK; ++bl) {
    const float* lnw  = ln_w    + (long)bl * EMBD;
    const float* cwb  = conv_w  + (long)bl * 4 * INNERD;
    const float* cbb  = conv_b  + (long)bl * INNERD;
    const float* Wib  = W_i     + (long)bl * GATES * NHEAD;
    const float* bib  = b_i     + (long)bl * NHEAD;
    const float* Wfb  = W_f     + (long)bl * GATES * NHEAD;
    const float* bfb  = b_f     + (long)bl * NHEAD;
    const float* skb  = skipw   + (long)bl * INNERD;
    const float* onw  = onorm_w + (long)bl * INNERD;
    const unsigned short* WupTb = WupT + (long)bl * 2 * INNERD * EMBD;
    const unsigned short* WdnTb = WdnT + (long)bl * EMBD * INNERD;
    const unsigned short* Wqbb  = Wqb + (long)bl * NHEAD * DHEAD * DHEAD;
    const unsigned short* Wkbb  = Wkb + (long)bl * NHEAD * DHEAD * DHEAD;
    const unsigned short* Wvbb  = Wvb + (long)bl * NHEAD * DHEAD * DHEAD;

    for (int b0 = 0; b0 < BATCH; b0 += CB) {
      float* hch = h + (long)b0 * SEQ * EMBD;

      ln_mul_kernel<<<RCH, 256, 0, stream>>>(hch, lnw, xn);

      // up: [4096x512] @ [512x2048] -> bf16 up_b   (512 blocks)
      gemm_mfma<2><<<dim3(2 * INNERD / 128, RCH / 128, 1), 256, 0, stream>>>(
          xn, EMBD, 0, WupTb, EMBD, 0, upb, 2 * INNERD, 0, nullptr, EMBD);

      conv_silu_kernel<<<((long)RCH * INNERD) / 256, 256, 0, stream>>>(
          upb, cwb, cbb, xcb);

      // q,k from xcb; v from xm (= up_b cols 0..1023), + transposed copy vbT
      gemm_mfma<2><<<dim3(2, RCH / 128, NHEAD), 256, 0, stream>>>(
          xcb, INNERD, DHEAD, Wqbb, DHEAD, (long)DHEAD * DHEAD,
          qbuf, INNERD, DHEAD, nullptr, DHEAD);
      gemm_mfma<2><<<dim3(2, RCH / 128, NHEAD), 256, 0, stream>>>(
          xcb, INNERD, DHEAD, Wkbb, DHEAD, (long)DHEAD * DHEAD,
          kbuf, INNERD, DHEAD, nullptr, DHEAD);
      gemm_mfma<3><<<dim3(2, RCH / 128, NHEAD), 256, 0, stream>>>(
          upb, 2 * INNERD, DHEAD, Wvbb, DHEAD, (long)DHEAD * DHEAD,
          vbuf, INNERD, DHEAD, vbT, DHEAD);

      gates_kernel<<<RCH, 256, 0, stream>>>(qbuf, kbuf, vbuf, Wib, bib, Wfb, bfb, ipb, fpb);
      fgate_kernel<<<CB * NHEAD, 64, 0, stream>>>(fpb, ipb, Fc, Bcc, mrw);

      cell_kernel<<<dim3(SEQ / 64, NHEAD, CB), 256, 0, stream>>>(
          qbuf, kbuf, vbT, Fc, Bcc, mrw, upb, onw, skb, xcb);

      // down: hch += [4096x1024] @ [1024x512]   (128 blocks)
      gemm_mfma<1><<<dim3(EMBD / 128, RCH / 128, 1), 256, 0, stream>>>(
          xcb, INNERD, 0, WdnTb, INNERD, 0, hch, EMBD, 0, nullptr, INNERD);
    }
  }

  final_kernel<<<BATCH, 256, 0, stream>>>(h, post_ln_w, out_ln_w, out_ln_b,
                                          W_head, b_head, out);
}

// Round 9
// 800.651 us; speedup vs baseline: 7.6978x; 1.2018x over previous
//
#include <hip/hip_runtime.h>
#include <hip/hip_bf16.h>

#define BATCH  16
#define SEQ    512
#define IND    32
#define OUTD   32
#define EMBD   512
#define NBLK   2
#define NHEAD  4
#define INNERD 1024   // 2*EMB
#define DHEAD  256    // INNER/NH
#define GATES  3072   // 3*INNER
#define LNEPS  1e-5f

#define CB     8                  // batches per chunk (workspace ~96 MB total)
#define RCH    (CB * SEQ)         // rows per chunk = 4096

typedef __attribute__((ext_vector_type(8))) short bf16x8;   // 8 bf16 in 4 VGPRs
typedef __attribute__((ext_vector_type(4))) float f32x4;

__device__ __forceinline__ float b2f(unsigned short u) {
  union { unsigned int i; float f; } v; v.i = ((unsigned int)u) << 16; return v.f;
}
__device__ __forceinline__ unsigned short f2b(float f) {
  __hip_bfloat16 h = __float2bfloat16(f);           // round-to-nearest
  unsigned short u; __builtin_memcpy(&u, &h, 2); return u;
}

// ---------------------------------------------------------------------------
__device__ __forceinline__ void block_sum2(float& a, float& b, float* red, int tid) {
#pragma unroll
  for (int o = 1; o < 64; o <<= 1) { a += __shfl_xor(a, o); b += __shfl_xor(b, o); }
  int wid = tid >> 6;
  if ((tid & 63) == 0) { red[wid] = a; red[4 + wid] = b; }
  __syncthreads();
  a = red[0] + red[1] + red[2] + red[3];
  b = red[4] + red[5] + red[6] + red[7];
  __syncthreads();
}

// ---------------------------------------------------------------------------
__global__ __launch_bounds__(256) void inproj_kernel(
    const float* __restrict__ in, const float* __restrict__ Win,
    float* __restrict__ h) {
  long idx = (long)blockIdx.x * 256 + threadIdx.x;
  int  e   = (int)(idx & (EMBD - 1));
  long row = idx >> 9;
  const float* ir = in + row * IND;
  float acc = 0.f;
#pragma unroll
  for (int i = 0; i < IND; ++i) acc += ir[i] * Win[i * EMBD + e];
  h[idx] = acc;
}

// ---------------------------------------------------------------------------
// xn[row,:] = bf16( LN(x[row,:]) * w )
__global__ __launch_bounds__(256) void ln_mul_kernel(
    const float* __restrict__ x, const float* __restrict__ w,
    unsigned short* __restrict__ y) {
  __shared__ float red[8];
  long row = blockIdx.x;
  int tid = threadIdx.x;
  const float* xr = x + row * EMBD;
  float v0 = xr[tid], v1 = xr[tid + 256];
  float s = v0 + v1, ss = v0 * v0 + v1 * v1;
  block_sum2(s, ss, red, tid);
  float mu = s * (1.f / EMBD);
  float var = ss * (1.f / EMBD) - mu * mu;
  float rs = rsqrtf(var + LNEPS);
  y[row * EMBD + tid]       = f2b((v0 - mu) * rs * w[tid]);
  y[row * EMBD + tid + 256] = f2b((v1 - mu) * rs * w[tid + 256]);
}

// ---------------------------------------------------------------------------
// weight transpose-cast: out[n][k] = bf16(in[k][n]); z batches
__global__ __launch_bounds__(256) void castT_kernel(
    const float* __restrict__ in, unsigned short* __restrict__ out, int K, int N) {
  __shared__ float t[32][33];
  long zoff = (long)blockIdx.z * K * N;
  in += zoff; out += zoff;
  int n0 = blockIdx.x * 32, k0 = blockIdx.y * 32;
  int tx = threadIdx.x & 31, ty = threadIdx.x >> 5;   // ty 0..7
#pragma unroll
  for (int i = 0; i < 32; i += 8)
    t[ty + i][tx] = in[(long)(k0 + ty + i) * N + n0 + tx];
  __syncthreads();
#pragma unroll
  for (int i = 0; i < 32; i += 8)
    out[(long)(n0 + ty + i) * K + k0 + tx] = f2b(t[tx][ty + i]);
}

__global__ __launch_bounds__(256) void castflat_kernel(
    const float* __restrict__ in, unsigned short* __restrict__ out) {
  long i = (long)blockIdx.x * 256 + threadIdx.x;
  out[i] = f2b(in[i]);
}

// ---------------------------------------------------------------------------
// bf16 MFMA GEMM: C[m,n] = sum_k A[m,k] * Bt[n,k]; 128x128 tile, 4 waves.
// MODE: 1 = f32 accumulate, 2 = bf16 store, 3 = bf16 store + transposed copy CT
//       (CT layout [b][z][col][row&511] for the v-projection, b = row>>9)
template <int MODE>
__global__ __launch_bounds__(256) void gemm_mfma(
    const unsigned short* __restrict__ A, int lda, long aOffZ,
    const unsigned short* __restrict__ B, int ldb, long bOffZ,
    void* __restrict__ Cv, int ldc, long cOffZ,
    unsigned short* __restrict__ CT, int K) {
  int z = blockIdx.z;
  A += (long)z * aOffZ;
  B += (long)z * bOffZ;
  __shared__ unsigned short As[128][72];   // 144B row stride: 16B-aligned, ~2-way reads
  __shared__ unsigned short Bs[128][72];
  int tid = threadIdx.x;
  int lane = tid & 63, w = tid >> 6;
  int l15 = lane & 15, l4 = lane >> 4;
  int wr = w >> 1, wc = w & 1;
  int m0 = blockIdx.y * 128, n0 = blockIdx.x * 128;
  f32x4 acc[4][4];
#pragma unroll
  for (int i = 0; i < 4; ++i)
#pragma unroll
    for (int j = 0; j < 4; ++j) acc[i][j] = (f32x4){0.f, 0.f, 0.f, 0.f};

  for (int k0 = 0; k0 < K; k0 += 32) {
    __syncthreads();
#pragma unroll
    for (int L = 0; L < 2; ++L) {
      int lidx = L * 256 + tid;
      int r = lidx >> 2, kq = (lidx & 3) * 8;
      *(bf16x8*)(&As[r][kq]) = *(const bf16x8*)(A + (long)(m0 + r) * lda + k0 + kq);
      *(bf16x8*)(&Bs[r][kq]) = *(const bf16x8*)(B + (long)(n0 + r) * ldb + k0 + kq);
    }
    __syncthreads();
    bf16x8 af[4], bfr[4];
#pragma unroll
    for (int i = 0; i < 4; ++i)
      af[i] = *(const bf16x8*)(&As[wr * 64 + i * 16 + l15][l4 * 8]);
#pragma unroll
    for (int j = 0; j < 4; ++j)
      bfr[j] = *(const bf16x8*)(&Bs[wc * 64 + j * 16 + l15][l4 * 8]);
#pragma unroll
    for (int i = 0; i < 4; ++i)
#pragma unroll
      for (int j = 0; j < 4; ++j)
        acc[i][j] = __builtin_amdgcn_mfma_f32_16x16x32_bf16(af[i], bfr[j], acc[i][j], 0, 0, 0);
  }

#pragma unroll
  for (int i = 0; i < 4; ++i) {
#pragma unroll
    for (int j = 0; j < 4; ++j) {
      int col = n0 + wc * 64 + j * 16 + l15;
#pragma unroll
      for (int r = 0; r < 4; ++r) {
        int m = m0 + wr * 64 + i * 16 + l4 * 4 + r;
        float val = acc[i][j][r];
        if (MODE == 1) {
          float* C = (float*)Cv + (long)z * cOffZ;
          C[(long)m * ldc + col] += val;
        } else {
          unsigned short* C = (unsigned short*)Cv + (long)z * cOffZ;
          unsigned short bv = f2b(val);
          C[(long)m * ldc + col] = bv;
          if (MODE == 3) {
            long ct = (((long)(m >> 9) * NHEAD + z) * DHEAD + col) * SEQ + (m & (SEQ - 1));
            CT[ct] = bv;
          }
        }
      }
    }
  }
}

// ---------------------------------------------------------------------------
// causal depthwise conv (K=4) over xm = up_b[:, :1024] (bf16) + bias, silu -> bf16
__global__ __launch_bounds__(256) void conv_silu_kernel(
    const unsigned short* __restrict__ upb, const float* __restrict__ w,
    const float* __restrict__ bias, unsigned short* __restrict__ xcb) {
  long idx = (long)blockIdx.x * 256 + threadIdx.x;  // RCH*INNER
  int c = (int)(idx & (INNERD - 1));
  long bs = idx >> 10;
  int s = (int)(bs & (SEQ - 1));
  long b = bs >> 9;
  float acc = bias[c];
#pragma unroll
  for (int kk = 0; kk < 4; ++kk) {
    int t = s + kk - 3;
    if (t >= 0) acc += w[kk * INNERD + c] * b2f(upb[((b << 9) + t) * (2 * INNERD) + c]);
  }
  float sig = 1.f / (1.f + __expf(-acc));
  xcb[bs * INNERD + c] = f2b(acc * sig);
}

// ---------------------------------------------------------------------------
// gate projections from bf16 q/k/v rows
__global__ __launch_bounds__(256) void gates_kernel(
    const unsigned short* __restrict__ qh, const unsigned short* __restrict__ kh,
    const unsigned short* __restrict__ vh,
    const float* __restrict__ Wi, const float* __restrict__ bi,
    const float* __restrict__ Wf, const float* __restrict__ bf,
    float* __restrict__ ip, float* __restrict__ fp) {
  __shared__ float red[4][8];
  long bs = blockIdx.x;
  int tid = threadIdx.x;
  int lane = tid & 63, wid = tid >> 6;
  float pi[4] = {}, pf[4] = {};
  const unsigned short* qr = qh + bs * INNERD;
  const unsigned short* kr = kh + bs * INNERD;
  const unsigned short* vr = vh + bs * INNERD;
  for (int j = tid; j < INNERD; j += 256) {
    float xq = b2f(qr[j]), xk = b2f(kr[j]), xv = b2f(vr[j]);
    const float* wiq = Wi + (long)j * NHEAD;
    const float* wik = Wi + (long)(j + INNERD) * NHEAD;
    const float* wiv = Wi + (long)(j + 2 * INNERD) * NHEAD;
    const float* wfq = Wf + (long)j * NHEAD;
    const float* wfk = Wf + (long)(j + INNERD) * NHEAD;
    const float* wfv = Wf + (long)(j + 2 * INNERD) * NHEAD;
#pragma unroll
    for (int n = 0; n < NHEAD; ++n) {
      pi[n] += xq * wiq[n] + xk * wik[n] + xv * wiv[n];
      pf[n] += xq * wfq[n] + xk * wfk[n] + xv * wfv[n];
    }
  }
#pragma unroll
  for (int n = 0; n < NHEAD; ++n) {
#pragma unroll
    for (int o = 1; o < 64; o <<= 1) {
      pi[n] += __shfl_xor(pi[n], o);
      pf[n] += __shfl_xor(pf[n], o);
    }
  }
  if (lane == 0) {
#pragma unroll
    for (int n = 0; n < NHEAD; ++n) { red[wid][n] = pi[n]; red[wid][4 + n] = pf[n]; }
  }
  __syncthreads();
  if (tid == 0) {
    long b = bs >> 9;
    int s = (int)(bs & (SEQ - 1));
#pragma unroll
    for (int n = 0; n < NHEAD; ++n) {
      float a = red[0][n] + red[1][n] + red[2][n] + red[3][n] + bi[n];
      float c = red[0][4 + n] + red[1][4 + n] + red[2][4 + n] + red[3][4 + n] + bf[n];
      ip[(b * NHEAD + n) * SEQ + s] = a;
      fp[(b * NHEAD + n) * SEQ + s] = c;
    }
  }
}

// ---------------------------------------------------------------------------
// parallel gate scan: F = cumsum(logsig(f)); Bc = F - i; mrow = F + runmax(i - F)
__global__ __launch_bounds__(64) void fgate_kernel(
    const float* __restrict__ fp, const float* __restrict__ ip,
    float* __restrict__ F, float* __restrict__ Bc, float* __restrict__ mrow) {
  int bh = blockIdx.x;
  int lane = threadIdx.x;
  const float* fr = fp + (long)bh * SEQ;
  const float* ir = ip + (long)bh * SEQ;
  float v[8]; float run = 0.f;
#pragma unroll
  for (int i = 0; i < 8; ++i) {
    float x = fr[lane * 8 + i];
    float ls = fminf(x, 0.f) - log1pf(__expf(-fabsf(x)));
    run += ls; v[i] = run;
  }
  float tot = run, scan = run;
#pragma unroll
  for (int off = 1; off < 64; off <<= 1) {
    float n = __shfl_up(scan, off);
    if (lane >= off) scan += n;
  }
  float excl = scan - tot;
  float Fv[8];
#pragma unroll
  for (int i = 0; i < 8; ++i) {
    Fv[i] = excl + v[i];
    F[(long)bh * SEQ + lane * 8 + i] = Fv[i];
  }
  float g[8], pmv[8]; float pm = -INFINITY;
#pragma unroll
  for (int i = 0; i < 8; ++i) {
    g[i] = ir[lane * 8 + i] - Fv[i];
    Bc[(long)bh * SEQ + lane * 8 + i] = -g[i];
    pm = fmaxf(pm, g[i]); pmv[i] = pm;
  }
  float mx = pm;
#pragma unroll
  for (int off = 1; off < 64; off <<= 1) {
    float n = __shfl_up(mx, off);
    if (lane >= off) mx = fmaxf(mx, n);
  }
  float ex = __shfl_up(mx, 1);
  if (lane == 0) ex = -INFINITY;
#pragma unroll
  for (int i = 0; i < 8; ++i) {
    float inc = fmaxf(ex, pmv[i]);
    mrow[(long)bh * SEQ + lane * 8 + i] = Fv[i] + inc;
  }
}

// ---------------------------------------------------------------------------
// flash mLSTM cell + fused head-norm/skip/silu(z).
// Grid: x = h + NHEAD*b (so same-(h,b) q-blocks land on the SAME XCD ->
//       K/V become L2-resident), y = q-tile. Block = 512 threads (8 waves):
// wave w: rg = w&3 (16 q-rows), th = w>>2 (t-half for QK^T, d-half for PV).
// Async stage: tile tt+1's global loads issue into regs during tile tt compute.
__global__ __launch_bounds__(512) void cell_kernel(
    const unsigned short* __restrict__ qb, const unsigned short* __restrict__ kb,
    const unsigned short* __restrict__ vbT,
    const float* __restrict__ F, const float* __restrict__ Bc,
    const float* __restrict__ mrow,
    const unsigned short* __restrict__ upb,
    const float* __restrict__ onw, const float* __restrict__ skw,
    unsigned short* __restrict__ xcb) {
  int hb = blockIdx.x;
  int h = hb & (NHEAD - 1), b = hb >> 2;
  int qt = blockIdx.y;
  int tid = threadIdx.x, lane = tid & 63, w = tid >> 6;   // w 0..7
  int l15 = lane & 15, l4 = lane >> 4;
  int rg = w & 3, th = w >> 2;
  __shared__ unsigned short Ks[64][264];   // 528B row stride
  __shared__ unsigned short Vs[256][72];   // 144B row stride
  __shared__ unsigned short P[64][72];
  __shared__ float redx[2][4][16];         // [th][rg][row-in-group]
  __shared__ float redy[2][4][16][2];
  int bh = b * NHEAD + h;
  const float* Fr = F + (long)bh * SEQ;
  const float* Br = Bc + (long)bh * SEQ;
  const float* Mr = mrow + (long)bh * SEQ;
  int s0 = qt * 64;
  long bs0 = (long)b * SEQ;
  int sr[4]; float Ar[4], Mv[4];
#pragma unroll
  for (int r = 0; r < 4; ++r) {
    sr[r] = s0 + rg * 16 + l4 * 4 + r;
    float fs = Fr[sr[r]];
    Mv[r] = Mr[sr[r]];
    Ar[r] = fs - Mv[r];
  }
  bf16x8 qf[8];
  const unsigned short* qp = qb + (bs0 + s0 + rg * 16 + l15) * INNERD + h * DHEAD + l4 * 8;
#pragma unroll
  for (int kk = 0; kk < 8; ++kk) qf[kk] = *(const bf16x8*)(qp + kk * 32);
  f32x4 o[8];
#pragma unroll
  for (int i = 0; i < 8; ++i) o[i] = (f32x4){0.f, 0.f, 0.f, 0.f};
  float rs[4] = {0.f, 0.f, 0.f, 0.f};

  const unsigned short* kbase = kb + bs0 * INNERD + h * DHEAD;
  const unsigned short* vbase = vbT + (long)bh * DHEAD * SEQ;
  // per-thread staging slots (same every tile)
  int kR[4], kC[4], vD[4], vC[4];
#pragma unroll
  for (int i = 0; i < 4; ++i) {
    int idx = tid + i * 512;      // 0..2047
    kR[i] = idx >> 5; kC[i] = (idx & 31) * 8;
    vD[i] = idx >> 3; vC[i] = (idx & 7) * 8;
  }
  bf16x8 kreg[4], vreg[4];
  // prologue: load tile 0
#pragma unroll
  for (int i = 0; i < 4; ++i) {
    kreg[i] = *(const bf16x8*)(kbase + (long)kR[i] * INNERD + kC[i]);
    vreg[i] = *(const bf16x8*)(vbase + (long)vD[i] * SEQ + vC[i]);
  }

  int nt = qt + 1;
  for (int tt = 0; tt < nt; ++tt) {
    int t0 = tt * 64;
    __syncthreads();                     // previous tile's LDS reads done
#pragma unroll
    for (int i = 0; i < 4; ++i) {
      *(bf16x8*)(&Ks[kR[i]][kC[i]]) = kreg[i];
      *(bf16x8*)(&Vs[vD[i]][vC[i]]) = vreg[i];
    }
    __syncthreads();
    if (tt + 1 < nt) {                   // async: overlaps compute below
      int t1 = (tt + 1) * 64;
#pragma unroll
      for (int i = 0; i < 4; ++i) {
        kreg[i] = *(const bf16x8*)(kbase + (long)(t1 + kR[i]) * INNERD + kC[i]);
        vreg[i] = *(const bf16x8*)(vbase + (long)vD[i] * SEQ + t1 + vC[i]);
      }
    }
    bool diag = (tt == nt - 1);
    // QK^T on this wave's t-half (2 x 16-col frags)
#pragma unroll
    for (int tfl = 0; tfl < 2; ++tfl) {
      f32x4 s = (f32x4){0.f, 0.f, 0.f, 0.f};
#pragma unroll
      for (int kk = 0; kk < 8; ++kk) {
        bf16x8 kf = *(const bf16x8*)(&Ks[th * 32 + tfl * 16 + l15][kk * 32 + l4 * 8]);
        s = __builtin_amdgcn_mfma_f32_16x16x32_bf16(qf[kk], kf, s, 0, 0, 0);
      }
      int tcol = t0 + th * 32 + tfl * 16 + l15;
      float bc = Br[tcol];
#pragma unroll
      for (int r = 0; r < 4; ++r) {
        float p = s[r] * 0.0625f * __expf(Ar[r] - bc);
        if (diag && tcol > sr[r]) p = 0.f;
        rs[r] += p;
        P[rg * 16 + l4 * 4 + r][th * 32 + tfl * 16 + l15] = f2b(p);
      }
    }
    __syncthreads();                     // P complete (both t-halves)
    // PV on this wave's d-half (8 x 16-col frags)
#pragma unroll
    for (int ks = 0; ks < 2; ++ks) {
      bf16x8 pa = *(const bf16x8*)(&P[rg * 16 + l15][ks * 32 + l4 * 8]);
#pragma unroll
      for (int df = 0; df < 8; ++df) {
        bf16x8 vf = *(const bf16x8*)(&Vs[th * 128 + df * 16 + l15][ks * 32 + l4 * 8]);
        o[df] = __builtin_amdgcn_mfma_f32_16x16x32_bf16(pa, vf, o[df], 0, 0, 0);
      }
    }
  }
  // rowsum: reduce over this wave's 16 t-lanes, then across th via LDS
#pragma unroll
  for (int r = 0; r < 4; ++r)
#pragma unroll
    for (int off = 1; off < 16; off <<= 1) rs[r] += __shfl_xor(rs[r], off);
  if (l15 == 0) {
#pragma unroll
    for (int r = 0; r < 4; ++r) redx[th][rg][l4 * 4 + r] = rs[r];
  }
  __syncthreads();
  float inv[4];
#pragma unroll
  for (int r = 0; r < 4; ++r) {
    float tot = redx[0][rg][l4 * 4 + r] + redx[1][rg][l4 * 4 + r];
    float denom = fmaxf(fabsf(tot), __expf(-Mv[r])) + 1e-6f;
    inv[r] = 1.f / denom;
  }
#pragma unroll
  for (int df = 0; df < 8; ++df)
#pragma unroll
    for (int r = 0; r < 4; ++r) o[df][r] *= inv[r];
  // head-LN over d=256: partials over this wave's 128 cols, exchange across th
  float sm[4] = {}, sq[4] = {};
#pragma unroll
  for (int df = 0; df < 8; ++df)
#pragma unroll
    for (int r = 0; r < 4; ++r) { float x = o[df][r]; sm[r] += x; sq[r] += x * x; }
#pragma unroll
  for (int r = 0; r < 4; ++r)
#pragma unroll
    for (int off = 1; off < 16; off <<= 1) {
      sm[r] += __shfl_xor(sm[r], off);
      sq[r] += __shfl_xor(sq[r], off);
    }
  if (l15 == 0) {
#pragma unroll
    for (int r = 0; r < 4; ++r) {
      redy[th][rg][l4 * 4 + r][0] = sm[r];
      redy[th][rg][l4 * 4 + r][1] = sq[r];
    }
  }
  __syncthreads();
  float mu[4], rstd[4];
#pragma unroll
  for (int r = 0; r < 4; ++r) {
    float smt = redy[0][rg][l4 * 4 + r][0] + redy[1][rg][l4 * 4 + r][0];
    float sqt = redy[0][rg][l4 * 4 + r][1] + redy[1][rg][l4 * 4 + r][1];
    mu[r] = smt * (1.f / DHEAD);
    float var = sqt * (1.f / DHEAD) - mu[r] * mu[r];
    rstd[r] = rsqrtf(var + LNEPS);
  }
#pragma unroll
  for (int df = 0; df < 8; ++df) {
    int c = h * DHEAD + th * 128 + df * 16 + l15;
    float ow = onw[c], sw = skw[c];
#pragma unroll
    for (int r = 0; r < 4; ++r) {
      long grow = bs0 + sr[r];
      float z = b2f(upb[grow * (2 * INNERD) + INNERD + c]);
      float sig = 1.f / (1.f + __expf(-z));
      float xcv = b2f(xcb[grow * INNERD + c]);   // in-place: read pre-value
      float y = (o[df][r] - mu[r]) * rstd[r];
      float g = (y * ow + sw * xcv) * (z * sig);
      xcb[grow * INNERD + c] = f2b(g);
    }
  }
}

// ---------------------------------------------------------------------------
__global__ __launch_bounds__(256) void final_kernel(
    const float* __restrict__ h, const float* __restrict__ pw,
    const float* __restrict__ ow, const float* __restrict__ ob,
    const float* __restrict__ Wh, const float* __restrict__ bh,
    float* __restrict__ out) {
  __shared__ float red[8];
  __shared__ float sh[EMBD];
  int b = blockIdx.x, tid = threadIdx.x;
  const float* xr = h + ((long)b * SEQ + (SEQ - 1)) * EMBD;
  float v0 = xr[tid], v1 = xr[tid + 256];
  float s = v0 + v1, ss = v0 * v0 + v1 * v1;
  block_sum2(s, ss, red, tid);
  float mu = s * (1.f / EMBD), var = ss * (1.f / EMBD) - mu * mu;
  float rs = rsqrtf(var + LNEPS);
  float y0 = (v0 - mu) * rs * pw[tid];
  float y1 = (v1 - mu) * rs * pw[tid + 256];
  float s2 = y0 + y1, ss2 = y0 * y0 + y1 * y1;
  block_sum2(s2, ss2, red, tid);
  float mu2 = s2 * (1.f / EMBD), var2 = ss2 * (1.f / EMBD) - mu2 * mu2;
  float rs2 = rsqrtf(var2 + LNEPS);
  sh[tid]       = (y0 - mu2) * rs2 * ow[tid] + ob[tid];
  sh[tid + 256] = (y1 - mu2) * rs2 * ow[tid + 256] + ob[tid + 256];
  __syncthreads();
  if (tid < OUTD) {
    float acc = bh[tid];
    for (int e = 0; e < EMBD; ++e) acc += sh[e] * Wh[e * OUTD + tid];
    out[b * OUTD + tid] = acc;
  }
}

// ---------------------------------------------------------------------------
extern "C" void kernel_launch(void* const* d_in, const int* in_sizes, int n_in,
                              void* d_out, int out_size, void* d_ws, size_t ws_size,
                              hipStream_t stream) {
  const float* inputs    = (const float*)d_in[0];
  const float* W_in      = (const float*)d_in[1];
  const float* ln_w      = (const float*)d_in[2];
  const float* W_up      = (const float*)d_in[3];
  const float* conv_w    = (const float*)d_in[4];
  const float* conv_b    = (const float*)d_in[5];
  const float* Wq        = (const float*)d_in[6];
  const float* Wk        = (const float*)d_in[7];
  const float* Wv        = (const float*)d_in[8];
  const float* W_i       = (const float*)d_in[9];
  const float* b_i       = (const float*)d_in[10];
  const float* W_f       = (const float*)d_in[11];
  const float* b_f       = (const float*)d_in[12];
  const float* skipw     = (const float*)d_in[13];
  const float* onorm_w   = (const float*)d_in[14];
  const float* W_down    = (const float*)d_in[15];
  const float* post_ln_w = (const float*)d_in[16];
  const float* out_ln_w  = (const float*)d_in[17];
  const float* out_ln_b  = (const float*)d_in[18];
  const float* W_head    = (const float*)d_in[19];
  const float* b_head    = (const float*)d_in[20];
  float* out = (float*)d_out;

  const long ROWS = (long)BATCH * SEQ;   // 8192
  // ---- workspace layout (~96 MB; chunked activations, CB=8) ----
  float* fpool = (float*)d_ws;
  float* h    = fpool; fpool += ROWS * EMBD;            // 16.8 MB (persistent)
  float* ipb  = fpool; fpool += (long)CB * NHEAD * SEQ;
  float* fpb  = fpool; fpool += (long)CB * NHEAD * SEQ;
  float* Fc   = fpool; fpool += (long)CB * NHEAD * SEQ;
  float* Bcc  = fpool; fpool += (long)CB * NHEAD * SEQ;
  float* mrw  = fpool; fpool += (long)CB * NHEAD * SEQ;
  unsigned short* upool = (unsigned short*)fpool;
  unsigned short* xn    = upool; upool += (long)RCH * EMBD;        //  4.2 MB
  unsigned short* upb   = upool; upool += (long)RCH * 2 * INNERD;  // 16.8 MB
  unsigned short* xcb   = upool; upool += (long)RCH * INNERD;      //  8.4 MB
  unsigned short* qbuf  = upool; upool += (long)RCH * INNERD;
  unsigned short* kbuf  = upool; upool += (long)RCH * INNERD;
  unsigned short* vbuf  = upool; upool += (long)RCH * INNERD;
  unsigned short* vbT   = upool; upool += (long)CB * NHEAD * DHEAD * SEQ;
  unsigned short* WupT  = upool; upool += (long)NBLK * 2 * INNERD * EMBD;
  unsigned short* WdnT  = upool; upool += (long)NBLK * EMBD * INNERD;
  unsigned short* Wqb   = upool; upool += (long)NBLK * NHEAD * DHEAD * DHEAD;
  unsigned short* Wkb   = upool; upool += (long)NBLK * NHEAD * DHEAD * DHEAD;
  unsigned short* Wvb   = upool; upool += (long)NBLK * NHEAD * DHEAD * DHEAD;

  // ---- weight prep (same work every call) ----
  castT_kernel<<<dim3(2 * INNERD / 32, EMBD / 32, NBLK), 256, 0, stream>>>(
      W_up, WupT, EMBD, 2 * INNERD);
  castT_kernel<<<dim3(EMBD / 32, INNERD / 32, NBLK), 256, 0, stream>>>(
      W_down, WdnT, INNERD, EMBD);
  const int WQN = NBLK * NHEAD * DHEAD * DHEAD;
  castflat_kernel<<<WQN / 256, 256, 0, stream>>>(Wq, Wqb);
  castflat_kernel<<<WQN / 256, 256, 0, stream>>>(Wk, Wkb);
  castflat_kernel<<<WQN / 256, 256, 0, stream>>>(Wv, Wvb);

  inproj_kernel<<<(ROWS * EMBD) / 256, 256, 0, stream>>>(inputs, W_in, h);

  for (int bl = 0; bl < NBLK; ++bl) {
    const float* lnw  = ln_w    + (long)bl * EMBD;
    const float* cwb  = conv_w  + (long)bl * 4 * INNERD;
    const float* cbb  = conv_b  + (long)bl * INNERD;
    const float* Wib  = W_i     + (long)bl * GATES * NHEAD;
    const float* bib  = b_i     + (long)bl * NHEAD;
    const float* Wfb  = W_f     + (long)bl * GATES * NHEAD;
    const float* bfb  = b_f     + (long)bl * NHEAD;
    const float* skb  = skipw   + (long)bl * INNERD;
    const float* onw  = onorm_w + (long)bl * INNERD;
    const unsigned short* WupTb = WupT + (long)bl * 2 * INNERD * EMBD;
    const unsigned short* WdnTb = WdnT + (long)bl * EMBD * INNERD;
    const unsigned short* Wqbb  = Wqb + (long)bl * NHEAD * DHEAD * DHEAD;
    const unsigned short* Wkbb  = Wkb + (long)bl * NHEAD * DHEAD * DHEAD;
    const unsigned short* Wvbb  = Wvb + (long)bl * NHEAD * DHEAD * DHEAD;

    for (int b0 = 0; b0 < BATCH; b0 += CB) {
      float* hch = h + (long)b0 * SEQ * EMBD;

      ln_mul_kernel<<<RCH, 256, 0, stream>>>(hch, lnw, xn);

      // up: [4096x512] @ [512x2048] -> bf16 up_b   (512 blocks)
      gemm_mfma<2><<<dim3(2 * INNERD / 128, RCH / 128, 1), 256, 0, stream>>>(
          xn, EMBD, 0, WupTb, EMBD, 0, upb, 2 * INNERD, 0, nullptr, EMBD);

      conv_silu_kernel<<<((long)RCH * INNERD) / 256, 256, 0, stream>>>(
          upb, cwb, cbb, xcb);

      // q,k from xcb; v from xm (= up_b cols 0..1023), + transposed copy vbT
      gemm_mfma<2><<<dim3(2, RCH / 128, NHEAD), 256, 0, stream>>>(
          xcb, INNERD, DHEAD, Wqbb, DHEAD, (long)DHEAD * DHEAD,
          qbuf, INNERD, DHEAD, nullptr, DHEAD);
      gemm_mfma<2><<<dim3(2, RCH / 128, NHEAD), 256, 0, stream>>>(
          xcb, INNERD, DHEAD, Wkbb, DHEAD, (long)DHEAD * DHEAD,
          kbuf, INNERD, DHEAD, nullptr, DHEAD);
      gemm_mfma<3><<<dim3(2, RCH / 128, NHEAD), 256, 0, stream>>>(
          upb, 2 * INNERD, DHEAD, Wvbb, DHEAD, (long)DHEAD * DHEAD,
          vbuf, INNERD, DHEAD, vbT, DHEAD);

      gates_kernel<<<RCH, 256, 0, stream>>>(qbuf, kbuf, vbuf, Wib, bib, Wfb, bfb, ipb, fpb);
      fgate_kernel<<<CB * NHEAD, 64, 0, stream>>>(fpb, ipb, Fc, Bcc, mrw);

      // x = hb (same-(h,b) blocks -> same XCD), y = q-tile; 512 threads
      cell_kernel<<<dim3(NHEAD * CB, SEQ / 64, 1), 512, 0, stream>>>(
          qbuf, kbuf, vbT, Fc, Bcc, mrw, upb, onw, skb, xcb);

      // down: hch += [4096x1024] @ [1024x512]   (128 blocks)
      gemm_mfma<1><<<dim3(EMBD / 128, RCH / 128, 1), 256, 0, stream>>>(
          xcb, INNERD, 0, WdnTb, INNERD, 0, hch, EMBD, 0, nullptr, INNERD);
    }
  }

  final_kernel<<<BATCH, 256, 0, stream>>>(h, post_ln_w, out_ln_w, out_ln_b,
                                          W_head, b_head, out);
}

// Round 10
// 624.602 us; speedup vs baseline: 9.8675x; 1.2819x over previous
//
#include <hip/hip_runtime.h>
#include <hip/hip_bf16.h>

#define BATCH  16
#define SEQ    512
#define IND    32
#define OUTD   32
#define EMBD   512
#define NBLK   2
#define NHEAD  4
#define INNERD 1024   // 2*EMB
#define DHEAD  256    // INNER/NH
#define GATES  3072   // 3*INNER
#define LNEPS  1e-5f

typedef __attribute__((ext_vector_type(8))) short bf16x8;   // 8 bf16 in 4 VGPRs
typedef __attribute__((ext_vector_type(4))) float f32x4;

__device__ __forceinline__ float b2f(unsigned short u) {
  union { unsigned int i; float f; } v; v.i = ((unsigned int)u) << 16; return v.f;
}
__device__ __forceinline__ unsigned short f2b(float f) {
  __hip_bfloat16 h = __float2bfloat16(f);           // round-to-nearest
  unsigned short u; __builtin_memcpy(&u, &h, 2); return u;
}

// ---------------------------------------------------------------------------
__device__ __forceinline__ void block_sum2(float& a, float& b, float* red, int tid) {
#pragma unroll
  for (int o = 1; o < 64; o <<= 1) { a += __shfl_xor(a, o); b += __shfl_xor(b, o); }
  int wid = tid >> 6;
  if ((tid & 63) == 0) { red[wid] = a; red[4 + wid] = b; }
  __syncthreads();
  a = red[0] + red[1] + red[2] + red[3];
  b = red[4] + red[5] + red[6] + red[7];
  __syncthreads();
}

// ---------------------------------------------------------------------------
__global__ __launch_bounds__(256) void inproj_kernel(
    const float* __restrict__ in, const float* __restrict__ Win,
    float* __restrict__ h) {
  long idx = (long)blockIdx.x * 256 + threadIdx.x;
  int  e   = (int)(idx & (EMBD - 1));
  long row = idx >> 9;
  const float* ir = in + row * IND;
  float acc = 0.f;
#pragma unroll
  for (int i = 0; i < IND; ++i) acc += ir[i] * Win[i * EMBD + e];
  h[idx] = acc;
}

// ---------------------------------------------------------------------------
// xn[row,:] = bf16( LN(x[row,:]) * w )
__global__ __launch_bounds__(256) void ln_mul_kernel(
    const float* __restrict__ x, const float* __restrict__ w,
    unsigned short* __restrict__ y) {
  __shared__ float red[8];
  long row = blockIdx.x;
  int tid = threadIdx.x;
  const float* xr = x + row * EMBD;
  float v0 = xr[tid], v1 = xr[tid + 256];
  float s = v0 + v1, ss = v0 * v0 + v1 * v1;
  block_sum2(s, ss, red, tid);
  float mu = s * (1.f / EMBD);
  float var = ss * (1.f / EMBD) - mu * mu;
  float rs = rsqrtf(var + LNEPS);
  y[row * EMBD + tid]       = f2b((v0 - mu) * rs * w[tid]);
  y[row * EMBD + tid + 256] = f2b((v1 - mu) * rs * w[tid + 256]);
}

// ---------------------------------------------------------------------------
// weight transpose-cast: out[n][k] = bf16(in[k][n]); z batches
__global__ __launch_bounds__(256) void castT_kernel(
    const float* __restrict__ in, unsigned short* __restrict__ out, int K, int N) {
  __shared__ float t[32][33];
  long zoff = (long)blockIdx.z * K * N;
  in += zoff; out += zoff;
  int n0 = blockIdx.x * 32, k0 = blockIdx.y * 32;
  int tx = threadIdx.x & 31, ty = threadIdx.x >> 5;   // ty 0..7
#pragma unroll
  for (int i = 0; i < 32; i += 8)
    t[ty + i][tx] = in[(long)(k0 + ty + i) * N + n0 + tx];
  __syncthreads();
#pragma unroll
  for (int i = 0; i < 32; i += 8)
    out[(long)(n0 + ty + i) * K + k0 + tx] = f2b(t[tx][ty + i]);
}

// cast q/k/v weights into packed Wqkv: [NBLK][3][NHEAD][DH][DH]
__global__ __launch_bounds__(256) void castqkv_kernel(
    const float* __restrict__ Wq, const float* __restrict__ Wk,
    const float* __restrict__ Wv, unsigned short* __restrict__ Wqkv) {
  int proj = blockIdx.z;
  const float* src = (proj == 0) ? Wq : (proj == 1) ? Wk : Wv;
  long i = (long)blockIdx.x * 256 + threadIdx.x;   // over NBLK*NH*DH*DH
  const long PER = (long)NHEAD * DHEAD * DHEAD;
  long bl = i / PER, rest = i - bl * PER;
  Wqkv[(bl * 3 + proj) * PER + rest] = f2b(src[i]);
}

// ---------------------------------------------------------------------------
// bf16 MFMA GEMM: C[m,n] = sum_k A[m,k] * Bt[n,k]; 128x128 tile, 4 waves.
// MODE: 1 = f32 accumulate, 2 = bf16 store
template <int MODE>
__global__ __launch_bounds__(256) void gemm_mfma(
    const unsigned short* __restrict__ A, int lda,
    const unsigned short* __restrict__ B, int ldb,
    void* __restrict__ Cv, int ldc, int K) {
  __shared__ unsigned short As[128][72];   // 144B row stride: 16B-aligned, ~2-way reads
  __shared__ unsigned short Bs[128][72];
  int tid = threadIdx.x;
  int lane = tid & 63, w = tid >> 6;
  int l15 = lane & 15, l4 = lane >> 4;
  int wr = w >> 1, wc = w & 1;
  int m0 = blockIdx.y * 128, n0 = blockIdx.x * 128;
  f32x4 acc[4][4];
#pragma unroll
  for (int i = 0; i < 4; ++i)
#pragma unroll
    for (int j = 0; j < 4; ++j) acc[i][j] = (f32x4){0.f, 0.f, 0.f, 0.f};

  for (int k0 = 0; k0 < K; k0 += 32) {
    __syncthreads();
#pragma unroll
    for (int L = 0; L < 2; ++L) {
      int lidx = L * 256 + tid;
      int r = lidx >> 2, kq = (lidx & 3) * 8;
      *(bf16x8*)(&As[r][kq]) = *(const bf16x8*)(A + (long)(m0 + r) * lda + k0 + kq);
      *(bf16x8*)(&Bs[r][kq]) = *(const bf16x8*)(B + (long)(n0 + r) * ldb + k0 + kq);
    }
    __syncthreads();
    bf16x8 af[4], bfr[4];
#pragma unroll
    for (int i = 0; i < 4; ++i)
      af[i] = *(const bf16x8*)(&As[wr * 64 + i * 16 + l15][l4 * 8]);
#pragma unroll
    for (int j = 0; j < 4; ++j)
      bfr[j] = *(const bf16x8*)(&Bs[wc * 64 + j * 16 + l15][l4 * 8]);
#pragma unroll
    for (int i = 0; i < 4; ++i)
#pragma unroll
      for (int j = 0; j < 4; ++j)
        acc[i][j] = __builtin_amdgcn_mfma_f32_16x16x32_bf16(af[i], bfr[j], acc[i][j], 0, 0, 0);
  }

#pragma unroll
  for (int i = 0; i < 4; ++i) {
#pragma unroll
    for (int j = 0; j < 4; ++j) {
      int col = n0 + wc * 64 + j * 16 + l15;
#pragma unroll
      for (int r = 0; r < 4; ++r) {
        int m = m0 + wr * 64 + i * 16 + l4 * 4 + r;
        float val = acc[i][j][r];
        if (MODE == 1) {
          float* C = (float*)Cv;
          C[(long)m * ldc + col] += val;
        } else {
          unsigned short* C = (unsigned short*)Cv;
          C[(long)m * ldc + col] = f2b(val);
        }
      }
    }
  }
}

// ---------------------------------------------------------------------------
// merged q/k/v projection GEMM, z = proj*4 + head (12 z-blocks).
// q: xcb@Wq[h]^T  k: xcb@Wk[h]^T  v: upb(xm)@Wv[h]^T (+ transposed copy vbT)
__global__ __launch_bounds__(256) void qkv_mfma(
    const unsigned short* __restrict__ xcb, const unsigned short* __restrict__ upb,
    const unsigned short* __restrict__ Wqkv,   // [3][NHEAD][DH][DH] (this block)
    unsigned short* __restrict__ qbuf, unsigned short* __restrict__ kbuf,
    unsigned short* __restrict__ vbuf, unsigned short* __restrict__ vbT) {
  int z = blockIdx.z;
  int proj = z >> 2, head = z & 3;
  const unsigned short* A = ((proj == 2) ? upb : xcb) + head * DHEAD;
  int lda = (proj == 2) ? 2 * INNERD : INNERD;
  const unsigned short* B = Wqkv + ((long)proj * NHEAD + head) * DHEAD * DHEAD;
  unsigned short* C = ((proj == 0) ? qbuf : (proj == 1) ? kbuf : vbuf) + head * DHEAD;
  __shared__ unsigned short As[128][72];
  __shared__ unsigned short Bs[128][72];
  int tid = threadIdx.x;
  int lane = tid & 63, w = tid >> 6;
  int l15 = lane & 15, l4 = lane >> 4;
  int wr = w >> 1, wc = w & 1;
  int m0 = blockIdx.y * 128, n0 = blockIdx.x * 128;
  f32x4 acc[4][4];
#pragma unroll
  for (int i = 0; i < 4; ++i)
#pragma unroll
    for (int j = 0; j < 4; ++j) acc[i][j] = (f32x4){0.f, 0.f, 0.f, 0.f};

  for (int k0 = 0; k0 < DHEAD; k0 += 32) {
    __syncthreads();
#pragma unroll
    for (int L = 0; L < 2; ++L) {
      int lidx = L * 256 + tid;
      int r = lidx >> 2, kq = (lidx & 3) * 8;
      *(bf16x8*)(&As[r][kq]) = *(const bf16x8*)(A + (long)(m0 + r) * lda + k0 + kq);
      *(bf16x8*)(&Bs[r][kq]) = *(const bf16x8*)(B + (long)(n0 + r) * DHEAD + k0 + kq);
    }
    __syncthreads();
    bf16x8 af[4], bfr[4];
#pragma unroll
    for (int i = 0; i < 4; ++i)
      af[i] = *(const bf16x8*)(&As[wr * 64 + i * 16 + l15][l4 * 8]);
#pragma unroll
    for (int j = 0; j < 4; ++j)
      bfr[j] = *(const bf16x8*)(&Bs[wc * 64 + j * 16 + l15][l4 * 8]);
#pragma unroll
    for (int i = 0; i < 4; ++i)
#pragma unroll
      for (int j = 0; j < 4; ++j)
        acc[i][j] = __builtin_amdgcn_mfma_f32_16x16x32_bf16(af[i], bfr[j], acc[i][j], 0, 0, 0);
  }

#pragma unroll
  for (int i = 0; i < 4; ++i) {
#pragma unroll
    for (int j = 0; j < 4; ++j) {
      int col = n0 + wc * 64 + j * 16 + l15;   // 0..255 within head
#pragma unroll
      for (int r = 0; r < 4; ++r) {
        int m = m0 + wr * 64 + i * 16 + l4 * 4 + r;
        unsigned short bv = f2b(acc[i][j][r]);
        C[(long)m * INNERD + col] = bv;
        if (proj == 2) {
          long ct = (((long)(m >> 9) * NHEAD + head) * DHEAD + col) * SEQ + (m & (SEQ - 1));
          vbT[ct] = bv;
        }
      }
    }
  }
}

// ---------------------------------------------------------------------------
// causal depthwise conv (K=4) over xm = up_b[:, :1024] (bf16) + bias, silu -> bf16
__global__ __launch_bounds__(256) void conv_silu_kernel(
    const unsigned short* __restrict__ upb, const float* __restrict__ w,
    const float* __restrict__ bias, unsigned short* __restrict__ xcb) {
  long idx = (long)blockIdx.x * 256 + threadIdx.x;  // ROWS*INNER
  int c = (int)(idx & (INNERD - 1));
  long bs = idx >> 10;
  int s = (int)(bs & (SEQ - 1));
  long b = bs >> 9;
  float acc = bias[c];
#pragma unroll
  for (int kk = 0; kk < 4; ++kk) {
    int t = s + kk - 3;
    if (t >= 0) acc += w[kk * INNERD + c] * b2f(upb[((b << 9) + t) * (2 * INNERD) + c]);
  }
  float sig = 1.f / (1.f + __expf(-acc));
  xcb[bs * INNERD + c] = f2b(acc * sig);
}

// ---------------------------------------------------------------------------
// gate projections from bf16 q/k/v rows
__global__ __launch_bounds__(256) void gates_kernel(
    const unsigned short* __restrict__ qh, const unsigned short* __restrict__ kh,
    const unsigned short* __restrict__ vh,
    const float* __restrict__ Wi, const float* __restrict__ bi,
    const float* __restrict__ Wf, const float* __restrict__ bf,
    float* __restrict__ ip, float* __restrict__ fp) {
  __shared__ float red[4][8];
  long bs = blockIdx.x;
  int tid = threadIdx.x;
  int lane = tid & 63, wid = tid >> 6;
  float pi[4] = {}, pf[4] = {};
  const unsigned short* qr = qh + bs * INNERD;
  const unsigned short* kr = kh + bs * INNERD;
  const unsigned short* vr = vh + bs * INNERD;
  for (int j = tid; j < INNERD; j += 256) {
    float xq = b2f(qr[j]), xk = b2f(kr[j]), xv = b2f(vr[j]);
    const float* wiq = Wi + (long)j * NHEAD;
    const float* wik = Wi + (long)(j + INNERD) * NHEAD;
    const float* wiv = Wi + (long)(j + 2 * INNERD) * NHEAD;
    const float* wfq = Wf + (long)j * NHEAD;
    const float* wfk = Wf + (long)(j + INNERD) * NHEAD;
    const float* wfv = Wf + (long)(j + 2 * INNERD) * NHEAD;
#pragma unroll
    for (int n = 0; n < NHEAD; ++n) {
      pi[n] += xq * wiq[n] + xk * wik[n] + xv * wiv[n];
      pf[n] += xq * wfq[n] + xk * wfk[n] + xv * wfv[n];
    }
  }
#pragma unroll
  for (int n = 0; n < NHEAD; ++n) {
#pragma unroll
    for (int o = 1; o < 64; o <<= 1) {
      pi[n] += __shfl_xor(pi[n], o);
      pf[n] += __shfl_xor(pf[n], o);
    }
  }
  if (lane == 0) {
#pragma unroll
    for (int n = 0; n < NHEAD; ++n) { red[wid][n] = pi[n]; red[wid][4 + n] = pf[n]; }
  }
  __syncthreads();
  if (tid == 0) {
    long b = bs >> 9;
    int s = (int)(bs & (SEQ - 1));
#pragma unroll
    for (int n = 0; n < NHEAD; ++n) {
      float a = red[0][n] + red[1][n] + red[2][n] + red[3][n] + bi[n];
      float c = red[0][4 + n] + red[1][4 + n] + red[2][4 + n] + red[3][4 + n] + bf[n];
      ip[(b * NHEAD + n) * SEQ + s] = a;
      fp[(b * NHEAD + n) * SEQ + s] = c;
    }
  }
}

// ---------------------------------------------------------------------------
// parallel gate scan: F = cumsum(logsig(f)); Bc = F - i; mrow = F + runmax(i - F)
__global__ __launch_bounds__(64) void fgate_kernel(
    const float* __restrict__ fp, const float* __restrict__ ip,
    float* __restrict__ F, float* __restrict__ Bc, float* __restrict__ mrow) {
  int bh = blockIdx.x;
  int lane = threadIdx.x;
  const float* fr = fp + (long)bh * SEQ;
  const float* ir = ip + (long)bh * SEQ;
  float v[8]; float run = 0.f;
#pragma unroll
  for (int i = 0; i < 8; ++i) {
    float x = fr[lane * 8 + i];
    float ls = fminf(x, 0.f) - log1pf(__expf(-fabsf(x)));
    run += ls; v[i] = run;
  }
  float tot = run, scan = run;
#pragma unroll
  for (int off = 1; off < 64; off <<= 1) {
    float n = __shfl_up(scan, off);
    if (lane >= off) scan += n;
  }
  float excl = scan - tot;
  float Fv[8];
#pragma unroll
  for (int i = 0; i < 8; ++i) {
    Fv[i] = excl + v[i];
    F[(long)bh * SEQ + lane * 8 + i] = Fv[i];
  }
  float g[8], pmv[8]; float pm = -INFINITY;
#pragma unroll
  for (int i = 0; i < 8; ++i) {
    g[i] = ir[lane * 8 + i] - Fv[i];
    Bc[(long)bh * SEQ + lane * 8 + i] = -g[i];
    pm = fmaxf(pm, g[i]); pmv[i] = pm;
  }
  float mx = pm;
#pragma unroll
  for (int off = 1; off < 64; off <<= 1) {
    float n = __shfl_up(mx, off);
    if (lane >= off) mx = fmaxf(mx, n);
  }
  float ex = __shfl_up(mx, 1);
  if (lane == 0) ex = -INFINITY;
#pragma unroll
  for (int i = 0; i < 8; ++i) {
    float inc = fmaxf(ex, pmv[i]);
    mrow[(long)bh * SEQ + lane * 8 + i] = Fv[i] + inc;
  }
}

// ---------------------------------------------------------------------------
// flash mLSTM cell + fused head-norm/skip/silu(z).
// Grid: x = h + NHEAD*b (same-(h,b) q-blocks -> same XCD -> K/V L2-resident),
//       y = q-tile. Block = 512 threads (8 waves):
// wave w: rg = w&3 (16 q-rows), th = w>>2 (t-half for QK^T, d-half for PV).
// Async stage: tile tt+1's global loads issue into regs during tile tt compute.
__global__ __launch_bounds__(512) void cell_kernel(
    const unsigned short* __restrict__ qb, const unsigned short* __restrict__ kb,
    const unsigned short* __restrict__ vbT,
    const float* __restrict__ F, const float* __restrict__ Bc,
    const float* __restrict__ mrow,
    const unsigned short* __restrict__ upb,
    const float* __restrict__ onw, const float* __restrict__ skw,
    unsigned short* __restrict__ xcb) {
  int hb = blockIdx.x;
  int h = hb & (NHEAD - 1), b = hb >> 2;
  int qt = blockIdx.y;
  int tid = threadIdx.x, lane = tid & 63, w = tid >> 6;   // w 0..7
  int l15 = lane & 15, l4 = lane >> 4;
  int rg = w & 3, th = w >> 2;
  __shared__ unsigned short Ks[64][264];   // 528B row stride
  __shared__ unsigned short Vs[256][72];   // 144B row stride
  __shared__ unsigned short P[64][72];
  __shared__ float redx[2][4][16];         // [th][rg][row-in-group]
  __shared__ float redy[2][4][16][2];
  int bh = b * NHEAD + h;
  const float* Fr = F + (long)bh * SEQ;
  const float* Br = Bc + (long)bh * SEQ;
  const float* Mr = mrow + (long)bh * SEQ;
  int s0 = qt * 64;
  long bs0 = (long)b * SEQ;
  int sr[4]; float Ar[4], Mv[4];
#pragma unroll
  for (int r = 0; r < 4; ++r) {
    sr[r] = s0 + rg * 16 + l4 * 4 + r;
    float fs = Fr[sr[r]];
    Mv[r] = Mr[sr[r]];
    Ar[r] = fs - Mv[r];
  }
  bf16x8 qf[8];
  const unsigned short* qp = qb + (bs0 + s0 + rg * 16 + l15) * INNERD + h * DHEAD + l4 * 8;
#pragma unroll
  for (int kk = 0; kk < 8; ++kk) qf[kk] = *(const bf16x8*)(qp + kk * 32);
  f32x4 o[8];
#pragma unroll
  for (int i = 0; i < 8; ++i) o[i] = (f32x4){0.f, 0.f, 0.f, 0.f};
  float rs[4] = {0.f, 0.f, 0.f, 0.f};

  const unsigned short* kbase = kb + bs0 * INNERD + h * DHEAD;
  const unsigned short* vbase = vbT + (long)bh * DHEAD * SEQ;
  int kR[4], kC[4], vD[4], vC[4];
#pragma unroll
  for (int i = 0; i < 4; ++i) {
    int idx = tid + i * 512;      // 0..2047
    kR[i] = idx >> 5; kC[i] = (idx & 31) * 8;
    vD[i] = idx >> 3; vC[i] = (idx & 7) * 8;
  }
  bf16x8 kreg[4], vreg[4];
#pragma unroll
  for (int i = 0; i < 4; ++i) {
    kreg[i] = *(const bf16x8*)(kbase + (long)kR[i] * INNERD + kC[i]);
    vreg[i] = *(const bf16x8*)(vbase + (long)vD[i] * SEQ + vC[i]);
  }

  int nt = qt + 1;
  for (int tt = 0; tt < nt; ++tt) {
    int t0 = tt * 64;
    __syncthreads();                     // previous tile's LDS reads done
#pragma unroll
    for (int i = 0; i < 4; ++i) {
      *(bf16x8*)(&Ks[kR[i]][kC[i]]) = kreg[i];
      *(bf16x8*)(&Vs[vD[i]][vC[i]]) = vreg[i];
    }
    __syncthreads();
    if (tt + 1 < nt) {                   // async: overlaps compute below
      int t1 = (tt + 1) * 64;
#pragma unroll
      for (int i = 0; i < 4; ++i) {
        kreg[i] = *(const bf16x8*)(kbase + (long)(t1 + kR[i]) * INNERD + kC[i]);
        vreg[i] = *(const bf16x8*)(vbase + (long)vD[i] * SEQ + t1 + vC[i]);
      }
    }
    bool diag = (tt == nt - 1);
#pragma unroll
    for (int tfl = 0; tfl < 2; ++tfl) {
      f32x4 s = (f32x4){0.f, 0.f, 0.f, 0.f};
#pragma unroll
      for (int kk = 0; kk < 8; ++kk) {
        bf16x8 kf = *(const bf16x8*)(&Ks[th * 32 + tfl * 16 + l15][kk * 32 + l4 * 8]);
        s = __builtin_amdgcn_mfma_f32_16x16x32_bf16(qf[kk], kf, s, 0, 0, 0);
      }
      int tcol = t0 + th * 32 + tfl * 16 + l15;
      float bc = Br[tcol];
#pragma unroll
      for (int r = 0; r < 4; ++r) {
        float p = s[r] * 0.0625f * __expf(Ar[r] - bc);
        if (diag && tcol > sr[r]) p = 0.f;
        rs[r] += p;
        P[rg * 16 + l4 * 4 + r][th * 32 + tfl * 16 + l15] = f2b(p);
      }
    }
    __syncthreads();                     // P complete (both t-halves)
#pragma unroll
    for (int ks = 0; ks < 2; ++ks) {
      bf16x8 pa = *(const bf16x8*)(&P[rg * 16 + l15][ks * 32 + l4 * 8]);
#pragma unroll
      for (int df = 0; df < 8; ++df) {
        bf16x8 vf = *(const bf16x8*)(&Vs[th * 128 + df * 16 + l15][ks * 32 + l4 * 8]);
        o[df] = __builtin_amdgcn_mfma_f32_16x16x32_bf16(pa, vf, o[df], 0, 0, 0);
      }
    }
  }
#pragma unroll
  for (int r = 0; r < 4; ++r)
#pragma unroll
    for (int off = 1; off < 16; off <<= 1) rs[r] += __shfl_xor(rs[r], off);
  if (l15 == 0) {
#pragma unroll
    for (int r = 0; r < 4; ++r) redx[th][rg][l4 * 4 + r] = rs[r];
  }
  __syncthreads();
  float inv[4];
#pragma unroll
  for (int r = 0; r < 4; ++r) {
    float tot = redx[0][rg][l4 * 4 + r] + redx[1][rg][l4 * 4 + r];
    float denom = fmaxf(fabsf(tot), __expf(-Mv[r])) + 1e-6f;
    inv[r] = 1.f / denom;
  }
#pragma unroll
  for (int df = 0; df < 8; ++df)
#pragma unroll
    for (int r = 0; r < 4; ++r) o[df][r] *= inv[r];
  float sm[4] = {}, sq[4] = {};
#pragma unroll
  for (int df = 0; df < 8; ++df)
#pragma unroll
    for (int r = 0; r < 4; ++r) { float x = o[df][r]; sm[r] += x; sq[r] += x * x; }
#pragma unroll
  for (int r = 0; r < 4; ++r)
#pragma unroll
    for (int off = 1; off < 16; off <<= 1) {
      sm[r] += __shfl_xor(sm[r], off);
      sq[r] += __shfl_xor(sq[r], off);
    }
  if (l15 == 0) {
#pragma unroll
    for (int r = 0; r < 4; ++r) {
      redy[th][rg][l4 * 4 + r][0] = sm[r];
      redy[th][rg][l4 * 4 + r][1] = sq[r];
    }
  }
  __syncthreads();
  float mu[4], rstd[4];
#pragma unroll
  for (int r = 0; r < 4; ++r) {
    float smt = redy[0][rg][l4 * 4 + r][0] + redy[1][rg][l4 * 4 + r][0];
    float sqt = redy[0][rg][l4 * 4 + r][1] + redy[1][rg][l4 * 4 + r][1];
    mu[r] = smt * (1.f / DHEAD);
    float var = sqt * (1.f / DHEAD) - mu[r] * mu[r];
    rstd[r] = rsqrtf(var + LNEPS);
  }
#pragma unroll
  for (int df = 0; df < 8; ++df) {
    int c = h * DHEAD + th * 128 + df * 16 + l15;
    float ow = onw[c], sw = skw[c];
#pragma unroll
    for (int r = 0; r < 4; ++r) {
      long grow = bs0 + sr[r];
      float z = b2f(upb[grow * (2 * INNERD) + INNERD + c]);
      float sig = 1.f / (1.f + __expf(-z));
      float xcv = b2f(xcb[grow * INNERD + c]);   // in-place: read pre-value
      float y = (o[df][r] - mu[r]) * rstd[r];
      float g = (y * ow + sw * xcv) * (z * sig);
      xcb[grow * INNERD + c] = f2b(g);
    }
  }
}

// ---------------------------------------------------------------------------
__global__ __launch_bounds__(256) void final_kernel(
    const float* __restrict__ h, const float* __restrict__ pw,
    const float* __restrict__ ow, const float* __restrict__ ob,
    const float* __restrict__ Wh, const float* __restrict__ bh,
    float* __restrict__ out) {
  __shared__ float red[8];
  __shared__ float sh[EMBD];
  int b = blockIdx.x, tid = threadIdx.x;
  const float* xr = h + ((long)b * SEQ + (SEQ - 1)) * EMBD;
  float v0 = xr[tid], v1 = xr[tid + 256];
  float s = v0 + v1, ss = v0 * v0 + v1 * v1;
  block_sum2(s, ss, red, tid);
  float mu = s * (1.f / EMBD), var = ss * (1.f / EMBD) - mu * mu;
  float rs = rsqrtf(var + LNEPS);
  float y0 = (v0 - mu) * rs * pw[tid];
  float y1 = (v1 - mu) * rs * pw[tid + 256];
  float s2 = y0 + y1, ss2 = y0 * y0 + y1 * y1;
  block_sum2(s2, ss2, red, tid);
  float mu2 = s2 * (1.f / EMBD), var2 = ss2 * (1.f / EMBD) - mu2 * mu2;
  float rs2 = rsqrtf(var2 + LNEPS);
  sh[tid]       = (y0 - mu2) * rs2 * ow[tid] + ob[tid];
  sh[tid + 256] = (y1 - mu2) * rs2 * ow[tid + 256] + ob[tid + 256];
  __syncthreads();
  if (tid < OUTD) {
    float acc = bh[tid];
    for (int e = 0; e < EMBD; ++e) acc += sh[e] * Wh[e * OUTD + tid];
    out[b * OUTD + tid] = acc;
  }
}

// ---------------------------------------------------------------------------
extern "C" void kernel_launch(void* const* d_in, const int* in_sizes, int n_in,
                              void* d_out, int out_size, void* d_ws, size_t ws_size,
                              hipStream_t stream) {
  const float* inputs    = (const float*)d_in[0];
  const float* W_in      = (const float*)d_in[1];
  const float* ln_w      = (const float*)d_in[2];
  const float* W_up      = (const float*)d_in[3];
  const float* conv_w    = (const float*)d_in[4];
  const float* conv_b    = (const float*)d_in[5];
  const float* Wq        = (const float*)d_in[6];
  const float* Wk        = (const float*)d_in[7];
  const float* Wv        = (const float*)d_in[8];
  const float* W_i       = (const float*)d_in[9];
  const float* b_i       = (const float*)d_in[10];
  const float* W_f       = (const float*)d_in[11];
  const float* b_f       = (const float*)d_in[12];
  const float* skipw     = (const float*)d_in[13];
  const float* onorm_w   = (const float*)d_in[14];
  const float* W_down    = (const float*)d_in[15];
  const float* post_ln_w = (const float*)d_in[16];
  const float* out_ln_w  = (const float*)d_in[17];
  const float* out_ln_b  = (const float*)d_in[18];
  const float* W_head    = (const float*)d_in[19];
  const float* b_head    = (const float*)d_in[20];
  float* out = (float*)d_out;

  const long ROWS = (long)BATCH * SEQ;   // 8192
  // ---- full-batch workspace layout (~159 MB; ws_size = 256 MB confirmed) ----
  float* fpool = (float*)d_ws;
  float* h    = fpool; fpool += ROWS * EMBD;            // 16.8 MB
  float* ipb  = fpool; fpool += (long)BATCH * NHEAD * SEQ;
  float* fpb  = fpool; fpool += (long)BATCH * NHEAD * SEQ;
  float* Fc   = fpool; fpool += (long)BATCH * NHEAD * SEQ;
  float* Bcc  = fpool; fpool += (long)BATCH * NHEAD * SEQ;
  float* mrw  = fpool; fpool += (long)BATCH * NHEAD * SEQ;
  unsigned short* upool = (unsigned short*)fpool;
  unsigned short* xn    = upool; upool += ROWS * EMBD;          //  8.4 MB
  unsigned short* upb   = upool; upool += ROWS * 2 * INNERD;    // 33.6 MB
  unsigned short* xcb   = upool; upool += ROWS * INNERD;        // 16.8 MB
  unsigned short* qbuf  = upool; upool += ROWS * INNERD;
  unsigned short* kbuf  = upool; upool += ROWS * INNERD;
  unsigned short* vbuf  = upool; upool += ROWS * INNERD;
  unsigned short* vbT   = upool; upool += (long)BATCH * NHEAD * DHEAD * SEQ;
  unsigned short* WupT  = upool; upool += (long)NBLK * 2 * INNERD * EMBD;
  unsigned short* WdnT  = upool; upool += (long)NBLK * EMBD * INNERD;
  unsigned short* Wqkv  = upool; upool += (long)NBLK * 3 * NHEAD * DHEAD * DHEAD;

  // ---- weight prep (same work every call) ----
  castT_kernel<<<dim3(2 * INNERD / 32, EMBD / 32, NBLK), 256, 0, stream>>>(
      W_up, WupT, EMBD, 2 * INNERD);
  castT_kernel<<<dim3(EMBD / 32, INNERD / 32, NBLK), 256, 0, stream>>>(
      W_down, WdnT, INNERD, EMBD);
  const long WQN = (long)NBLK * NHEAD * DHEAD * DHEAD;
  castqkv_kernel<<<dim3(WQN / 256, 1, 3), 256, 0, stream>>>(Wq, Wk, Wv, Wqkv);

  inproj_kernel<<<(ROWS * EMBD) / 256, 256, 0, stream>>>(inputs, W_in, h);

  for (int bl = 0; bl < NBLK; ++bl) {
    const float* lnw  = ln_w    + (long)bl * EMBD;
    const float* cwb  = conv_w  + (long)bl * 4 * INNERD;
    const float* cbb  = conv_b  + (long)bl * INNERD;
    const float* Wib  = W_i     + (long)bl * GATES * NHEAD;
    const float* bib  = b_i     + (long)bl * NHEAD;
    const float* Wfb  = W_f     + (long)bl * GATES * NHEAD;
    const float* bfb  = b_f     + (long)bl * NHEAD;
    const float* skb  = skipw   + (long)bl * INNERD;
    const float* onw  = onorm_w + (long)bl * INNERD;
    const unsigned short* WupTb = WupT + (long)bl * 2 * INNERD * EMBD;
    const unsigned short* WdnTb = WdnT + (long)bl * EMBD * INNERD;
    const unsigned short* Wqkvb = Wqkv + (long)bl * 3 * NHEAD * DHEAD * DHEAD;

    ln_mul_kernel<<<ROWS, 256, 0, stream>>>(h, lnw, xn);

    // up: [8192x512] @ [512x2048] -> bf16 up_b   (1024 blocks)
    gemm_mfma<2><<<dim3(2 * INNERD / 128, ROWS / 128, 1), 256, 0, stream>>>(
        xn, EMBD, WupTb, EMBD, upb, 2 * INNERD, EMBD);

    conv_silu_kernel<<<(ROWS * INNERD) / 256, 256, 0, stream>>>(upb, cwb, cbb, xcb);

    // merged q/k/v projections (z = proj*4 + head), 1536 blocks
    qkv_mfma<<<dim3(DHEAD / 128, ROWS / 128, 12), 256, 0, stream>>>(
        xcb, upb, Wqkvb, qbuf, kbuf, vbuf, vbT);

    gates_kernel<<<ROWS, 256, 0, stream>>>(qbuf, kbuf, vbuf, Wib, bib, Wfb, bfb, ipb, fpb);
    fgate_kernel<<<BATCH * NHEAD, 64, 0, stream>>>(fpb, ipb, Fc, Bcc, mrw);

    // x = hb (same-(h,b) blocks -> same XCD), y = q-tile; 512 threads
    cell_kernel<<<dim3(NHEAD * BATCH, SEQ / 64, 1), 512, 0, stream>>>(
        qbuf, kbuf, vbT, Fc, Bcc, mrw, upb, onw, skb, xcb);

    // down: h += [8192x1024] @ [1024x512]   (256 blocks)
    gemm_mfma<1><<<dim3(EMBD / 128, ROWS / 128, 1), 256, 0, stream>>>(
        xcb, INNERD, WdnTb, INNERD, h, EMBD, INNERD);
  }

  final_kernel<<<BATCH, 256, 0, stream>>>(h, post_ln_w, out_ln_w, out_ln_b,
                                          W_head, b_head, out);
}

// Round 11
// 617.919 us; speedup vs baseline: 9.9742x; 1.0108x over previous
//
#include <hip/hip_runtime.h>
#include <hip/hip_bf16.h>

#define BATCH  16
#define SEQ    512
#define IND    32
#define OUTD   32
#define EMBD   512
#define NBLK   2
#define NHEAD  4
#define INNERD 1024   // 2*EMB
#define DHEAD  256    // INNER/NH
#define GATES  3072   // 3*INNER
#define LNEPS  1e-5f

typedef __attribute__((ext_vector_type(8))) short bf16x8;   // 8 bf16 in 4 VGPRs
typedef __attribute__((ext_vector_type(4))) float f32x4;

__device__ __forceinline__ float b2f(unsigned short u) {
  union { unsigned int i; float f; } v; v.i = ((unsigned int)u) << 16; return v.f;
}
__device__ __forceinline__ unsigned short f2b(float f) {
  __hip_bfloat16 h = __float2bfloat16(f);           // round-to-nearest
  unsigned short u; __builtin_memcpy(&u, &h, 2); return u;
}

// async global -> LDS, 16B per lane (global_load_lds_dwordx4)
__device__ __forceinline__ void gload16(const void* g, void* l) {
  __builtin_amdgcn_global_load_lds(
      (const __attribute__((address_space(1))) unsigned int*)g,
      (__attribute__((address_space(3))) unsigned int*)l, 16, 0, 0);
}

// ---------------------------------------------------------------------------
__device__ __forceinline__ void block_sum2(float& a, float& b, float* red, int tid) {
#pragma unroll
  for (int o = 1; o < 64; o <<= 1) { a += __shfl_xor(a, o); b += __shfl_xor(b, o); }
  int wid = tid >> 6;
  if ((tid & 63) == 0) { red[wid] = a; red[4 + wid] = b; }
  __syncthreads();
  a = red[0] + red[1] + red[2] + red[3];
  b = red[4] + red[5] + red[6] + red[7];
  __syncthreads();
}

// ---------------------------------------------------------------------------
__global__ __launch_bounds__(256) void inproj_kernel(
    const float* __restrict__ in, const float* __restrict__ Win,
    float* __restrict__ h) {
  long idx = (long)blockIdx.x * 256 + threadIdx.x;
  int  e   = (int)(idx & (EMBD - 1));
  long row = idx >> 9;
  const float* ir = in + row * IND;
  float acc = 0.f;
#pragma unroll
  for (int i = 0; i < IND; ++i) acc += ir[i] * Win[i * EMBD + e];
  h[idx] = acc;
}

// ---------------------------------------------------------------------------
// xn[row,:] = bf16( LN(x[row,:]) * w )
__global__ __launch_bounds__(256) void ln_mul_kernel(
    const float* __restrict__ x, const float* __restrict__ w,
    unsigned short* __restrict__ y) {
  __shared__ float red[8];
  long row = blockIdx.x;
  int tid = threadIdx.x;
  const float* xr = x + row * EMBD;
  float v0 = xr[tid], v1 = xr[tid + 256];
  float s = v0 + v1, ss = v0 * v0 + v1 * v1;
  block_sum2(s, ss, red, tid);
  float mu = s * (1.f / EMBD);
  float var = ss * (1.f / EMBD) - mu * mu;
  float rs = rsqrtf(var + LNEPS);
  y[row * EMBD + tid]       = f2b((v0 - mu) * rs * w[tid]);
  y[row * EMBD + tid + 256] = f2b((v1 - mu) * rs * w[tid + 256]);
}

// ---------------------------------------------------------------------------
// weight transpose-cast: out[n][k] = bf16(in[k][n]); z batches
__global__ __launch_bounds__(256) void castT_kernel(
    const float* __restrict__ in, unsigned short* __restrict__ out, int K, int N) {
  __shared__ float t[32][33];
  long zoff = (long)blockIdx.z * K * N;
  in += zoff; out += zoff;
  int n0 = blockIdx.x * 32, k0 = blockIdx.y * 32;
  int tx = threadIdx.x & 31, ty = threadIdx.x >> 5;   // ty 0..7
#pragma unroll
  for (int i = 0; i < 32; i += 8)
    t[ty + i][tx] = in[(long)(k0 + ty + i) * N + n0 + tx];
  __syncthreads();
#pragma unroll
  for (int i = 0; i < 32; i += 8)
    out[(long)(n0 + ty + i) * K + k0 + tx] = f2b(t[tx][ty + i]);
}

// cast q/k/v weights into packed Wqkv: [NBLK][3][NHEAD][DH][DH]
__global__ __launch_bounds__(256) void castqkv_kernel(
    const float* __restrict__ Wq, const float* __restrict__ Wk,
    const float* __restrict__ Wv, unsigned short* __restrict__ Wqkv) {
  int proj = blockIdx.z;
  const float* src = (proj == 0) ? Wq : (proj == 1) ? Wk : Wv;
  long i = (long)blockIdx.x * 256 + threadIdx.x;   // over NBLK*NH*DH*DH
  const long PER = (long)NHEAD * DHEAD * DHEAD;
  long bl = i / PER, rest = i - bl * PER;
  Wqkv[(bl * 3 + proj) * PER + rest] = f2b(src[i]);
}

// ---------------------------------------------------------------------------
// bf16 MFMA GEMM (m97 structure): C[m,n] = sum_k A[m,k] * Bt[n,k];
// 128x128 tile, 4 waves, linear LDS [128][32], global_load_lds staging.
// MODE: 1 = f32 accumulate, 2 = bf16 store
template <int MODE>
__global__ __launch_bounds__(256) void gemm_mfma(
    const unsigned short* __restrict__ A, int lda,
    const unsigned short* __restrict__ B, int ldb,
    void* __restrict__ Cv, int ldc, int K) {
  __shared__ unsigned short As[128][32];
  __shared__ unsigned short Bs[128][32];
  int tid = threadIdx.x;
  int lane = tid & 63, w = tid >> 6;
  int l15 = lane & 15, l4 = lane >> 4;
  int wr = w >> 1, wc = w & 1;
  int m0 = blockIdx.y * 128, n0 = blockIdx.x * 128;
  int srow = lane >> 2, scol = (lane & 3) * 8;   // staging: lane -> row/col
  f32x4 acc[4][4];
#pragma unroll
  for (int i = 0; i < 4; ++i)
#pragma unroll
    for (int j = 0; j < 4; ++j) acc[i][j] = (f32x4){0.f, 0.f, 0.f, 0.f};

  for (int k0 = 0; k0 < K; k0 += 32) {
    __syncthreads();                       // prev compute done reading LDS
#pragma unroll
    for (int ia = 0; ia < 2; ++ia) {
      int rb = (ia * 4 + w) * 16;          // wave-uniform row base
      gload16(A + (long)(m0 + rb + srow) * lda + k0 + scol, &As[rb][0]);
      gload16(B + (long)(n0 + rb + srow) * ldb + k0 + scol, &Bs[rb][0]);
    }
    __syncthreads();                       // vmcnt(0) drain at barrier
    bf16x8 af[4], bfr[4];
#pragma unroll
    for (int i = 0; i < 4; ++i)
      af[i] = *(const bf16x8*)(&As[wr * 64 + i * 16 + l15][l4 * 8]);
#pragma unroll
    for (int j = 0; j < 4; ++j)
      bfr[j] = *(const bf16x8*)(&Bs[wc * 64 + j * 16 + l15][l4 * 8]);
#pragma unroll
    for (int i = 0; i < 4; ++i)
#pragma unroll
      for (int j = 0; j < 4; ++j)
        acc[i][j] = __builtin_amdgcn_mfma_f32_16x16x32_bf16(af[i], bfr[j], acc[i][j], 0, 0, 0);
  }

#pragma unroll
  for (int i = 0; i < 4; ++i) {
#pragma unroll
    for (int j = 0; j < 4; ++j) {
      int col = n0 + wc * 64 + j * 16 + l15;
#pragma unroll
      for (int r = 0; r < 4; ++r) {
        int m = m0 + wr * 64 + i * 16 + l4 * 4 + r;
        float val = acc[i][j][r];
        if (MODE == 1) {
          float* C = (float*)Cv;
          C[(long)m * ldc + col] += val;
        } else {
          unsigned short* C = (unsigned short*)Cv;
          C[(long)m * ldc + col] = f2b(val);
        }
      }
    }
  }
}

// ---------------------------------------------------------------------------
// merged q/k/v projection GEMM (m97 staging), z = proj*4 + head (12 z-blocks).
// q: xcb@Wq[h]^T  k: xcb@Wk[h]^T  v: upb(xm)@Wv[h]^T (+ transposed copy vbT)
__global__ __launch_bounds__(256) void qkv_mfma(
    const unsigned short* __restrict__ xcb, const unsigned short* __restrict__ upb,
    const unsigned short* __restrict__ Wqkv,   // [3][NHEAD][DH][DH] (this block)
    unsigned short* __restrict__ qbuf, unsigned short* __restrict__ kbuf,
    unsigned short* __restrict__ vbuf, unsigned short* __restrict__ vbT) {
  int z = blockIdx.z;
  int proj = z >> 2, head = z & 3;
  const unsigned short* A = ((proj == 2) ? upb : xcb) + head * DHEAD;
  int lda = (proj == 2) ? 2 * INNERD : INNERD;
  const unsigned short* B = Wqkv + ((long)proj * NHEAD + head) * DHEAD * DHEAD;
  unsigned short* C = ((proj == 0) ? qbuf : (proj == 1) ? kbuf : vbuf) + head * DHEAD;
  __shared__ unsigned short As[128][32];
  __shared__ unsigned short Bs[128][32];
  int tid = threadIdx.x;
  int lane = tid & 63, w = tid >> 6;
  int l15 = lane & 15, l4 = lane >> 4;
  int wr = w >> 1, wc = w & 1;
  int m0 = blockIdx.y * 128, n0 = blockIdx.x * 128;
  int srow = lane >> 2, scol = (lane & 3) * 8;
  f32x4 acc[4][4];
#pragma unroll
  for (int i = 0; i < 4; ++i)
#pragma unroll
    for (int j = 0; j < 4; ++j) acc[i][j] = (f32x4){0.f, 0.f, 0.f, 0.f};

  for (int k0 = 0; k0 < DHEAD; k0 += 32) {
    __syncthreads();
#pragma unroll
    for (int ia = 0; ia < 2; ++ia) {
      int rb = (ia * 4 + w) * 16;
      gload16(A + (long)(m0 + rb + srow) * lda + k0 + scol, &As[rb][0]);
      gload16(B + (long)(n0 + rb + srow) * DHEAD + k0 + scol, &Bs[rb][0]);
    }
    __syncthreads();
    bf16x8 af[4], bfr[4];
#pragma unroll
    for (int i = 0; i < 4; ++i)
      af[i] = *(const bf16x8*)(&As[wr * 64 + i * 16 + l15][l4 * 8]);
#pragma unroll
    for (int j = 0; j < 4; ++j)
      bfr[j] = *(const bf16x8*)(&Bs[wc * 64 + j * 16 + l15][l4 * 8]);
#pragma unroll
    for (int i = 0; i < 4; ++i)
#pragma unroll
      for (int j = 0; j < 4; ++j)
        acc[i][j] = __builtin_amdgcn_mfma_f32_16x16x32_bf16(af[i], bfr[j], acc[i][j], 0, 0, 0);
  }

#pragma unroll
  for (int i = 0; i < 4; ++i) {
#pragma unroll
    for (int j = 0; j < 4; ++j) {
      int col = n0 + wc * 64 + j * 16 + l15;   // 0..255 within head
#pragma unroll
      for (int r = 0; r < 4; ++r) {
        int m = m0 + wr * 64 + i * 16 + l4 * 4 + r;
        unsigned short bv = f2b(acc[i][j][r]);
        C[(long)m * INNERD + col] = bv;
        if (proj == 2) {
          long ct = (((long)(m >> 9) * NHEAD + head) * DHEAD + col) * SEQ + (m & (SEQ - 1));
          vbT[ct] = bv;
        }
      }
    }
  }
}

// ---------------------------------------------------------------------------
// causal depthwise conv (K=4) over xm = up_b[:, :1024] (bf16) + bias, silu -> bf16
__global__ __launch_bounds__(256) void conv_silu_kernel(
    const unsigned short* __restrict__ upb, const float* __restrict__ w,
    const float* __restrict__ bias, unsigned short* __restrict__ xcb) {
  long idx = (long)blockIdx.x * 256 + threadIdx.x;  // ROWS*INNER
  int c = (int)(idx & (INNERD - 1));
  long bs = idx >> 10;
  int s = (int)(bs & (SEQ - 1));
  long b = bs >> 9;
  float acc = bias[c];
#pragma unroll
  for (int kk = 0; kk < 4; ++kk) {
    int t = s + kk - 3;
    if (t >= 0) acc += w[kk * INNERD + c] * b2f(upb[((b << 9) + t) * (2 * INNERD) + c]);
  }
  float sig = 1.f / (1.f + __expf(-acc));
  xcb[bs * INNERD + c] = f2b(acc * sig);
}

// ---------------------------------------------------------------------------
// gate projections from bf16 q/k/v rows
__global__ __launch_bounds__(256) void gates_kernel(
    const unsigned short* __restrict__ qh, const unsigned short* __restrict__ kh,
    const unsigned short* __restrict__ vh,
    const float* __restrict__ Wi, const float* __restrict__ bi,
    const float* __restrict__ Wf, const float* __restrict__ bf,
    float* __restrict__ ip, float* __restrict__ fp) {
  __shared__ float red[4][8];
  long bs = blockIdx.x;
  int tid = threadIdx.x;
  int lane = tid & 63, wid = tid >> 6;
  float pi[4] = {}, pf[4] = {};
  const unsigned short* qr = qh + bs * INNERD;
  const unsigned short* kr = kh + bs * INNERD;
  const unsigned short* vr = vh + bs * INNERD;
  for (int j = tid; j < INNERD; j += 256) {
    float xq = b2f(qr[j]), xk = b2f(kr[j]), xv = b2f(vr[j]);
    const float* wiq = Wi + (long)j * NHEAD;
    const float* wik = Wi + (long)(j + INNERD) * NHEAD;
    const float* wiv = Wi + (long)(j + 2 * INNERD) * NHEAD;
    const float* wfq = Wf + (long)j * NHEAD;
    const float* wfk = Wf + (long)(j + INNERD) * NHEAD;
    const float* wfv = Wf + (long)(j + 2 * INNERD) * NHEAD;
#pragma unroll
    for (int n = 0; n < NHEAD; ++n) {
      pi[n] += xq * wiq[n] + xk * wik[n] + xv * wiv[n];
      pf[n] += xq * wfq[n] + xk * wfk[n] + xv * wfv[n];
    }
  }
#pragma unroll
  for (int n = 0; n < NHEAD; ++n) {
#pragma unroll
    for (int o = 1; o < 64; o <<= 1) {
      pi[n] += __shfl_xor(pi[n], o);
      pf[n] += __shfl_xor(pf[n], o);
    }
  }
  if (lane == 0) {
#pragma unroll
    for (int n = 0; n < NHEAD; ++n) { red[wid][n] = pi[n]; red[wid][4 + n] = pf[n]; }
  }
  __syncthreads();
  if (tid == 0) {
    long b = bs >> 9;
    int s = (int)(bs & (SEQ - 1));
#pragma unroll
    for (int n = 0; n < NHEAD; ++n) {
      float a = red[0][n] + red[1][n] + red[2][n] + red[3][n] + bi[n];
      float c = red[0][4 + n] + red[1][4 + n] + red[2][4 + n] + red[3][4 + n] + bf[n];
      ip[(b * NHEAD + n) * SEQ + s] = a;
      fp[(b * NHEAD + n) * SEQ + s] = c;
    }
  }
}

// ---------------------------------------------------------------------------
// parallel gate scan: F = cumsum(logsig(f)); Bc = F - i; mrow = F + runmax(i - F)
__global__ __launch_bounds__(64) void fgate_kernel(
    const float* __restrict__ fp, const float* __restrict__ ip,
    float* __restrict__ F, float* __restrict__ Bc, float* __restrict__ mrow) {
  int bh = blockIdx.x;
  int lane = threadIdx.x;
  const float* fr = fp + (long)bh * SEQ;
  const float* ir = ip + (long)bh * SEQ;
  float v[8]; float run = 0.f;
#pragma unroll
  for (int i = 0; i < 8; ++i) {
    float x = fr[lane * 8 + i];
    float ls = fminf(x, 0.f) - log1pf(__expf(-fabsf(x)));
    run += ls; v[i] = run;
  }
  float tot = run, scan = run;
#pragma unroll
  for (int off = 1; off < 64; off <<= 1) {
    float n = __shfl_up(scan, off);
    if (lane >= off) scan += n;
  }
  float excl = scan - tot;
  float Fv[8];
#pragma unroll
  for (int i = 0; i < 8; ++i) {
    Fv[i] = excl + v[i];
    F[(long)bh * SEQ + lane * 8 + i] = Fv[i];
  }
  float g[8], pmv[8]; float pm = -INFINITY;
#pragma unroll
  for (int i = 0; i < 8; ++i) {
    g[i] = ir[lane * 8 + i] - Fv[i];
    Bc[(long)bh * SEQ + lane * 8 + i] = -g[i];
    pm = fmaxf(pm, g[i]); pmv[i] = pm;
  }
  float mx = pm;
#pragma unroll
  for (int off = 1; off < 64; off <<= 1) {
    float n = __shfl_up(mx, off);
    if (lane >= off) mx = fmaxf(mx, n);
  }
  float ex = __shfl_up(mx, 1);
  if (lane == 0) ex = -INFINITY;
#pragma unroll
  for (int i = 0; i < 8; ++i) {
    float inc = fmaxf(ex, pmv[i]);
    mrow[(long)bh * SEQ + lane * 8 + i] = Fv[i] + inc;
  }
}

// ---------------------------------------------------------------------------
// flash mLSTM cell + fused head-norm/skip/silu(z).
// Grid: x = h + NHEAD*b (same-(h,b) q-blocks -> same XCD -> K/V L2-resident),
//       y = q-tile. Block = 512 threads (8 waves):
// wave w: rg = w&3 (16 q-rows), th = w>>2 (t-half for QK^T, d-half for PV).
// Async stage: tile tt+1's global loads issue into regs during tile tt compute.
__global__ __launch_bounds__(512) void cell_kernel(
    const unsigned short* __restrict__ qb, const unsigned short* __restrict__ kb,
    const unsigned short* __restrict__ vbT,
    const float* __restrict__ F, const float* __restrict__ Bc,
    const float* __restrict__ mrow,
    const unsigned short* __restrict__ upb,
    const float* __restrict__ onw, const float* __restrict__ skw,
    unsigned short* __restrict__ xcb) {
  int hb = blockIdx.x;
  int h = hb & (NHEAD - 1), b = hb >> 2;
  int qt = blockIdx.y;
  int tid = threadIdx.x, lane = tid & 63, w = tid >> 6;   // w 0..7
  int l15 = lane & 15, l4 = lane >> 4;
  int rg = w & 3, th = w >> 2;
  __shared__ unsigned short Ks[64][264];   // 528B row stride
  __shared__ unsigned short Vs[256][72];   // 144B row stride
  __shared__ unsigned short P[64][72];
  __shared__ float redx[2][4][16];         // [th][rg][row-in-group]
  __shared__ float redy[2][4][16][2];
  int bh = b * NHEAD + h;
  const float* Fr = F + (long)bh * SEQ;
  const float* Br = Bc + (long)bh * SEQ;
  const float* Mr = mrow + (long)bh * SEQ;
  int s0 = qt * 64;
  long bs0 = (long)b * SEQ;
  int sr[4]; float Ar[4], Mv[4];
#pragma unroll
  for (int r = 0; r < 4; ++r) {
    sr[r] = s0 + rg * 16 + l4 * 4 + r;
    float fs = Fr[sr[r]];
    Mv[r] = Mr[sr[r]];
    Ar[r] = fs - Mv[r];
  }
  bf16x8 qf[8];
  const unsigned short* qp = qb + (bs0 + s0 + rg * 16 + l15) * INNERD + h * DHEAD + l4 * 8;
#pragma unroll
  for (int kk = 0; kk < 8; ++kk) qf[kk] = *(const bf16x8*)(qp + kk * 32);
  f32x4 o[8];
#pragma unroll
  for (int i = 0; i < 8; ++i) o[i] = (f32x4){0.f, 0.f, 0.f, 0.f};
  float rs[4] = {0.f, 0.f, 0.f, 0.f};

  const unsigned short* kbase = kb + bs0 * INNERD + h * DHEAD;
  const unsigned short* vbase = vbT + (long)bh * DHEAD * SEQ;
  int kR[4], kC[4], vD[4], vC[4];
#pragma unroll
  for (int i = 0; i < 4; ++i) {
    int idx = tid + i * 512;      // 0..2047
    kR[i] = idx >> 5; kC[i] = (idx & 31) * 8;
    vD[i] = idx >> 3; vC[i] = (idx & 7) * 8;
  }
  bf16x8 kreg[4], vreg[4];
#pragma unroll
  for (int i = 0; i < 4; ++i) {
    kreg[i] = *(const bf16x8*)(kbase + (long)kR[i] * INNERD + kC[i]);
    vreg[i] = *(const bf16x8*)(vbase + (long)vD[i] * SEQ + vC[i]);
  }

  int nt = qt + 1;
  for (int tt = 0; tt < nt; ++tt) {
    int t0 = tt * 64;
    __syncthreads();                     // previous tile's LDS reads done
#pragma unroll
    for (int i = 0; i < 4; ++i) {
      *(bf16x8*)(&Ks[kR[i]][kC[i]]) = kreg[i];
      *(bf16x8*)(&Vs[vD[i]][vC[i]]) = vreg[i];
    }
    __syncthreads();
    if (tt + 1 < nt) {                   // async: overlaps compute below
      int t1 = (tt + 1) * 64;
#pragma unroll
      for (int i = 0; i < 4; ++i) {
        kreg[i] = *(const bf16x8*)(kbase + (long)(t1 + kR[i]) * INNERD + kC[i]);
        vreg[i] = *(const bf16x8*)(vbase + (long)vD[i] * SEQ + t1 + vC[i]);
      }
    }
    bool diag = (tt == nt - 1);
#pragma unroll
    for (int tfl = 0; tfl < 2; ++tfl) {
      f32x4 s = (f32x4){0.f, 0.f, 0.f, 0.f};
#pragma unroll
      for (int kk = 0; kk < 8; ++kk) {
        bf16x8 kf = *(const bf16x8*)(&Ks[th * 32 + tfl * 16 + l15][kk * 32 + l4 * 8]);
        s = __builtin_amdgcn_mfma_f32_16x16x32_bf16(qf[kk], kf, s, 0, 0, 0);
      }
      int tcol = t0 + th * 32 + tfl * 16 + l15;
      float bc = Br[tcol];
#pragma unroll
      for (int r = 0; r < 4; ++r) {
        float p = s[r] * 0.0625f * __expf(Ar[r] - bc);
        if (diag && tcol > sr[r]) p = 0.f;
        rs[r] += p;
        P[rg * 16 + l4 * 4 + r][th * 32 + tfl * 16 + l15] = f2b(p);
      }
    }
    __syncthreads();                     // P complete (both t-halves)
#pragma unroll
    for (int ks = 0; ks < 2; ++ks) {
      bf16x8 pa = *(const bf16x8*)(&P[rg * 16 + l15][ks * 32 + l4 * 8]);
#pragma unroll
      for (int df = 0; df < 8; ++df) {
        bf16x8 vf = *(const bf16x8*)(&Vs[th * 128 + df * 16 + l15][ks * 32 + l4 * 8]);
        o[df] = __builtin_amdgcn_mfma_f32_16x16x32_bf16(pa, vf, o[df], 0, 0, 0);
      }
    }
  }
#pragma unroll
  for (int r = 0; r < 4; ++r)
#pragma unroll
    for (int off = 1; off < 16; off <<= 1) rs[r] += __shfl_xor(rs[r], off);
  if (l15 == 0) {
#pragma unroll
    for (int r = 0; r < 4; ++r) redx[th][rg][l4 * 4 + r] = rs[r];
  }
  __syncthreads();
  float inv[4];
#pragma unroll
  for (int r = 0; r < 4; ++r) {
    float tot = redx[0][rg][l4 * 4 + r] + redx[1][rg][l4 * 4 + r];
    float denom = fmaxf(fabsf(tot), __expf(-Mv[r])) + 1e-6f;
    inv[r] = 1.f / denom;
  }
#pragma unroll
  for (int df = 0; df < 8; ++df)
#pragma unroll
    for (int r = 0; r < 4; ++r) o[df][r] *= inv[r];
  float sm[4] = {}, sq[4] = {};
#pragma unroll
  for (int df = 0; df < 8; ++df)
#pragma unroll
    for (int r = 0; r < 4; ++r) { float x = o[df][r]; sm[r] += x; sq[r] += x * x; }
#pragma unroll
  for (int r = 0; r < 4; ++r)
#pragma unroll
    for (int off = 1; off < 16; off <<= 1) {
      sm[r] += __shfl_xor(sm[r], off);
      sq[r] += __shfl_xor(sq[r], off);
    }
  if (l15 == 0) {
#pragma unroll
    for (int r = 0; r < 4; ++r) {
      redy[th][rg][l4 * 4 + r][0] = sm[r];
      redy[th][rg][l4 * 4 + r][1] = sq[r];
    }
  }
  __syncthreads();
  float mu[4], rstd[4];
#pragma unroll
  for (int r = 0; r < 4; ++r) {
    float smt = redy[0][rg][l4 * 4 + r][0] + redy[1][rg][l4 * 4 + r][0];
    float sqt = redy[0][rg][l4 * 4 + r][1] + redy[1][rg][l4 * 4 + r][1];
    mu[r] = smt * (1.f / DHEAD);
    float var = sqt * (1.f / DHEAD) - mu[r] * mu[r];
    rstd[r] = rsqrtf(var + LNEPS);
  }
#pragma unroll
  for (int df = 0; df < 8; ++df) {
    int c = h * DHEAD + th * 128 + df * 16 + l15;
    float ow = onw[c], sw = skw[c];
#pragma unroll
    for (int r = 0; r < 4; ++r) {
      long grow = bs0 + sr[r];
      float z = b2f(upb[grow * (2 * INNERD) + INNERD + c]);
      float sig = 1.f / (1.f + __expf(-z));
      float xcv = b2f(xcb[grow * INNERD + c]);   // in-place: read pre-value
      float y = (o[df][r] - mu[r]) * rstd[r];
      float g = (y * ow + sw * xcv) * (z * sig);
      xcb[grow * INNERD + c] = f2b(g);
    }
  }
}

// ---------------------------------------------------------------------------
__global__ __launch_bounds__(256) void final_kernel(
    const float* __restrict__ h, const float* __restrict__ pw,
    const float* __restrict__ ow, const float* __restrict__ ob,
    const float* __restrict__ Wh, const float* __restrict__ bh,
    float* __restrict__ out) {
  __shared__ float red[8];
  __shared__ float sh[EMBD];
  int b = blockIdx.x, tid = threadIdx.x;
  const float* xr = h + ((long)b * SEQ + (SEQ - 1)) * EMBD;
  float v0 = xr[tid], v1 = xr[tid + 256];
  float s = v0 + v1, ss = v0 * v0 + v1 * v1;
  block_sum2(s, ss, red, tid);
  float mu = s * (1.f / EMBD), var = ss * (1.f / EMBD) - mu * mu;
  float rs = rsqrtf(var + LNEPS);
  float y0 = (v0 - mu) * rs * pw[tid];
  float y1 = (v1 - mu) * rs * pw[tid + 256];
  float s2 = y0 + y1, ss2 = y0 * y0 + y1 * y1;
  block_sum2(s2, ss2, red, tid);
  float mu2 = s2 * (1.f / EMBD), var2 = ss2 * (1.f / EMBD) - mu2 * mu2;
  float rs2 = rsqrtf(var2 + LNEPS);
  sh[tid]       = (y0 - mu2) * rs2 * ow[tid] + ob[tid];
  sh[tid + 256] = (y1 - mu2) * rs2 * ow[tid + 256] + ob[tid + 256];
  __syncthreads();
  if (tid < OUTD) {
    float acc = bh[tid];
    for (int e = 0; e < EMBD; ++e) acc += sh[e] * Wh[e * OUTD + tid];
    out[b * OUTD + tid] = acc;
  }
}

// ---------------------------------------------------------------------------
extern "C" void kernel_launch(void* const* d_in, const int* in_sizes, int n_in,
                              void* d_out, int out_size, void* d_ws, size_t ws_size,
                              hipStream_t stream) {
  const float* inputs    = (const float*)d_in[0];
  const float* W_in      = (const float*)d_in[1];
  const float* ln_w      = (const float*)d_in[2];
  const float* W_up      = (const float*)d_in[3];
  const float* conv_w    = (const float*)d_in[4];
  const float* conv_b    = (const float*)d_in[5];
  const float* Wq        = (const float*)d_in[6];
  const float* Wk        = (const float*)d_in[7];
  const float* Wv        = (const float*)d_in[8];
  const float* W_i       = (const float*)d_in[9];
  const float* b_i       = (const float*)d_in[10];
  const float* W_f       = (const float*)d_in[11];
  const float* b_f       = (const float*)d_in[12];
  const float* skipw     = (const float*)d_in[13];
  const float* onorm_w   = (const float*)d_in[14];
  const float* W_down    = (const float*)d_in[15];
  const float* post_ln_w = (const float*)d_in[16];
  const float* out_ln_w  = (const float*)d_in[17];
  const float* out_ln_b  = (const float*)d_in[18];
  const float* W_head    = (const float*)d_in[19];
  const float* b_head    = (const float*)d_in[20];
  float* out = (float*)d_out;

  const long ROWS = (long)BATCH * SEQ;   // 8192
  // ---- full-batch workspace layout (~159 MB; ws_size = 256 MB confirmed) ----
  float* fpool = (float*)d_ws;
  float* h    = fpool; fpool += ROWS * EMBD;            // 16.8 MB
  float* ipb  = fpool; fpool += (long)BATCH * NHEAD * SEQ;
  float* fpb  = fpool; fpool += (long)BATCH * NHEAD * SEQ;
  float* Fc   = fpool; fpool += (long)BATCH * NHEAD * SEQ;
  float* Bcc  = fpool; fpool += (long)BATCH * NHEAD * SEQ;
  float* mrw  = fpool; fpool += (long)BATCH * NHEAD * SEQ;
  unsigned short* upool = (unsigned short*)fpool;
  unsigned short* xn    = upool; upool += ROWS * EMBD;          //  8.4 MB
  unsigned short* upb   = upool; upool += ROWS * 2 * INNERD;    // 33.6 MB
  unsigned short* xcb   = upool; upool += ROWS * INNERD;        // 16.8 MB
  unsigned short* qbuf  = upool; upool += ROWS * INNERD;
  unsigned short* kbuf  = upool; upool += ROWS * INNERD;
  unsigned short* vbuf  = upool; upool += ROWS * INNERD;
  unsigned short* vbT   = upool; upool += (long)BATCH * NHEAD * DHEAD * SEQ;
  unsigned short* WupT  = upool; upool += (long)NBLK * 2 * INNERD * EMBD;
  unsigned short* WdnT  = upool; upool += (long)NBLK * EMBD * INNERD;
  unsigned short* Wqkv  = upool; upool += (long)NBLK * 3 * NHEAD * DHEAD * DHEAD;

  // ---- weight prep (same work every call) ----
  castT_kernel<<<dim3(2 * INNERD / 32, EMBD / 32, NBLK), 256, 0, stream>>>(
      W_up, WupT, EMBD, 2 * INNERD);
  castT_kernel<<<dim3(EMBD / 32, INNERD / 32, NBLK), 256, 0, stream>>>(
      W_down, WdnT, INNERD, EMBD);
  const long WQN = (long)NBLK * NHEAD * DHEAD * DHEAD;
  castqkv_kernel<<<dim3(WQN / 256, 1, 3), 256, 0, stream>>>(Wq, Wk, Wv, Wqkv);

  inproj_kernel<<<(ROWS * EMBD) / 256, 256, 0, stream>>>(inputs, W_in, h);

  for (int bl = 0; bl < NBLK; ++bl) {
    const float* lnw  = ln_w    + (long)bl * EMBD;
    const float* cwb  = conv_w  + (long)bl * 4 * INNERD;
    const float* cbb  = conv_b  + (long)bl * INNERD;
    const float* Wib  = W_i     + (long)bl * GATES * NHEAD;
    const float* bib  = b_i     + (long)bl * NHEAD;
    const float* Wfb  = W_f     + (long)bl * GATES * NHEAD;
    const float* bfb  = b_f     + (long)bl * NHEAD;
    const float* skb  = skipw   + (long)bl * INNERD;
    const float* onw  = onorm_w + (long)bl * INNERD;
    const unsigned short* WupTb = WupT + (long)bl * 2 * INNERD * EMBD;
    const unsigned short* WdnTb = WdnT + (long)bl * EMBD * INNERD;
    const unsigned short* Wqkvb = Wqkv + (long)bl * 3 * NHEAD * DHEAD * DHEAD;

    ln_mul_kernel<<<ROWS, 256, 0, stream>>>(h, lnw, xn);

    // up: [8192x512] @ [512x2048] -> bf16 up_b   (1024 blocks)
    gemm_mfma<2><<<dim3(2 * INNERD / 128, ROWS / 128, 1), 256, 0, stream>>>(
        xn, EMBD, WupTb, EMBD, upb, 2 * INNERD, EMBD);

    conv_silu_kernel<<<(ROWS * INNERD) / 256, 256, 0, stream>>>(upb, cwb, cbb, xcb);

    // merged q/k/v projections (z = proj*4 + head), 1536 blocks
    qkv_mfma<<<dim3(DHEAD / 128, ROWS / 128, 12), 256, 0, stream>>>(
        xcb, upb, Wqkvb, qbuf, kbuf, vbuf, vbT);

    gates_kernel<<<ROWS, 256, 0, stream>>>(qbuf, kbuf, vbuf, Wib, bib, Wfb, bfb, ipb, fpb);
    fgate_kernel<<<BATCH * NHEAD, 64, 0, stream>>>(fpb, ipb, Fc, Bcc, mrw);

    // x = hb (same-(h,b) blocks -> same XCD), y = q-tile; 512 threads
    cell_kernel<<<dim3(NHEAD * BATCH, SEQ / 64, 1), 512, 0, stream>>>(
        qbuf, kbuf, vbT, Fc, Bcc, mrw, upb, onw, skb, xcb);

    // down: h += [8192x1024] @ [1024x512]   (256 blocks)
    gemm_mfma<1><<<dim3(EMBD / 128, ROWS / 128, 1), 256, 0, stream>>>(
        xcb, INNERD, WdnTb, INNERD, h, EMBD, INNERD);
  }

  final_kernel<<<BATCH, 256, 0, stream>>>(h, post_ln_w, out_ln_w, out_ln_b,
                                          W_head, b_head, out);
}

// Round 12
// 615.842 us; speedup vs baseline: 10.0079x; 1.0034x over previous
//
#include <hip/hip_runtime.h>
#include <hip/hip_bf16.h>

#define BATCH  16
#define SEQ    512
#define IND    32
#define OUTD   32
#define EMBD   512
#define NBLK   2
#define NHEAD  4
#define INNERD 1024   // 2*EMB
#define DHEAD  256    // INNER/NH
#define GATES  3072   // 3*INNER
#define LNEPS  1e-5f

typedef __attribute__((ext_vector_type(8))) short bf16x8;   // 8 bf16 in 4 VGPRs
typedef __attribute__((ext_vector_type(4))) float f32x4;

__device__ __forceinline__ float b2f(unsigned short u) {
  union { unsigned int i; float f; } v; v.i = ((unsigned int)u) << 16; return v.f;
}
__device__ __forceinline__ unsigned short f2b(float f) {
  __hip_bfloat16 h = __float2bfloat16(f);           // round-to-nearest
  unsigned short u; __builtin_memcpy(&u, &h, 2); return u;
}

// async global -> LDS, 16B per lane (global_load_lds_dwordx4)
__device__ __forceinline__ void gload16(const void* g, void* l) {
  __builtin_amdgcn_global_load_lds(
      (const __attribute__((address_space(1))) unsigned int*)g,
      (__attribute__((address_space(3))) unsigned int*)l, 16, 0, 0);
}

// ---------------------------------------------------------------------------
__device__ __forceinline__ void block_sum2(float& a, float& b, float* red, int tid) {
#pragma unroll
  for (int o = 1; o < 64; o <<= 1) { a += __shfl_xor(a, o); b += __shfl_xor(b, o); }
  int wid = tid >> 6;
  if ((tid & 63) == 0) { red[wid] = a; red[4 + wid] = b; }
  __syncthreads();
  a = red[0] + red[1] + red[2] + red[3];
  b = red[4] + red[5] + red[6] + red[7];
  __syncthreads();
}

// ---------------------------------------------------------------------------
__global__ __launch_bounds__(256) void inproj_kernel(
    const float* __restrict__ in, const float* __restrict__ Win,
    float* __restrict__ h) {
  long idx = (long)blockIdx.x * 256 + threadIdx.x;
  int  e   = (int)(idx & (EMBD - 1));
  long row = idx >> 9;
  const float* ir = in + row * IND;
  float acc = 0.f;
#pragma unroll
  for (int i = 0; i < IND; ++i) acc += ir[i] * Win[i * EMBD + e];
  h[idx] = acc;
}

// ---------------------------------------------------------------------------
// xn[row,:] = bf16( LN(x[row,:]) * w )
__global__ __launch_bounds__(256) void ln_mul_kernel(
    const float* __restrict__ x, const float* __restrict__ w,
    unsigned short* __restrict__ y) {
  __shared__ float red[8];
  long row = blockIdx.x;
  int tid = threadIdx.x;
  const float* xr = x + row * EMBD;
  float v0 = xr[tid], v1 = xr[tid + 256];
  float s = v0 + v1, ss = v0 * v0 + v1 * v1;
  block_sum2(s, ss, red, tid);
  float mu = s * (1.f / EMBD);
  float var = ss * (1.f / EMBD) - mu * mu;
  float rs = rsqrtf(var + LNEPS);
  y[row * EMBD + tid]       = f2b((v0 - mu) * rs * w[tid]);
  y[row * EMBD + tid + 256] = f2b((v1 - mu) * rs * w[tid + 256]);
}

// ---------------------------------------------------------------------------
// weight transpose-cast: out[n][k] = bf16(in[k][n]); z batches
__global__ __launch_bounds__(256) void castT_kernel(
    const float* __restrict__ in, unsigned short* __restrict__ out, int K, int N) {
  __shared__ float t[32][33];
  long zoff = (long)blockIdx.z * K * N;
  in += zoff; out += zoff;
  int n0 = blockIdx.x * 32, k0 = blockIdx.y * 32;
  int tx = threadIdx.x & 31, ty = threadIdx.x >> 5;   // ty 0..7
#pragma unroll
  for (int i = 0; i < 32; i += 8)
    t[ty + i][tx] = in[(long)(k0 + ty + i) * N + n0 + tx];
  __syncthreads();
#pragma unroll
  for (int i = 0; i < 32; i += 8)
    out[(long)(n0 + ty + i) * K + k0 + tx] = f2b(t[tx][ty + i]);
}

// cast q/k/v weights into packed Wqkv: [NBLK][3][NHEAD][DH][DH]
__global__ __launch_bounds__(256) void castqkv_kernel(
    const float* __restrict__ Wq, const float* __restrict__ Wk,
    const float* __restrict__ Wv, unsigned short* __restrict__ Wqkv) {
  int proj = blockIdx.z;
  const float* src = (proj == 0) ? Wq : (proj == 1) ? Wk : Wv;
  long i = (long)blockIdx.x * 256 + threadIdx.x;   // over NBLK*NH*DH*DH
  const long PER = (long)NHEAD * DHEAD * DHEAD;
  long bl = i / PER, rest = i - bl * PER;
  Wqkv[(bl * 3 + proj) * PER + rest] = f2b(src[i]);
}

// ---------------------------------------------------------------------------
// bf16 MFMA GEMM (m97 structure + bijective XCD swizzle):
// C[m,n] = sum_k A[m,k] * Bt[n,k]; 128x128 tile, 4 waves, linear LDS,
// global_load_lds staging.  MODE: 1 = f32 accumulate, 2 = bf16 store
template <int MODE>
__global__ __launch_bounds__(256) void gemm_mfma(
    const unsigned short* __restrict__ A, int lda,
    const unsigned short* __restrict__ B, int ldb,
    void* __restrict__ Cv, int ldc, int K) {
  // XCD swizzle: each XCD gets a contiguous chunk of tiles -> A/B panels L2-local
  int nwg = gridDim.x * gridDim.y;                 // multiple of 8
  int g = blockIdx.x + gridDim.x * blockIdx.y;
  int q8 = nwg >> 3;
  int gs = (g & 7) * q8 + (g >> 3);
  int bx = gs % gridDim.x, by = gs / gridDim.x;
  __shared__ unsigned short As[128][32];
  __shared__ unsigned short Bs[128][32];
  int tid = threadIdx.x;
  int lane = tid & 63, w = tid >> 6;
  int l15 = lane & 15, l4 = lane >> 4;
  int wr = w >> 1, wc = w & 1;
  int m0 = by * 128, n0 = bx * 128;
  int srow = lane >> 2, scol = (lane & 3) * 8;   // staging: lane -> row/col
  f32x4 acc[4][4];
#pragma unroll
  for (int i = 0; i < 4; ++i)
#pragma unroll
    for (int j = 0; j < 4; ++j) acc[i][j] = (f32x4){0.f, 0.f, 0.f, 0.f};

  for (int k0 = 0; k0 < K; k0 += 32) {
    __syncthreads();                       // prev compute done reading LDS
#pragma unroll
    for (int ia = 0; ia < 2; ++ia) {
      int rb = (ia * 4 + w) * 16;          // wave-uniform row base
      gload16(A + (long)(m0 + rb + srow) * lda + k0 + scol, &As[rb][0]);
      gload16(B + (long)(n0 + rb + srow) * ldb + k0 + scol, &Bs[rb][0]);
    }
    __syncthreads();                       // vmcnt(0) drain at barrier
    bf16x8 af[4], bfr[4];
#pragma unroll
    for (int i = 0; i < 4; ++i)
      af[i] = *(const bf16x8*)(&As[wr * 64 + i * 16 + l15][l4 * 8]);
#pragma unroll
    for (int j = 0; j < 4; ++j)
      bfr[j] = *(const bf16x8*)(&Bs[wc * 64 + j * 16 + l15][l4 * 8]);
#pragma unroll
    for (int i = 0; i < 4; ++i)
#pragma unroll
      for (int j = 0; j < 4; ++j)
        acc[i][j] = __builtin_amdgcn_mfma_f32_16x16x32_bf16(af[i], bfr[j], acc[i][j], 0, 0, 0);
  }

#pragma unroll
  for (int i = 0; i < 4; ++i) {
#pragma unroll
    for (int j = 0; j < 4; ++j) {
      int col = n0 + wc * 64 + j * 16 + l15;
#pragma unroll
      for (int r = 0; r < 4; ++r) {
        int m = m0 + wr * 64 + i * 16 + l4 * 4 + r;
        float val = acc[i][j][r];
        if (MODE == 1) {
          float* C = (float*)Cv;
          C[(long)m * ldc + col] += val;
        } else {
          unsigned short* C = (unsigned short*)Cv;
          C[(long)m * ldc + col] = f2b(val);
        }
      }
    }
  }
}

// ---------------------------------------------------------------------------
// merged q/k/v projection GEMM (m97 staging + XCD swizzle), 12 z-slices.
// Swizzled z is head-major: z = head*3 + proj, so q&k of the same head
// (same A-panel) land in the same XCD chunk.
__global__ __launch_bounds__(256) void qkv_mfma(
    const unsigned short* __restrict__ xcb, const unsigned short* __restrict__ upb,
    const unsigned short* __restrict__ Wqkv,   // [3][NHEAD][DH][DH] (this block)
    unsigned short* __restrict__ qbuf, unsigned short* __restrict__ kbuf,
    unsigned short* __restrict__ vbuf, unsigned short* __restrict__ vbT) {
  int nwg = gridDim.x * gridDim.y * gridDim.z;   // 1536
  int g = blockIdx.x + gridDim.x * (blockIdx.y + gridDim.y * blockIdx.z);
  int q8 = nwg >> 3;
  int gs = (g & 7) * q8 + (g >> 3);
  int bx = gs % gridDim.x;
  int rem = gs / gridDim.x;
  int by = rem % gridDim.y;
  int z  = rem / gridDim.y;          // 0..11, head-major
  int head = z / 3, proj = z % 3;
  const unsigned short* A = ((proj == 2) ? upb : xcb) + head * DHEAD;
  int lda = (proj == 2) ? 2 * INNERD : INNERD;
  const unsigned short* B = Wqkv + ((long)proj * NHEAD + head) * DHEAD * DHEAD;
  unsigned short* C = ((proj == 0) ? qbuf : (proj == 1) ? kbuf : vbuf) + head * DHEAD;
  __shared__ unsigned short As[128][32];
  __shared__ unsigned short Bs[128][32];
  int tid = threadIdx.x;
  int lane = tid & 63, w = tid >> 6;
  int l15 = lane & 15, l4 = lane >> 4;
  int wr = w >> 1, wc = w & 1;
  int m0 = by * 128, n0 = bx * 128;
  int srow = lane >> 2, scol = (lane & 3) * 8;
  f32x4 acc[4][4];
#pragma unroll
  for (int i = 0; i < 4; ++i)
#pragma unroll
    for (int j = 0; j < 4; ++j) acc[i][j] = (f32x4){0.f, 0.f, 0.f, 0.f};

  for (int k0 = 0; k0 < DHEAD; k0 += 32) {
    __syncthreads();
#pragma unroll
    for (int ia = 0; ia < 2; ++ia) {
      int rb = (ia * 4 + w) * 16;
      gload16(A + (long)(m0 + rb + srow) * lda + k0 + scol, &As[rb][0]);
      gload16(B + (long)(n0 + rb + srow) * DHEAD + k0 + scol, &Bs[rb][0]);
    }
    __syncthreads();
    bf16x8 af[4], bfr[4];
#pragma unroll
    for (int i = 0; i < 4; ++i)
      af[i] = *(const bf16x8*)(&As[wr * 64 + i * 16 + l15][l4 * 8]);
#pragma unroll
    for (int j = 0; j < 4; ++j)
      bfr[j] = *(const bf16x8*)(&Bs[wc * 64 + j * 16 + l15][l4 * 8]);
#pragma unroll
    for (int i = 0; i < 4; ++i)
#pragma unroll
      for (int j = 0; j < 4; ++j)
        acc[i][j] = __builtin_amdgcn_mfma_f32_16x16x32_bf16(af[i], bfr[j], acc[i][j], 0, 0, 0);
  }

#pragma unroll
  for (int i = 0; i < 4; ++i) {
#pragma unroll
    for (int j = 0; j < 4; ++j) {
      int col = n0 + wc * 64 + j * 16 + l15;   // 0..255 within head
#pragma unroll
      for (int r = 0; r < 4; ++r) {
        int m = m0 + wr * 64 + i * 16 + l4 * 4 + r;
        unsigned short bv = f2b(acc[i][j][r]);
        C[(long)m * INNERD + col] = bv;
        if (proj == 2) {
          long ct = (((long)(m >> 9) * NHEAD + head) * DHEAD + col) * SEQ + (m & (SEQ - 1));
          vbT[ct] = bv;
        }
      }
    }
  }
}

// ---------------------------------------------------------------------------
// causal depthwise conv (K=4) over xm = up_b[:, :1024] (bf16) + bias, silu -> bf16
__global__ __launch_bounds__(256) void conv_silu_kernel(
    const unsigned short* __restrict__ upb, const float* __restrict__ w,
    const float* __restrict__ bias, unsigned short* __restrict__ xcb) {
  long idx = (long)blockIdx.x * 256 + threadIdx.x;  // ROWS*INNER
  int c = (int)(idx & (INNERD - 1));
  long bs = idx >> 10;
  int s = (int)(bs & (SEQ - 1));
  long b = bs >> 9;
  float acc = bias[c];
#pragma unroll
  for (int kk = 0; kk < 4; ++kk) {
    int t = s + kk - 3;
    if (t >= 0) acc += w[kk * INNERD + c] * b2f(upb[((b << 9) + t) * (2 * INNERD) + c]);
  }
  float sig = 1.f / (1.f + __expf(-acc));
  xcb[bs * INNERD + c] = f2b(acc * sig);
}

// ---------------------------------------------------------------------------
// gate projections from bf16 q/k/v rows
__global__ __launch_bounds__(256) void gates_kernel(
    const unsigned short* __restrict__ qh, const unsigned short* __restrict__ kh,
    const unsigned short* __restrict__ vh,
    const float* __restrict__ Wi, const float* __restrict__ bi,
    const float* __restrict__ Wf, const float* __restrict__ bf,
    float* __restrict__ ip, float* __restrict__ fp) {
  __shared__ float red[4][8];
  long bs = blockIdx.x;
  int tid = threadIdx.x;
  int lane = tid & 63, wid = tid >> 6;
  float pi[4] = {}, pf[4] = {};
  const unsigned short* qr = qh + bs * INNERD;
  const unsigned short* kr = kh + bs * INNERD;
  const unsigned short* vr = vh + bs * INNERD;
  for (int j = tid; j < INNERD; j += 256) {
    float xq = b2f(qr[j]), xk = b2f(kr[j]), xv = b2f(vr[j]);
    const float* wiq = Wi + (long)j * NHEAD;
    const float* wik = Wi + (long)(j + INNERD) * NHEAD;
    const float* wiv = Wi + (long)(j + 2 * INNERD) * NHEAD;
    const float* wfq = Wf + (long)j * NHEAD;
    const float* wfk = Wf + (long)(j + INNERD) * NHEAD;
    const float* wfv = Wf + (long)(j + 2 * INNERD) * NHEAD;
#pragma unroll
    for (int n = 0; n < NHEAD; ++n) {
      pi[n] += xq * wiq[n] + xk * wik[n] + xv * wiv[n];
      pf[n] += xq * wfq[n] + xk * wfk[n] + xv * wfv[n];
    }
  }
#pragma unroll
  for (int n = 0; n < NHEAD; ++n) {
#pragma unroll
    for (int o = 1; o < 64; o <<= 1) {
      pi[n] += __shfl_xor(pi[n], o);
      pf[n] += __shfl_xor(pf[n], o);
    }
  }
  if (lane == 0) {
#pragma unroll
    for (int n = 0; n < NHEAD; ++n) { red[wid][n] = pi[n]; red[wid][4 + n] = pf[n]; }
  }
  __syncthreads();
  if (tid == 0) {
    long b = bs >> 9;
    int s = (int)(bs & (SEQ - 1));
#pragma unroll
    for (int n = 0; n < NHEAD; ++n) {
      float a = red[0][n] + red[1][n] + red[2][n] + red[3][n] + bi[n];
      float c = red[0][4 + n] + red[1][4 + n] + red[2][4 + n] + red[3][4 + n] + bf[n];
      ip[(b * NHEAD + n) * SEQ + s] = a;
      fp[(b * NHEAD + n) * SEQ + s] = c;
    }
  }
}

// ---------------------------------------------------------------------------
// parallel gate scan: F = cumsum(logsig(f)); Bc = F - i; mrow = F + runmax(i - F)
__global__ __launch_bounds__(64) void fgate_kernel(
    const float* __restrict__ fp, const float* __restrict__ ip,
    float* __restrict__ F, float* __restrict__ Bc, float* __restrict__ mrow) {
  int bh = blockIdx.x;
  int lane = threadIdx.x;
  const float* fr = fp + (long)bh * SEQ;
  const float* ir = ip + (long)bh * SEQ;
  float v[8]; float run = 0.f;
#pragma unroll
  for (int i = 0; i < 8; ++i) {
    float x = fr[lane * 8 + i];
    float ls = fminf(x, 0.f) - log1pf(__expf(-fabsf(x)));
    run += ls; v[i] = run;
  }
  float tot = run, scan = run;
#pragma unroll
  for (int off = 1; off < 64; off <<= 1) {
    float n = __shfl_up(scan, off);
    if (lane >= off) scan += n;
  }
  float excl = scan - tot;
  float Fv[8];
#pragma unroll
  for (int i = 0; i < 8; ++i) {
    Fv[i] = excl + v[i];
    F[(long)bh * SEQ + lane * 8 + i] = Fv[i];
  }
  float g[8], pmv[8]; float pm = -INFINITY;
#pragma unroll
  for (int i = 0; i < 8; ++i) {
    g[i] = ir[lane * 8 + i] - Fv[i];
    Bc[(long)bh * SEQ + lane * 8 + i] = -g[i];
    pm = fmaxf(pm, g[i]); pmv[i] = pm;
  }
  float mx = pm;
#pragma unroll
  for (int off = 1; off < 64; off <<= 1) {
    float n = __shfl_up(mx, off);
    if (lane >= off) mx = fmaxf(mx, n);
  }
  float ex = __shfl_up(mx, 1);
  if (lane == 0) ex = -INFINITY;
#pragma unroll
  for (int i = 0; i < 8; ++i) {
    float inc = fmaxf(ex, pmv[i]);
    mrow[(long)bh * SEQ + lane * 8 + i] = Fv[i] + inc;
  }
}

// ---------------------------------------------------------------------------
// flash mLSTM cell + fused head-norm/skip/silu(z).
// Grid: x = h + NHEAD*b (same-(h,b) q-blocks -> same XCD -> K/V L2-resident),
//       y = q-tile. Block = 512 threads (8 waves):
// wave w: rg = w&3 (16 q-rows), th = w>>2 (t-half for QK^T, d-half for PV).
// Async stage: tile tt+1's global loads issue into regs during tile tt compute.
__global__ __launch_bounds__(512) void cell_kernel(
    const unsigned short* __restrict__ qb, const unsigned short* __restrict__ kb,
    const unsigned short* __restrict__ vbT,
    const float* __restrict__ F, const float* __restrict__ Bc,
    const float* __restrict__ mrow,
    const unsigned short* __restrict__ upb,
    const float* __restrict__ onw, const float* __restrict__ skw,
    unsigned short* __restrict__ xcb) {
  int hb = blockIdx.x;
  int h = hb & (NHEAD - 1), b = hb >> 2;
  int qt = blockIdx.y;
  int tid = threadIdx.x, lane = tid & 63, w = tid >> 6;   // w 0..7
  int l15 = lane & 15, l4 = lane >> 4;
  int rg = w & 3, th = w >> 2;
  __shared__ unsigned short Ks[64][264];   // 528B row stride
  __shared__ unsigned short Vs[256][72];   // 144B row stride
  __shared__ unsigned short P[64][72];
  __shared__ float redx[2][4][16];         // [th][rg][row-in-group]
  __shared__ float redy[2][4][16][2];
  int bh = b * NHEAD + h;
  const float* Fr = F + (long)bh * SEQ;
  const float* Br = Bc + (long)bh * SEQ;
  const float* Mr = mrow + (long)bh * SEQ;
  int s0 = qt * 64;
  long bs0 = (long)b * SEQ;
  int sr[4]; float Ar[4], Mv[4];
#pragma unroll
  for (int r = 0; r < 4; ++r) {
    sr[r] = s0 + rg * 16 + l4 * 4 + r;
    float fs = Fr[sr[r]];
    Mv[r] = Mr[sr[r]];
    Ar[r] = fs - Mv[r];
  }
  bf16x8 qf[8];
  const unsigned short* qp = qb + (bs0 + s0 + rg * 16 + l15) * INNERD + h * DHEAD + l4 * 8;
#pragma unroll
  for (int kk = 0; kk < 8; ++kk) qf[kk] = *(const bf16x8*)(qp + kk * 32);
  f32x4 o[8];
#pragma unroll
  for (int i = 0; i < 8; ++i) o[i] = (f32x4){0.f, 0.f, 0.f, 0.f};
  float rs[4] = {0.f, 0.f, 0.f, 0.f};

  const unsigned short* kbase = kb + bs0 * INNERD + h * DHEAD;
  const unsigned short* vbase = vbT + (long)bh * DHEAD * SEQ;
  int kR[4], kC[4], vD[4], vC[4];
#pragma unroll
  for (int i = 0; i < 4; ++i) {
    int idx = tid + i * 512;      // 0..2047
    kR[i] = idx >> 5; kC[i] = (idx & 31) * 8;
    vD[i] = idx >> 3; vC[i] = (idx & 7) * 8;
  }
  bf16x8 kreg[4], vreg[4];
#pragma unroll
  for (int i = 0; i < 4; ++i) {
    kreg[i] = *(const bf16x8*)(kbase + (long)kR[i] * INNERD + kC[i]);
    vreg[i] = *(const bf16x8*)(vbase + (long)vD[i] * SEQ + vC[i]);
  }

  int nt = qt + 1;
  for (int tt = 0; tt < nt; ++tt) {
    int t0 = tt * 64;
    __syncthreads();                     // previous tile's LDS reads done
#pragma unroll
    for (int i = 0; i < 4; ++i) {
      *(bf16x8*)(&Ks[kR[i]][kC[i]]) = kreg[i];
      *(bf16x8*)(&Vs[vD[i]][vC[i]]) = vreg[i];
    }
    __syncthreads();
    if (tt + 1 < nt) {                   // async: overlaps compute below
      int t1 = (tt + 1) * 64;
#pragma unroll
      for (int i = 0; i < 4; ++i) {
        kreg[i] = *(const bf16x8*)(kbase + (long)(t1 + kR[i]) * INNERD + kC[i]);
        vreg[i] = *(const bf16x8*)(vbase + (long)vD[i] * SEQ + t1 + vC[i]);
      }
    }
    bool diag = (tt == nt - 1);
#pragma unroll
    for (int tfl = 0; tfl < 2; ++tfl) {
      f32x4 s = (f32x4){0.f, 0.f, 0.f, 0.f};
#pragma unroll
      for (int kk = 0; kk < 8; ++kk) {
        bf16x8 kf = *(const bf16x8*)(&Ks[th * 32 + tfl * 16 + l15][kk * 32 + l4 * 8]);
        s = __builtin_amdgcn_mfma_f32_16x16x32_bf16(qf[kk], kf, s, 0, 0, 0);
      }
      int tcol = t0 + th * 32 + tfl * 16 + l15;
      float bc = Br[tcol];
#pragma unroll
      for (int r = 0; r < 4; ++r) {
        float p = s[r] * 0.0625f * __expf(Ar[r] - bc);
        if (diag && tcol > sr[r]) p = 0.f;
        rs[r] += p;
        P[rg * 16 + l4 * 4 + r][th * 32 + tfl * 16 + l15] = f2b(p);
      }
    }
    __syncthreads();                     // P complete (both t-halves)
#pragma unroll
    for (int ks = 0; ks < 2; ++ks) {
      bf16x8 pa = *(const bf16x8*)(&P[rg * 16 + l15][ks * 32 + l4 * 8]);
#pragma unroll
      for (int df = 0; df < 8; ++df) {
        bf16x8 vf = *(const bf16x8*)(&Vs[th * 128 + df * 16 + l15][ks * 32 + l4 * 8]);
        o[df] = __builtin_amdgcn_mfma_f32_16x16x32_bf16(pa, vf, o[df], 0, 0, 0);
      }
    }
  }
#pragma unroll
  for (int r = 0; r < 4; ++r)
#pragma unroll
    for (int off = 1; off < 16; off <<= 1) rs[r] += __shfl_xor(rs[r], off);
  if (l15 == 0) {
#pragma unroll
    for (int r = 0; r < 4; ++r) redx[th][rg][l4 * 4 + r] = rs[r];
  }
  __syncthreads();
  float inv[4];
#pragma unroll
  for (int r = 0; r < 4; ++r) {
    float tot = redx[0][rg][l4 * 4 + r] + redx[1][rg][l4 * 4 + r];
    float denom = fmaxf(fabsf(tot), __expf(-Mv[r])) + 1e-6f;
    inv[r] = 1.f / denom;
  }
#pragma unroll
  for (int df = 0; df < 8; ++df)
#pragma unroll
    for (int r = 0; r < 4; ++r) o[df][r] *= inv[r];
  float sm[4] = {}, sq[4] = {};
#pragma unroll
  for (int df = 0; df < 8; ++df)
#pragma unroll
    for (int r = 0; r < 4; ++r) { float x = o[df][r]; sm[r] += x; sq[r] += x * x; }
#pragma unroll
  for (int r = 0; r < 4; ++r)
#pragma unroll
    for (int off = 1; off < 16; off <<= 1) {
      sm[r] += __shfl_xor(sm[r], off);
      sq[r] += __shfl_xor(sq[r], off);
    }
  if (l15 == 0) {
#pragma unroll
    for (int r = 0; r < 4; ++r) {
      redy[th][rg][l4 * 4 + r][0] = sm[r];
      redy[th][rg][l4 * 4 + r][1] = sq[r];
    }
  }
  __syncthreads();
  float mu[4], rstd[4];
#pragma unroll
  for (int r = 0; r < 4; ++r) {
    float smt = redy[0][rg][l4 * 4 + r][0] + redy[1][rg][l4 * 4 + r][0];
    float sqt = redy[0][rg][l4 * 4 + r][1] + redy[1][rg][l4 * 4 + r][1];
    mu[r] = smt * (1.f / DHEAD);
    float var = sqt * (1.f / DHEAD) - mu[r] * mu[r];
    rstd[r] = rsqrtf(var + LNEPS);
  }
#pragma unroll
  for (int df = 0; df < 8; ++df) {
    int c = h * DHEAD + th * 128 + df * 16 + l15;
    float ow = onw[c], sw = skw[c];
#pragma unroll
    for (int r = 0; r < 4; ++r) {
      long grow = bs0 + sr[r];
      float z = b2f(upb[grow * (2 * INNERD) + INNERD + c]);
      float sig = 1.f / (1.f + __expf(-z));
      float xcv = b2f(xcb[grow * INNERD + c]);   // in-place: read pre-value
      float y = (o[df][r] - mu[r]) * rstd[r];
      float g = (y * ow + sw * xcv) * (z * sig);
      xcb[grow * INNERD + c] = f2b(g);
    }
  }
}

// ---------------------------------------------------------------------------
__global__ __launch_bounds__(256) void final_kernel(
    const float* __restrict__ h, const float* __restrict__ pw,
    const float* __restrict__ ow, const float* __restrict__ ob,
    const float* __restrict__ Wh, const float* __restrict__ bh,
    float* __restrict__ out) {
  __shared__ float red[8];
  __shared__ float sh[EMBD];
  int b = blockIdx.x, tid = threadIdx.x;
  const float* xr = h + ((long)b * SEQ + (SEQ - 1)) * EMBD;
  float v0 = xr[tid], v1 = xr[tid + 256];
  float s = v0 + v1, ss = v0 * v0 + v1 * v1;
  block_sum2(s, ss, red, tid);
  float mu = s * (1.f / EMBD), var = ss * (1.f / EMBD) - mu * mu;
  float rs = rsqrtf(var + LNEPS);
  float y0 = (v0 - mu) * rs * pw[tid];
  float y1 = (v1 - mu) * rs * pw[tid + 256];
  float s2 = y0 + y1, ss2 = y0 * y0 + y1 * y1;
  block_sum2(s2, ss2, red, tid);
  float mu2 = s2 * (1.f / EMBD), var2 = ss2 * (1.f / EMBD) - mu2 * mu2;
  float rs2 = rsqrtf(var2 + LNEPS);
  sh[tid]       = (y0 - mu2) * rs2 * ow[tid] + ob[tid];
  sh[tid + 256] = (y1 - mu2) * rs2 * ow[tid + 256] + ob[tid + 256];
  __syncthreads();
  if (tid < OUTD) {
    float acc = bh[tid];
    for (int e = 0; e < EMBD; ++e) acc += sh[e] * Wh[e * OUTD + tid];
    out[b * OUTD + tid] = acc;
  }
}

// ---------------------------------------------------------------------------
extern "C" void kernel_launch(void* const* d_in, const int* in_sizes, int n_in,
                              void* d_out, int out_size, void* d_ws, size_t ws_size,
                              hipStream_t stream) {
  const float* inputs    = (const float*)d_in[0];
  const float* W_in      = (const float*)d_in[1];
  const float* ln_w      = (const float*)d_in[2];
  const float* W_up      = (const float*)d_in[3];
  const float* conv_w    = (const float*)d_in[4];
  const float* conv_b    = (const float*)d_in[5];
  const float* Wq        = (const float*)d_in[6];
  const float* Wk        = (const float*)d_in[7];
  const float* Wv        = (const float*)d_in[8];
  const float* W_i       = (const float*)d_in[9];
  const float* b_i       = (const float*)d_in[10];
  const float* W_f       = (const float*)d_in[11];
  const float* b_f       = (const float*)d_in[12];
  const float* skipw     = (const float*)d_in[13];
  const float* onorm_w   = (const float*)d_in[14];
  const float* W_down    = (const float*)d_in[15];
  const float* post_ln_w = (const float*)d_in[16];
  const float* out_ln_w  = (const float*)d_in[17];
  const float* out_ln_b  = (const float*)d_in[18];
  const float* W_head    = (const float*)d_in[19];
  const float* b_head    = (const float*)d_in[20];
  float* out = (float*)d_out;

  const long ROWS = (long)BATCH * SEQ;   // 8192
  // ---- full-batch workspace layout (~159 MB; ws_size = 256 MB confirmed) ----
  float* fpool = (float*)d_ws;
  float* h    = fpool; fpool += ROWS * EMBD;            // 16.8 MB
  float* ipb  = fpool; fpool += (long)BATCH * NHEAD * SEQ;
  float* fpb  = fpool; fpool += (long)BATCH * NHEAD * SEQ;
  float* Fc   = fpool; fpool += (long)BATCH * NHEAD * SEQ;
  float* Bcc  = fpool; fpool += (long)BATCH * NHEAD * SEQ;
  float* mrw  = fpool; fpool += (long)BATCH * NHEAD * SEQ;
  unsigned short* upool = (unsigned short*)fpool;
  unsigned short* xn    = upool; upool += ROWS * EMBD;          //  8.4 MB
  unsigned short* upb   = upool; upool += ROWS * 2 * INNERD;    // 33.6 MB
  unsigned short* xcb   = upool; upool += ROWS * INNERD;        // 16.8 MB
  unsigned short* qbuf  = upool; upool += ROWS * INNERD;
  unsigned short* kbuf  = upool; upool += ROWS * INNERD;
  unsigned short* vbuf  = upool; upool += ROWS * INNERD;
  unsigned short* vbT   = upool; upool += (long)BATCH * NHEAD * DHEAD * SEQ;
  unsigned short* WupT  = upool; upool += (long)NBLK * 2 * INNERD * EMBD;
  unsigned short* WdnT  = upool; upool += (long)NBLK * EMBD * INNERD;
  unsigned short* Wqkv  = upool; upool += (long)NBLK * 3 * NHEAD * DHEAD * DHEAD;

  // ---- weight prep (same work every call) ----
  castT_kernel<<<dim3(2 * INNERD / 32, EMBD / 32, NBLK), 256, 0, stream>>>(
      W_up, WupT, EMBD, 2 * INNERD);
  castT_kernel<<<dim3(EMBD / 32, INNERD / 32, NBLK), 256, 0, stream>>>(
      W_down, WdnT, INNERD, EMBD);
  const long WQN = (long)NBLK * NHEAD * DHEAD * DHEAD;
  castqkv_kernel<<<dim3(WQN / 256, 1, 3), 256, 0, stream>>>(Wq, Wk, Wv, Wqkv);

  inproj_kernel<<<(ROWS * EMBD) / 256, 256, 0, stream>>>(inputs, W_in, h);

  for (int bl = 0; bl < NBLK; ++bl) {
    const float* lnw  = ln_w    + (long)bl * EMBD;
    const float* cwb  = conv_w  + (long)bl * 4 * INNERD;
    const float* cbb  = conv_b  + (long)bl * INNERD;
    const float* Wib  = W_i     + (long)bl * GATES * NHEAD;
    const float* bib  = b_i     + (long)bl * NHEAD;
    const float* Wfb  = W_f     + (long)bl * GATES * NHEAD;
    const float* bfb  = b_f     + (long)bl * NHEAD;
    const float* skb  = skipw   + (long)bl * INNERD;
    const float* onw  = onorm_w + (long)bl * INNERD;
    const unsigned short* WupTb = WupT + (long)bl * 2 * INNERD * EMBD;
    const unsigned short* WdnTb = WdnT + (long)bl * EMBD * INNERD;
    const unsigned short* Wqkvb = Wqkv + (long)bl * 3 * NHEAD * DHEAD * DHEAD;

    ln_mul_kernel<<<ROWS, 256, 0, stream>>>(h, lnw, xn);

    // up: [8192x512] @ [512x2048] -> bf16 up_b   (1024 blocks, XCD-swizzled)
    gemm_mfma<2><<<dim3(2 * INNERD / 128, ROWS / 128, 1), 256, 0, stream>>>(
        xn, EMBD, WupTb, EMBD, upb, 2 * INNERD, EMBD);

    conv_silu_kernel<<<(ROWS * INNERD) / 256, 256, 0, stream>>>(upb, cwb, cbb, xcb);

    // merged q/k/v projections (12 z, head-major after swizzle), 1536 blocks
    qkv_mfma<<<dim3(DHEAD / 128, ROWS / 128, 12), 256, 0, stream>>>(
        xcb, upb, Wqkvb, qbuf, kbuf, vbuf, vbT);

    gates_kernel<<<ROWS, 256, 0, stream>>>(qbuf, kbuf, vbuf, Wib, bib, Wfb, bfb, ipb, fpb);
    fgate_kernel<<<BATCH * NHEAD, 64, 0, stream>>>(fpb, ipb, Fc, Bcc, mrw);

    // x = hb (same-(h,b) blocks -> same XCD), y = q-tile; 512 threads
    cell_kernel<<<dim3(NHEAD * BATCH, SEQ / 64, 1), 512, 0, stream>>>(
        qbuf, kbuf, vbT, Fc, Bcc, mrw, upb, onw, skb, xcb);

    // down: h += [8192x1024] @ [1024x512]   (256 blocks, XCD-swizzled)
    gemm_mfma<1><<<dim3(EMBD / 128, ROWS / 128, 1), 256, 0, stream>>>(
        xcb, INNERD, WdnTb, INNERD, h, EMBD, INNERD);
  }

  final_kernel<<<BATCH, 256, 0, stream>>>(h, post_ln_w, out_ln_w, out_ln_b,
                                          W_head, b_head, out);
}

// Round 13
// 615.740 us; speedup vs baseline: 10.0095x; 1.0002x over previous
//
#include <hip/hip_runtime.h>
#include <hip/hip_bf16.h>

#define BATCH  16
#define SEQ    512
#define IND    32
#define OUTD   32
#define EMBD   512
#define NBLK   2
#define NHEAD  4
#define INNERD 1024   // 2*EMB
#define DHEAD  256    // INNER/NH
#define GATES  3072   // 3*INNER
#define LNEPS  1e-5f

typedef __attribute__((ext_vector_type(8))) short bf16x8;   // 8 bf16 in 4 VGPRs
typedef __attribute__((ext_vector_type(4))) float f32x4;

__device__ __forceinline__ float b2f(unsigned short u) {
  union { unsigned int i; float f; } v; v.i = ((unsigned int)u) << 16; return v.f;
}
__device__ __forceinline__ unsigned short f2b(float f) {
  __hip_bfloat16 h = __float2bfloat16(f);           // round-to-nearest
  unsigned short u; __builtin_memcpy(&u, &h, 2); return u;
}

// async global -> LDS, 16B per lane (global_load_lds_dwordx4)
__device__ __forceinline__ void gload16(const void* g, void* l) {
  __builtin_amdgcn_global_load_lds(
      (const __attribute__((address_space(1))) unsigned int*)g,
      (__attribute__((address_space(3))) unsigned int*)l, 16, 0, 0);
}

// ---------------------------------------------------------------------------
__device__ __forceinline__ void block_sum2(float& a, float& b, float* red, int tid) {
#pragma unroll
  for (int o = 1; o < 64; o <<= 1) { a += __shfl_xor(a, o); b += __shfl_xor(b, o); }
  int wid = tid >> 6;
  if ((tid & 63) == 0) { red[wid] = a; red[4 + wid] = b; }
  __syncthreads();
  a = red[0] + red[1] + red[2] + red[3];
  b = red[4] + red[5] + red[6] + red[7];
  __syncthreads();
}

// ---------------------------------------------------------------------------
__global__ __launch_bounds__(256) void inproj_kernel(
    const float* __restrict__ in, const float* __restrict__ Win,
    float* __restrict__ h) {
  long idx = (long)blockIdx.x * 256 + threadIdx.x;
  int  e   = (int)(idx & (EMBD - 1));
  long row = idx >> 9;
  const float* ir = in + row * IND;
  float acc = 0.f;
#pragma unroll
  for (int i = 0; i < IND; ++i) acc += ir[i] * Win[i * EMBD + e];
  h[idx] = acc;
}

// ---------------------------------------------------------------------------
// xn[row,:] = bf16( LN(x[row,:]) * w )
__global__ __launch_bounds__(256) void ln_mul_kernel(
    const float* __restrict__ x, const float* __restrict__ w,
    unsigned short* __restrict__ y) {
  __shared__ float red[8];
  long row = blockIdx.x;
  int tid = threadIdx.x;
  const float* xr = x + row * EMBD;
  float v0 = xr[tid], v1 = xr[tid + 256];
  float s = v0 + v1, ss = v0 * v0 + v1 * v1;
  block_sum2(s, ss, red, tid);
  float mu = s * (1.f / EMBD);
  float var = ss * (1.f / EMBD) - mu * mu;
  float rs = rsqrtf(var + LNEPS);
  y[row * EMBD + tid]       = f2b((v0 - mu) * rs * w[tid]);
  y[row * EMBD + tid + 256] = f2b((v1 - mu) * rs * w[tid + 256]);
}

// ---------------------------------------------------------------------------
// weight transpose-cast: out[n][k] = bf16(in[k][n]); z batches
__global__ __launch_bounds__(256) void castT_kernel(
    const float* __restrict__ in, unsigned short* __restrict__ out, int K, int N) {
  __shared__ float t[32][33];
  long zoff = (long)blockIdx.z * K * N;
  in += zoff; out += zoff;
  int n0 = blockIdx.x * 32, k0 = blockIdx.y * 32;
  int tx = threadIdx.x & 31, ty = threadIdx.x >> 5;   // ty 0..7
#pragma unroll
  for (int i = 0; i < 32; i += 8)
    t[ty + i][tx] = in[(long)(k0 + ty + i) * N + n0 + tx];
  __syncthreads();
#pragma unroll
  for (int i = 0; i < 32; i += 8)
    out[(long)(n0 + ty + i) * K + k0 + tx] = f2b(t[tx][ty + i]);
}

// cast q/k/v weights into packed Wqkv: [NBLK][3][NHEAD][DH][DH]
__global__ __launch_bounds__(256) void castqkv_kernel(
    const float* __restrict__ Wq, const float* __restrict__ Wk,
    const float* __restrict__ Wv, unsigned short* __restrict__ Wqkv) {
  int proj = blockIdx.z;
  const float* src = (proj == 0) ? Wq : (proj == 1) ? Wk : Wv;
  long i = (long)blockIdx.x * 256 + threadIdx.x;   // over NBLK*NH*DH*DH
  const long PER = (long)NHEAD * DHEAD * DHEAD;
  long bl = i / PER, rest = i - bl * PER;
  Wqkv[(bl * 3 + proj) * PER + rest] = f2b(src[i]);
}

// ---------------------------------------------------------------------------
// bf16 MFMA GEMM (2-phase double-buffered m230 recipe + XCD swizzle):
// prologue stage(buf0); barrier; loop { stage(buf^1,t+1); compute(buf); barrier }
// 128x128 tile, 4 waves, linear LDS, global_load_lds staging.
// MODE: 1 = f32 accumulate, 2 = bf16 store
template <int MODE>
__global__ __launch_bounds__(256) void gemm_mfma(
    const unsigned short* __restrict__ A, int lda,
    const unsigned short* __restrict__ B, int ldb,
    void* __restrict__ Cv, int ldc, int K) {
  int nwg = gridDim.x * gridDim.y;                 // multiple of 8
  int g = blockIdx.x + gridDim.x * blockIdx.y;
  int q8 = nwg >> 3;
  int gs = (g & 7) * q8 + (g >> 3);
  int bx = gs % gridDim.x, by = gs / gridDim.x;
  __shared__ unsigned short As[2][128][32];
  __shared__ unsigned short Bs[2][128][32];
  int tid = threadIdx.x;
  int lane = tid & 63, w = tid >> 6;
  int l15 = lane & 15, l4 = lane >> 4;
  int wr = w >> 1, wc = w & 1;
  int m0 = by * 128, n0 = bx * 128;
  int srow = lane >> 2, scol = (lane & 3) * 8;   // staging: lane -> row/col
  f32x4 acc[4][4];
#pragma unroll
  for (int i = 0; i < 4; ++i)
#pragma unroll
    for (int j = 0; j < 4; ++j) acc[i][j] = (f32x4){0.f, 0.f, 0.f, 0.f};

#define STAGE_G(bu, k0)                                                       \
  {                                                                           \
    _Pragma("unroll")                                                         \
    for (int ia = 0; ia < 2; ++ia) {                                          \
      int rb = (ia * 4 + w) * 16;                                             \
      gload16(A + (long)(m0 + rb + srow) * lda + (k0) + scol, &As[bu][rb][0]);\
      gload16(B + (long)(n0 + rb + srow) * ldb + (k0) + scol, &Bs[bu][rb][0]);\
    }                                                                         \
  }

  STAGE_G(0, 0);
  __syncthreads();                       // buf0 ready (vmcnt drained)
  int nk = K >> 5, cur = 0;
  for (int t = 0; t < nk; ++t) {
    if (t + 1 < nk) STAGE_G(cur ^ 1, (t + 1) << 5);   // flies during compute
    bf16x8 af[4], bfr[4];
#pragma unroll
    for (int i = 0; i < 4; ++i)
      af[i] = *(const bf16x8*)(&As[cur][wr * 64 + i * 16 + l15][l4 * 8]);
#pragma unroll
    for (int j = 0; j < 4; ++j)
      bfr[j] = *(const bf16x8*)(&Bs[cur][wc * 64 + j * 16 + l15][l4 * 8]);
#pragma unroll
    for (int i = 0; i < 4; ++i)
#pragma unroll
      for (int j = 0; j < 4; ++j)
        acc[i][j] = __builtin_amdgcn_mfma_f32_16x16x32_bf16(af[i], bfr[j], acc[i][j], 0, 0, 0);
    __syncthreads();                     // next buf ready + all waves done reading cur
    cur ^= 1;
  }
#undef STAGE_G

#pragma unroll
  for (int i = 0; i < 4; ++i) {
#pragma unroll
    for (int j = 0; j < 4; ++j) {
      int col = n0 + wc * 64 + j * 16 + l15;
#pragma unroll
      for (int r = 0; r < 4; ++r) {
        int m = m0 + wr * 64 + i * 16 + l4 * 4 + r;
        float val = acc[i][j][r];
        if (MODE == 1) {
          float* C = (float*)Cv;
          C[(long)m * ldc + col] += val;
        } else {
          unsigned short* C = (unsigned short*)Cv;
          C[(long)m * ldc + col] = f2b(val);
        }
      }
    }
  }
}

// ---------------------------------------------------------------------------
// merged q/k/v projection GEMM (2-phase dbuf + XCD swizzle), 12 z-slices.
// Swizzled z is head-major: z = head*3 + proj.
__global__ __launch_bounds__(256) void qkv_mfma(
    const unsigned short* __restrict__ xcb, const unsigned short* __restrict__ upb,
    const unsigned short* __restrict__ Wqkv,   // [3][NHEAD][DH][DH] (this block)
    unsigned short* __restrict__ qbuf, unsigned short* __restrict__ kbuf,
    unsigned short* __restrict__ vbuf, unsigned short* __restrict__ vbT) {
  int nwg = gridDim.x * gridDim.y * gridDim.z;   // 1536
  int g = blockIdx.x + gridDim.x * (blockIdx.y + gridDim.y * blockIdx.z);
  int q8 = nwg >> 3;
  int gs = (g & 7) * q8 + (g >> 3);
  int bx = gs % gridDim.x;
  int rem = gs / gridDim.x;
  int by = rem % gridDim.y;
  int z  = rem / gridDim.y;          // 0..11, head-major
  int head = z / 3, proj = z % 3;
  const unsigned short* A = ((proj == 2) ? upb : xcb) + head * DHEAD;
  int lda = (proj == 2) ? 2 * INNERD : INNERD;
  const unsigned short* B = Wqkv + ((long)proj * NHEAD + head) * DHEAD * DHEAD;
  unsigned short* C = ((proj == 0) ? qbuf : (proj == 1) ? kbuf : vbuf) + head * DHEAD;
  __shared__ unsigned short As[2][128][32];
  __shared__ unsigned short Bs[2][128][32];
  int tid = threadIdx.x;
  int lane = tid & 63, w = tid >> 6;
  int l15 = lane & 15, l4 = lane >> 4;
  int wr = w >> 1, wc = w & 1;
  int m0 = by * 128, n0 = bx * 128;
  int srow = lane >> 2, scol = (lane & 3) * 8;
  f32x4 acc[4][4];
#pragma unroll
  for (int i = 0; i < 4; ++i)
#pragma unroll
    for (int j = 0; j < 4; ++j) acc[i][j] = (f32x4){0.f, 0.f, 0.f, 0.f};

#define STAGE_Q(bu, k0)                                                        \
  {                                                                            \
    _Pragma("unroll")                                                          \
    for (int ia = 0; ia < 2; ++ia) {                                           \
      int rb = (ia * 4 + w) * 16;                                              \
      gload16(A + (long)(m0 + rb + srow) * lda + (k0) + scol, &As[bu][rb][0]); \
      gload16(B + (long)(n0 + rb + srow) * DHEAD + (k0) + scol, &Bs[bu][rb][0]);\
    }                                                                          \
  }

  STAGE_Q(0, 0);
  __syncthreads();
  int cur = 0;
  for (int t = 0; t < (DHEAD >> 5); ++t) {
    if (t + 1 < (DHEAD >> 5)) STAGE_Q(cur ^ 1, (t + 1) << 5);
    bf16x8 af[4], bfr[4];
#pragma unroll
    for (int i = 0; i < 4; ++i)
      af[i] = *(const bf16x8*)(&As[cur][wr * 64 + i * 16 + l15][l4 * 8]);
#pragma unroll
    for (int j = 0; j < 4; ++j)
      bfr[j] = *(const bf16x8*)(&Bs[cur][wc * 64 + j * 16 + l15][l4 * 8]);
#pragma unroll
    for (int i = 0; i < 4; ++i)
#pragma unroll
      for (int j = 0; j < 4; ++j)
        acc[i][j] = __builtin_amdgcn_mfma_f32_16x16x32_bf16(af[i], bfr[j], acc[i][j], 0, 0, 0);
    __syncthreads();
    cur ^= 1;
  }
#undef STAGE_Q

#pragma unroll
  for (int i = 0; i < 4; ++i) {
#pragma unroll
    for (int j = 0; j < 4; ++j) {
      int col = n0 + wc * 64 + j * 16 + l15;   // 0..255 within head
#pragma unroll
      for (int r = 0; r < 4; ++r) {
        int m = m0 + wr * 64 + i * 16 + l4 * 4 + r;
        unsigned short bv = f2b(acc[i][j][r]);
        C[(long)m * INNERD + col] = bv;
        if (proj == 2) {
          long ct = (((long)(m >> 9) * NHEAD + head) * DHEAD + col) * SEQ + (m & (SEQ - 1));
          vbT[ct] = bv;
        }
      }
    }
  }
}

// ---------------------------------------------------------------------------
// causal depthwise conv (K=4) over xm = up_b[:, :1024] (bf16) + bias, silu -> bf16
__global__ __launch_bounds__(256) void conv_silu_kernel(
    const unsigned short* __restrict__ upb, const float* __restrict__ w,
    const float* __restrict__ bias, unsigned short* __restrict__ xcb) {
  long idx = (long)blockIdx.x * 256 + threadIdx.x;  // ROWS*INNER
  int c = (int)(idx & (INNERD - 1));
  long bs = idx >> 10;
  int s = (int)(bs & (SEQ - 1));
  long b = bs >> 9;
  float acc = bias[c];
#pragma unroll
  for (int kk = 0; kk < 4; ++kk) {
    int t = s + kk - 3;
    if (t >= 0) acc += w[kk * INNERD + c] * b2f(upb[((b << 9) + t) * (2 * INNERD) + c]);
  }
  float sig = 1.f / (1.f + __expf(-acc));
  xcb[bs * INNERD + c] = f2b(acc * sig);
}

// ---------------------------------------------------------------------------
// gate projections from bf16 q/k/v rows
__global__ __launch_bounds__(256) void gates_kernel(
    const unsigned short* __restrict__ qh, const unsigned short* __restrict__ kh,
    const unsigned short* __restrict__ vh,
    const float* __restrict__ Wi, const float* __restrict__ bi,
    const float* __restrict__ Wf, const float* __restrict__ bf,
    float* __restrict__ ip, float* __restrict__ fp) {
  __shared__ float red[4][8];
  long bs = blockIdx.x;
  int tid = threadIdx.x;
  int lane = tid & 63, wid = tid >> 6;
  float pi[4] = {}, pf[4] = {};
  const unsigned short* qr = qh + bs * INNERD;
  const unsigned short* kr = kh + bs * INNERD;
  const unsigned short* vr = vh + bs * INNERD;
  for (int j = tid; j < INNERD; j += 256) {
    float xq = b2f(qr[j]), xk = b2f(kr[j]), xv = b2f(vr[j]);
    const float* wiq = Wi + (long)j * NHEAD;
    const float* wik = Wi + (long)(j + INNERD) * NHEAD;
    const float* wiv = Wi + (long)(j + 2 * INNERD) * NHEAD;
    const float* wfq = Wf + (long)j * NHEAD;
    const float* wfk = Wf + (long)(j + INNERD) * NHEAD;
    const float* wfv = Wf + (long)(j + 2 * INNERD) * NHEAD;
#pragma unroll
    for (int n = 0; n < NHEAD; ++n) {
      pi[n] += xq * wiq[n] + xk * wik[n] + xv * wiv[n];
      pf[n] += xq * wfq[n] + xk * wfk[n] + xv * wfv[n];
    }
  }
#pragma unroll
  for (int n = 0; n < NHEAD; ++n) {
#pragma unroll
    for (int o = 1; o < 64; o <<= 1) {
      pi[n] += __shfl_xor(pi[n], o);
      pf[n] += __shfl_xor(pf[n], o);
    }
  }
  if (lane == 0) {
#pragma unroll
    for (int n = 0; n < NHEAD; ++n) { red[wid][n] = pi[n]; red[wid][4 + n] = pf[n]; }
  }
  __syncthreads();
  if (tid == 0) {
    long b = bs >> 9;
    int s = (int)(bs & (SEQ - 1));
#pragma unroll
    for (int n = 0; n < NHEAD; ++n) {
      float a = red[0][n] + red[1][n] + red[2][n] + red[3][n] + bi[n];
      float c = red[0][4 + n] + red[1][4 + n] + red[2][4 + n] + red[3][4 + n] + bf[n];
      ip[(b * NHEAD + n) * SEQ + s] = a;
      fp[(b * NHEAD + n) * SEQ + s] = c;
    }
  }
}

// ---------------------------------------------------------------------------
// parallel gate scan: F = cumsum(logsig(f)); Bc = F - i; mrow = F + runmax(i - F)
__global__ __launch_bounds__(64) void fgate_kernel(
    const float* __restrict__ fp, const float* __restrict__ ip,
    float* __restrict__ F, float* __restrict__ Bc, float* __restrict__ mrow) {
  int bh = blockIdx.x;
  int lane = threadIdx.x;
  const float* fr = fp + (long)bh * SEQ;
  const float* ir = ip + (long)bh * SEQ;
  float v[8]; float run = 0.f;
#pragma unroll
  for (int i = 0; i < 8; ++i) {
    float x = fr[lane * 8 + i];
    float ls = fminf(x, 0.f) - log1pf(__expf(-fabsf(x)));
    run += ls; v[i] = run;
  }
  float tot = run, scan = run;
#pragma unroll
  for (int off = 1; off < 64; off <<= 1) {
    float n = __shfl_up(scan, off);
    if (lane >= off) scan += n;
  }
  float excl = scan - tot;
  float Fv[8];
#pragma unroll
  for (int i = 0; i < 8; ++i) {
    Fv[i] = excl + v[i];
    F[(long)bh * SEQ + lane * 8 + i] = Fv[i];
  }
  float g[8], pmv[8]; float pm = -INFINITY;
#pragma unroll
  for (int i = 0; i < 8; ++i) {
    g[i] = ir[lane * 8 + i] - Fv[i];
    Bc[(long)bh * SEQ + lane * 8 + i] = -g[i];
    pm = fmaxf(pm, g[i]); pmv[i] = pm;
  }
  float mx = pm;
#pragma unroll
  for (int off = 1; off < 64; off <<= 1) {
    float n = __shfl_up(mx, off);
    if (lane >= off) mx = fmaxf(mx, n);
  }
  float ex = __shfl_up(mx, 1);
  if (lane == 0) ex = -INFINITY;
#pragma unroll
  for (int i = 0; i < 8; ++i) {
    float inc = fmaxf(ex, pmv[i]);
    mrow[(long)bh * SEQ + lane * 8 + i] = Fv[i] + inc;
  }
}

// ---------------------------------------------------------------------------
// flash mLSTM cell + fused head-norm/skip/silu(z).
// Grid: x = h + NHEAD*b (same-(h,b) q-blocks -> same XCD -> K/V L2-resident),
//       y = q-tile. Block = 512 threads (8 waves):
// wave w: rg = w&3 (16 q-rows), th = w>>2 (t-half for QK^T, d-half for PV).
// Async stage: tile tt+1's global loads issue into regs during tile tt compute.
__global__ __launch_bounds__(512) void cell_kernel(
    const unsigned short* __restrict__ qb, const unsigned short* __restrict__ kb,
    const unsigned short* __restrict__ vbT,
    const float* __restrict__ F, const float* __restrict__ Bc,
    const float* __restrict__ mrow,
    const unsigned short* __restrict__ upb,
    const float* __restrict__ onw, const float* __restrict__ skw,
    unsigned short* __restrict__ xcb) {
  int hb = blockIdx.x;
  int h = hb & (NHEAD - 1), b = hb >> 2;
  int qt = blockIdx.y;
  int tid = threadIdx.x, lane = tid & 63, w = tid >> 6;   // w 0..7
  int l15 = lane & 15, l4 = lane >> 4;
  int rg = w & 3, th = w >> 2;
  __shared__ unsigned short Ks[64][264];   // 528B row stride
  __shared__ unsigned short Vs[256][72];   // 144B row stride
  __shared__ unsigned short P[64][72];
  __shared__ float redx[2][4][16];         // [th][rg][row-in-group]
  __shared__ float redy[2][4][16][2];
  int bh = b * NHEAD + h;
  const float* Fr = F + (long)bh * SEQ;
  const float* Br = Bc + (long)bh * SEQ;
  const float* Mr = mrow + (long)bh * SEQ;
  int s0 = qt * 64;
  long bs0 = (long)b * SEQ;
  int sr[4]; float Ar[4], Mv[4];
#pragma unroll
  for (int r = 0; r < 4; ++r) {
    sr[r] = s0 + rg * 16 + l4 * 4 + r;
    float fs = Fr[sr[r]];
    Mv[r] = Mr[sr[r]];
    Ar[r] = fs - Mv[r];
  }
  bf16x8 qf[8];
  const unsigned short* qp = qb + (bs0 + s0 + rg * 16 + l15) * INNERD + h * DHEAD + l4 * 8;
#pragma unroll
  for (int kk = 0; kk < 8; ++kk) qf[kk] = *(const bf16x8*)(qp + kk * 32);
  f32x4 o[8];
#pragma unroll
  for (int i = 0; i < 8; ++i) o[i] = (f32x4){0.f, 0.f, 0.f, 0.f};
  float rs[4] = {0.f, 0.f, 0.f, 0.f};

  const unsigned short* kbase = kb + bs0 * INNERD + h * DHEAD;
  const unsigned short* vbase = vbT + (long)bh * DHEAD * SEQ;
  int kR[4], kC[4], vD[4], vC[4];
#pragma unroll
  for (int i = 0; i < 4; ++i) {
    int idx = tid + i * 512;      // 0..2047
    kR[i] = idx >> 5; kC[i] = (idx & 31) * 8;
    vD[i] = idx >> 3; vC[i] = (idx & 7) * 8;
  }
  bf16x8 kreg[4], vreg[4];
#pragma unroll
  for (int i = 0; i < 4; ++i) {
    kreg[i] = *(const bf16x8*)(kbase + (long)kR[i] * INNERD + kC[i]);
    vreg[i] = *(const bf16x8*)(vbase + (long)vD[i] * SEQ + vC[i]);
  }

  int nt = qt + 1;
  for (int tt = 0; tt < nt; ++tt) {
    int t0 = tt * 64;
    __syncthreads();                     // previous tile's LDS reads done
#pragma unroll
    for (int i = 0; i < 4; ++i) {
      *(bf16x8*)(&Ks[kR[i]][kC[i]]) = kreg[i];
      *(bf16x8*)(&Vs[vD[i]][vC[i]]) = vreg[i];
    }
    __syncthreads();
    if (tt + 1 < nt) {                   // async: overlaps compute below
      int t1 = (tt + 1) * 64;
#pragma unroll
      for (int i = 0; i < 4; ++i) {
        kreg[i] = *(const bf16x8*)(kbase + (long)(t1 + kR[i]) * INNERD + kC[i]);
        vreg[i] = *(const bf16x8*)(vbase + (long)vD[i] * SEQ + t1 + vC[i]);
      }
    }
    bool diag = (tt == nt - 1);
#pragma unroll
    for (int tfl = 0; tfl < 2; ++tfl) {
      f32x4 s = (f32x4){0.f, 0.f, 0.f, 0.f};
#pragma unroll
      for (int kk = 0; kk < 8; ++kk) {
        bf16x8 kf = *(const bf16x8*)(&Ks[th * 32 + tfl * 16 + l15][kk * 32 + l4 * 8]);
        s = __builtin_amdgcn_mfma_f32_16x16x32_bf16(qf[kk], kf, s, 0, 0, 0);
      }
      int tcol = t0 + th * 32 + tfl * 16 + l15;
      float bc = Br[tcol];
#pragma unroll
      for (int r = 0; r < 4; ++r) {
        float p = s[r] * 0.0625f * __expf(Ar[r] - bc);
        if (diag && tcol > sr[r]) p = 0.f;
        rs[r] += p;
        P[rg * 16 + l4 * 4 + r][th * 32 + tfl * 16 + l15] = f2b(p);
      }
    }
    __syncthreads();                     // P complete (both t-halves)
#pragma unroll
    for (int ks = 0; ks < 2; ++ks) {
      bf16x8 pa = *(const bf16x8*)(&P[rg * 16 + l15][ks * 32 + l4 * 8]);
#pragma unroll
      for (int df = 0; df < 8; ++df) {
        bf16x8 vf = *(const bf16x8*)(&Vs[th * 128 + df * 16 + l15][ks * 32 + l4 * 8]);
        o[df] = __builtin_amdgcn_mfma_f32_16x16x32_bf16(pa, vf, o[df], 0, 0, 0);
      }
    }
  }
#pragma unroll
  for (int r = 0; r < 4; ++r)
#pragma unroll
    for (int off = 1; off < 16; off <<= 1) rs[r] += __shfl_xor(rs[r], off);
  if (l15 == 0) {
#pragma unroll
    for (int r = 0; r < 4; ++r) redx[th][rg][l4 * 4 + r] = rs[r];
  }
  __syncthreads();
  float inv[4];
#pragma unroll
  for (int r = 0; r < 4; ++r) {
    float tot = redx[0][rg][l4 * 4 + r] + redx[1][rg][l4 * 4 + r];
    float denom = fmaxf(fabsf(tot), __expf(-Mv[r])) + 1e-6f;
    inv[r] = 1.f / denom;
  }
#pragma unroll
  for (int df = 0; df < 8; ++df)
#pragma unroll
    for (int r = 0; r < 4; ++r) o[df][r] *= inv[r];
  float sm[4] = {}, sq[4] = {};
#pragma unroll
  for (int df = 0; df < 8; ++df)
#pragma unroll
    for (int r = 0; r < 4; ++r) { float x = o[df][r]; sm[r] += x; sq[r] += x * x; }
#pragma unroll
  for (int r = 0; r < 4; ++r)
#pragma unroll
    for (int off = 1; off < 16; off <<= 1) {
      sm[r] += __shfl_xor(sm[r], off);
      sq[r] += __shfl_xor(sq[r], off);
    }
  if (l15 == 0) {
#pragma unroll
    for (int r = 0; r < 4; ++r) {
      redy[th][rg][l4 * 4 + r][0] = sm[r];
      redy[th][rg][l4 * 4 + r][1] = sq[r];
    }
  }
  __syncthreads();
  float mu[4], rstd[4];
#pragma unroll
  for (int r = 0; r < 4; ++r) {
    float smt = redy[0][rg][l4 * 4 + r][0] + redy[1][rg][l4 * 4 + r][0];
    float sqt = redy[0][rg][l4 * 4 + r][1] + redy[1][rg][l4 * 4 + r][1];
    mu[r] = smt * (1.f / DHEAD);
    float var = sqt * (1.f / DHEAD) - mu[r] * mu[r];
    rstd[r] = rsqrtf(var + LNEPS);
  }
#pragma unroll
  for (int df = 0; df < 8; ++df) {
    int c = h * DHEAD + th * 128 + df * 16 + l15;
    float ow = onw[c], sw = skw[c];
#pragma unroll
    for (int r = 0; r < 4; ++r) {
      long grow = bs0 + sr[r];
      float z = b2f(upb[grow * (2 * INNERD) + INNERD + c]);
      float sig = 1.f / (1.f + __expf(-z));
      float xcv = b2f(xcb[grow * INNERD + c]);   // in-place: read pre-value
      float y = (o[df][r] - mu[r]) * rstd[r];
      float g = (y * ow + sw * xcv) * (z * sig);
      xcb[grow * INNERD + c] = f2b(g);
    }
  }
}

// ---------------------------------------------------------------------------
__global__ __launch_bounds__(256) void final_kernel(
    const float* __restrict__ h, const float* __restrict__ pw,
    const float* __restrict__ ow, const float* __restrict__ ob,
    const float* __restrict__ Wh, const float* __restrict__ bh,
    float* __restrict__ out) {
  __shared__ float red[8];
  __shared__ float sh[EMBD];
  int b = blockIdx.x, tid = threadIdx.x;
  const float* xr = h + ((long)b * SEQ + (SEQ - 1)) * EMBD;
  float v0 = xr[tid], v1 = xr[tid + 256];
  float s = v0 + v1, ss = v0 * v0 + v1 * v1;
  block_sum2(s, ss, red, tid);
  float mu = s * (1.f / EMBD), var = ss * (1.f / EMBD) - mu * mu;
  float rs = rsqrtf(var + LNEPS);
  float y0 = (v0 - mu) * rs * pw[tid];
  float y1 = (v1 - mu) * rs * pw[tid + 256];
  float s2 = y0 + y1, ss2 = y0 * y0 + y1 * y1;
  block_sum2(s2, ss2, red, tid);
  float mu2 = s2 * (1.f / EMBD), var2 = ss2 * (1.f / EMBD) - mu2 * mu2;
  float rs2 = rsqrtf(var2 + LNEPS);
  sh[tid]       = (y0 - mu2) * rs2 * ow[tid] + ob[tid];
  sh[tid + 256] = (y1 - mu2) * rs2 * ow[tid + 256] + ob[tid + 256];
  __syncthreads();
  if (tid < OUTD) {
    float acc = bh[tid];
    for (int e = 0; e < EMBD; ++e) acc += sh[e] * Wh[e * OUTD + tid];
    out[b * OUTD + tid] = acc;
  }
}

// ---------------------------------------------------------------------------
extern "C" void kernel_launch(void* const* d_in, const int* in_sizes, int n_in,
                              void* d_out, int out_size, void* d_ws, size_t ws_size,
                              hipStream_t stream) {
  const float* inputs    = (const float*)d_in[0];
  const float* W_in      = (const float*)d_in[1];
  const float* ln_w      = (const float*)d_in[2];
  const float* W_up      = (const float*)d_in[3];
  const float* conv_w    = (const float*)d_in[4];
  const float* conv_b    = (const float*)d_in[5];
  const float* Wq        = (const float*)d_in[6];
  const float* Wk        = (const float*)d_in[7];
  const float* Wv        = (const float*)d_in[8];
  const float* W_i       = (const float*)d_in[9];
  const float* b_i       = (const float*)d_in[10];
  const float* W_f       = (const float*)d_in[11];
  const float* b_f       = (const float*)d_in[12];
  const float* skipw     = (const float*)d_in[13];
  const float* onorm_w   = (const float*)d_in[14];
  const float* W_down    = (const float*)d_in[15];
  const float* post_ln_w = (const float*)d_in[16];
  const float* out_ln_w  = (const float*)d_in[17];
  const float* out_ln_b  = (const float*)d_in[18];
  const float* W_head    = (const float*)d_in[19];
  const float* b_head    = (const float*)d_in[20];
  float* out = (float*)d_out;

  const long ROWS = (long)BATCH * SEQ;   // 8192
  // ---- full-batch workspace layout (~159 MB; ws_size = 256 MB confirmed) ----
  float* fpool = (float*)d_ws;
  float* h    = fpool; fpool += ROWS * EMBD;            // 16.8 MB
  float* ipb  = fpool; fpool += (long)BATCH * NHEAD * SEQ;
  float* fpb  = fpool; fpool += (long)BATCH * NHEAD * SEQ;
  float* Fc   = fpool; fpool += (long)BATCH * NHEAD * SEQ;
  float* Bcc  = fpool; fpool += (long)BATCH * NHEAD * SEQ;
  float* mrw  = fpool; fpool += (long)BATCH * NHEAD * SEQ;
  unsigned short* upool = (unsigned short*)fpool;
  unsigned short* xn    = upool; upool += ROWS * EMBD;          //  8.4 MB
  unsigned short* upb   = upool; upool += ROWS * 2 * INNERD;    // 33.6 MB
  unsigned short* xcb   = upool; upool += ROWS * INNERD;        // 16.8 MB
  unsigned short* qbuf  = upool; upool += ROWS * INNERD;
  unsigned short* kbuf  = upool; upool += ROWS * INNERD;
  unsigned short* vbuf  = upool; upool += ROWS * INNERD;
  unsigned short* vbT   = upool; upool += (long)BATCH * NHEAD * DHEAD * SEQ;
  unsigned short* WupT  = upool; upool += (long)NBLK * 2 * INNERD * EMBD;
  unsigned short* WdnT  = upool; upool += (long)NBLK * EMBD * INNERD;
  unsigned short* Wqkv  = upool; upool += (long)NBLK * 3 * NHEAD * DHEAD * DHEAD;

  // ---- weight prep (same work every call) ----
  castT_kernel<<<dim3(2 * INNERD / 32, EMBD / 32, NBLK), 256, 0, stream>>>(
      W_up, WupT, EMBD, 2 * INNERD);
  castT_kernel<<<dim3(EMBD / 32, INNERD / 32, NBLK), 256, 0, stream>>>(
      W_down, WdnT, INNERD, EMBD);
  const long WQN = (long)NBLK * NHEAD * DHEAD * DHEAD;
  castqkv_kernel<<<dim3(WQN / 256, 1, 3), 256, 0, stream>>>(Wq, Wk, Wv, Wqkv);

  inproj_kernel<<<(ROWS * EMBD) / 256, 256, 0, stream>>>(inputs, W_in, h);

  for (int bl = 0; bl < NBLK; ++bl) {
    const float* lnw  = ln_w    + (long)bl * EMBD;
    const float* cwb  = conv_w  + (long)bl * 4 * INNERD;
    const float* cbb  = conv_b  + (long)bl * INNERD;
    const float* Wib  = W_i     + (long)bl * GATES * NHEAD;
    const float* bib  = b_i     + (long)bl * NHEAD;
    const float* Wfb  = W_f     + (long)bl * GATES * NHEAD;
    const float* bfb  = b_f     + (long)bl * NHEAD;
    const float* skb  = skipw   + (long)bl * INNERD;
    const float* onw  = onorm_w + (long)bl * INNERD;
    const unsigned short* WupTb = WupT + (long)bl * 2 * INNERD * EMBD;
    const unsigned short* WdnTb = WdnT + (long)bl * EMBD * INNERD;
    const unsigned short* Wqkvb = Wqkv + (long)bl * 3 * NHEAD * DHEAD * DHEAD;

    ln_mul_kernel<<<ROWS, 256, 0, stream>>>(h, lnw, xn);

    // up: [8192x512] @ [512x2048] -> bf16 up_b   (1024 blocks, XCD-swizzled)
    gemm_mfma<2><<<dim3(2 * INNERD / 128, ROWS / 128, 1), 256, 0, stream>>>(
        xn, EMBD, WupTb, EMBD, upb, 2 * INNERD, EMBD);

    conv_silu_kernel<<<(ROWS * INNERD) / 256, 256, 0, stream>>>(upb, cwb, cbb, xcb);

    // merged q/k/v projections (12 z, head-major after swizzle), 1536 blocks
    qkv_mfma<<<dim3(DHEAD / 128, ROWS / 128, 12), 256, 0, stream>>>(
        xcb, upb, Wqkvb, qbuf, kbuf, vbuf, vbT);

    gates_kernel<<<ROWS, 256, 0, stream>>>(qbuf, kbuf, vbuf, Wib, bib, Wfb, bfb, ipb, fpb);
    fgate_kernel<<<BATCH * NHEAD, 64, 0, stream>>>(fpb, ipb, Fc, Bcc, mrw);

    // x = hb (same-(h,b) blocks -> same XCD), y = q-tile; 512 threads
    cell_kernel<<<dim3(NHEAD * BATCH, SEQ / 64, 1), 512, 0, stream>>>(
        qbuf, kbuf, vbT, Fc, Bcc, mrw, upb, onw, skb, xcb);

    // down: h += [8192x1024] @ [1024x512]   (256 blocks, XCD-swizzled)
    gemm_mfma<1><<<dim3(EMBD / 128, ROWS / 128, 1), 256, 0, stream>>>(
        xcb, INNERD, WdnTb, INNERD, h, EMBD, INNERD);
  }

  final_kernel<<<BATCH, 256, 0, stream>>>(h, post_ln_w, out_ln_w, out_ln_b,
                                          W_head, b_head, out);
}